// Round 10
// baseline (410.361 us; speedup 1.0000x reference)
//
#include <hip/hip_runtime.h>
#include <math.h>

#define LAM 9.0f
#define EPSF 1e-8f

typedef unsigned int uint;
typedef unsigned short ushort_t;
typedef __attribute__((ext_vector_type(8))) short short8;
typedef __attribute__((ext_vector_type(4))) float float4v;
typedef __attribute__((ext_vector_type(16))) float f32x16;

// ws layout (floats)
#define OFF_MMU 0                       // ushort planes: [hi 16384][lo 16384] per matrix
#define OFF_MLV (512*32)
#define OFF_M1  (2*512*32)
#define OFF_S   (3*512*32)              // 49152 : s[c][l] (64*32)
#define OFF_W   (OFF_S + 64*32)         // 51200 : w[b][c] (64*64)
#define OFF_QN  (OFF_W + 64*64)         // 55296 : qn[c][l][f] (64*32*32)
#define OFF_TS  (OFF_QN + 64*32*32)     // 120832: tnode_s[c][b][l][f] (64*64*32*32)
#define OFF_ATTN (OFF_TS + 64*64*32*32) // attn [2304][NW]
#define OFF_CVT  (OFF_ATTN + 2304*2048) // hi/lo bf16 arrays (ushort); REUSED by imgT2 after k2a

#define N_IMG_EL 2359296                // 2304*1024
#define N_CAP_EL 2097152                // 2048*1024
// imgT2 per plane (ushorts), 32x32x16-A-frag order: 64b * 32estep * 3kstep * 64lane * 8
#define IMGT2_EL 3145728

__device__ __forceinline__ ushort_t bf16_rne(float x) {
    uint u = __float_as_uint(x);
    uint r = (u + 0x7fffu + ((u >> 16) & 1u)) >> 16;
    return (ushort_t)r;
}
__device__ __forceinline__ float bf16_f(ushort_t h) {
    return __uint_as_float(((uint)h) << 16);
}
__device__ __forceinline__ uint pack2(ushort_t a, ushort_t b) {
    return (uint)a | ((uint)b << 16);
}

// ---------------- kcvt: split images+captions into hi/lo bf16 (Markidis) ----------------
__global__ __launch_bounds__(256) void kcvt(const float* __restrict__ img,
                                            const float* __restrict__ cap,
                                            ushort_t* __restrict__ dst) {
    size_t i = (size_t)blockIdx.x * 256 + threadIdx.x;   // float4 index
    const float* src;
    ushort_t *H, *L;
    size_t base;
    if (i < (N_IMG_EL / 4)) {
        src = img; H = dst; L = dst + N_IMG_EL; base = i * 4;
    } else {
        src = cap; H = dst + 2 * (size_t)N_IMG_EL; L = H + N_CAP_EL; base = (i - N_IMG_EL / 4) * 4;
    }
    float4 v = *(const float4*)(src + base);
    float x[4] = {v.x, v.y, v.z, v.w};
    ushort_t hh[4], ll[4];
    #pragma unroll
    for (int j = 0; j < 4; j++) {
        hh[j] = bf16_rne(x[j]);
        ll[j] = bf16_rne(x[j] - bf16_f(hh[j]));
    }
    *(uint2*)(H + base) = make_uint2(pack2(hh[0], hh[1]), pack2(hh[2], hh[3]));
    *(uint2*)(L + base) = make_uint2(pack2(ll[0], ll[1]), pack2(ll[2], ll[3]));
}

// ---------------- kcvt2 v2: build imgT2 in 32x32x16 MFMA A-fragment order, hi/lo ----------
// A[m=e_loc][k=r]: lane holds m = lane&31, k-slice = (lane>>5)*8 + j (per kstep of 16).
// layout: plane*IMGT2_EL + (((b*32 + estep)*3 + ks3)*64 + lane)*8
// elem j = img[b][r = ks3*16 + (lane>>5)*8 + j][e = estep*32 + (lane&31)]  (0 for r>=36)
__global__ __launch_bounds__(256) void kcvt2(const float* __restrict__ img,
                                             ushort_t* __restrict__ dstH) {
    int b = blockIdx.x >> 3, ecg = blockIdx.x & 7;      // e-group: e = ecg*128 .. +127
    __shared__ float S[36][132];
    int t = threadIdx.x;
    for (int i = t; i < 1152; i += 256) {               // img[b][r][e-slice]
        int r = i >> 5, q = i & 31;
        *(float4*)&S[r][q * 4] = *(const float4*)(img + ((size_t)b * 36 + r) * 1024 + ecg * 128 + q * 4);
    }
    __syncthreads();
    int lane = t & 63, grp = t >> 6;
    int m = lane & 31, hi = lane >> 5;
    #pragma unroll
    for (int w2 = 0; w2 < 3; w2++) {
        int item = grp + w2 * 4;            // 0..11 = estepL(4) x ks3(3)
        int estepL = item / 3;
        int ks3 = item - estepL * 3;
        ushort_t hh[8], ll[8];
        #pragma unroll
        for (int j = 0; j < 8; j++) {
            int r = ks3 * 16 + hi * 8 + j;
            float v = (r < 36) ? S[r][estepL * 32 + m] : 0.f;
            hh[j] = bf16_rne(v);
            ll[j] = bf16_rne(v - bf16_f(hh[j]));
        }
        int estep = ecg * 4 + estepL;
        size_t off = ((((size_t)b * 32 + estep) * 3 + ks3) * 64 + lane) * 8;
        uint4 uh, ul;
        uh.x = pack2(hh[0], hh[1]); uh.y = pack2(hh[2], hh[3]);
        uh.z = pack2(hh[4], hh[5]); uh.w = pack2(hh[6], hh[7]);
        ul.x = pack2(ll[0], ll[1]); ul.y = pack2(ll[2], ll[3]);
        ul.z = pack2(ll[4], ll[5]); ul.w = pack2(ll[6], ll[7]);
        *(uint4*)(dstH + off) = uh;
        *(uint4*)(dstH + IMGT2_EL + off) = ul;
    }
}

// ---------------- k2a_mfma v3: attn GEMM + fused leaky-ReLU + per-(row,caption) l2norm ---
// Staging via global_load_lds width=16 (v14, verified). NEW: epilogue applies
// leakyrelu(0.1) then x / (sqrt(sum_l x^2)+EPS) over each caption's 32 cols of a row,
// reduced across the 16 mn-lanes via shfl_xor(1/2/4/8). k2bm then only needs softmax.
// (fp32 fallback path k2a+k2b is unchanged and does its own preproc.)
__global__ __launch_bounds__(256) void k2a_mfma(const ushort_t* __restrict__ cvt,
                                                float* __restrict__ C) {
    const ushort_t* imgH = cvt;
    const ushort_t* imgL = cvt + N_IMG_EL;
    const ushort_t* capH = cvt + 2 * (size_t)N_IMG_EL;
    const ushort_t* capL = capH + N_CAP_EL;
    __shared__ ushort_t Ah[128][32], Al[128][32], Bh[64][32], Bl[64][32];
    int t = threadIdx.x, w = t >> 6, lane = t & 63;
    int quad = lane >> 4, mn = lane & 15;
    int m0 = blockIdx.x * 128, n0 = blockIdx.y * 64;
    float4v acc[2][4];
    #pragma unroll
    for (int i = 0; i < 2; i++)
        #pragma unroll
        for (int j = 0; j < 4; j++) acc[i][j] = (float4v){0.f, 0.f, 0.f, 0.f};

    for (int kc = 0; kc < 32; kc++) {
        #pragma unroll
        for (int j = 0; j < 6; j++) {
            int ch = t + j * 256;                   // 1536 16B chunks; branch is wave-uniform
            const ushort_t* src;
            ushort_t* dst;
            if (ch < 512) {
                int row = ch >> 2, seg = ch & 3;
                src = imgH + (size_t)(m0 + row) * 1024 + kc * 32 + seg * 8;
                dst = &Ah[0][0] + ch * 8;
            } else if (ch < 1024) {
                int r2 = ch - 512, row = r2 >> 2, seg = r2 & 3;
                src = imgL + (size_t)(m0 + row) * 1024 + kc * 32 + seg * 8;
                dst = &Al[0][0] + r2 * 8;
            } else if (ch < 1280) {
                int r2 = ch - 1024, row = r2 >> 2, seg = r2 & 3;
                src = capH + (size_t)(n0 + row) * 1024 + kc * 32 + seg * 8;
                dst = &Bh[0][0] + r2 * 8;
            } else {
                int r2 = ch - 1280, row = r2 >> 2, seg = r2 & 3;
                src = capL + (size_t)(n0 + row) * 1024 + kc * 32 + seg * 8;
                dst = &Bl[0][0] + r2 * 8;
            }
            __builtin_amdgcn_global_load_lds(
                (const __attribute__((address_space(1))) uint*)src,
                (__attribute__((address_space(3))) uint*)dst, 16, 0, 0);
        }
        __syncthreads();
        short8 ah[2], al[2];
        #pragma unroll
        for (int tm = 0; tm < 2; tm++) {
            ah[tm] = *(short8*)&Ah[w * 32 + tm * 16 + mn][quad * 8];
            al[tm] = *(short8*)&Al[w * 32 + tm * 16 + mn][quad * 8];
        }
        #pragma unroll
        for (int nt = 0; nt < 4; nt++) {
            short8 bh = *(short8*)&Bh[nt * 16 + mn][quad * 8];
            short8 bl = *(short8*)&Bl[nt * 16 + mn][quad * 8];
            #pragma unroll
            for (int tm = 0; tm < 2; tm++) {
                acc[tm][nt] = __builtin_amdgcn_mfma_f32_16x16x32_bf16(ah[tm], bh, acc[tm][nt], 0, 0, 0);
                acc[tm][nt] = __builtin_amdgcn_mfma_f32_16x16x32_bf16(ah[tm], bl, acc[tm][nt], 0, 0, 0);
                acc[tm][nt] = __builtin_amdgcn_mfma_f32_16x16x32_bf16(al[tm], bh, acc[tm][nt], 0, 0, 0);
            }
        }
        __syncthreads();
    }
    // epilogue: leaky, then l2norm over cols 0-31 (cap A) and 32-63 (cap B) per row.
    // row = (w,tm,quad,r); its 32 caption-cols live across 16 mn lanes x 2 nt.
    #pragma unroll
    for (int tm = 0; tm < 2; tm++)
        #pragma unroll
        for (int nt = 0; nt < 4; nt++)
            #pragma unroll
            for (int r = 0; r < 4; r++) {
                float v = acc[tm][nt][r];
                acc[tm][nt][r] = (v >= 0.f) ? v : 0.1f * v;
            }
    float invA[2][4], invB[2][4];
    #pragma unroll
    for (int tm = 0; tm < 2; tm++)
        #pragma unroll
        for (int r = 0; r < 4; r++) {
            float ssA = acc[tm][0][r] * acc[tm][0][r] + acc[tm][1][r] * acc[tm][1][r];
            float ssB = acc[tm][2][r] * acc[tm][2][r] + acc[tm][3][r] * acc[tm][3][r];
            #pragma unroll
            for (int off = 1; off < 16; off <<= 1) {
                ssA += __shfl_xor(ssA, off);
                ssB += __shfl_xor(ssB, off);
            }
            invA[tm][r] = 1.f / (sqrtf(ssA) + EPSF);
            invB[tm][r] = 1.f / (sqrtf(ssB) + EPSF);
        }
    #pragma unroll
    for (int tm = 0; tm < 2; tm++)
        #pragma unroll
        for (int nt = 0; nt < 4; nt++)
            #pragma unroll
            for (int r = 0; r < 4; r++) {
                int mrow = m0 + w * 32 + tm * 16 + quad * 4 + r;
                int ncol = n0 + nt * 16 + mn;
                float sc = (nt < 2) ? invA[tm][r] : invB[tm][r];
                C[(size_t)mrow * 2048 + ncol] = acc[tm][nt][r] * sc;
            }
}

// ---------------- kpre: M_X = W_X @ W_gc (512x32); emit bf16 hi/lo planes ----------------
__global__ __launch_bounds__(256) void kpre(const float* __restrict__ Wmu,
                                            const float* __restrict__ Wlv,
                                            const float* __restrict__ W1,
                                            const float* __restrict__ Wgc,
                                            float* __restrict__ ws) {
    int m = blockIdx.x >> 6;            // 0..2
    int hg = blockIdx.x & 63;           // 0..63
    int h0 = hg * 8;
    const float* W = (m == 0) ? Wmu : (m == 1) ? Wlv : W1;
    __shared__ float Gs[64][32];
    __shared__ float Ws[8][68];
    int t = threadIdx.x;
    int h = t >> 5, f = t & 31;
    float acc = 0.f;
    for (int kc = 0; kc < 8; kc++) {
        for (int i = t; i < 512; i += 256) {
            int row = i >> 3, c4 = i & 7;
            *(float4*)&Gs[row][c4 * 4] = *(const float4*)(Wgc + (kc * 64 + row) * 32 + c4 * 4);
        }
        if (t < 128) {
            int hh = t >> 4, c4 = t & 15;
            *(float4*)&Ws[hh][c4 * 4] = *(const float4*)(W + (size_t)(h0 + hh) * 512 + kc * 64 + c4 * 4);
        }
        __syncthreads();
        #pragma unroll 4
        for (int k = 0; k < 64; k++) acc += Ws[h][k] * Gs[k][f];
        __syncthreads();
    }
    ushort_t* Mb = (ushort_t*)ws + m * 32768;       // [hi 16384][lo 16384]
    ushort_t hi = bf16_rne(acc);
    ushort_t lo = bf16_rne(acc - bf16_f(hi));
    Mb[(h0 + h) * 32 + f] = hi;
    Mb[16384 + (h0 + h) * 32 + f] = lo;
}

// ---------------- k1: per caption: words_sim -> adj -> s[c][l] ; + qn[c][l][f] ----------------
__global__ __launch_bounds__(256) void k1(const float* __restrict__ captions,
                                          const int* __restrict__ depends,
                                          float* __restrict__ ws) {
    int c = blockIdx.x;
    __shared__ float caps[32][65];
    __shared__ float G[32][33];
    __shared__ float adj[32][33];
    int t = threadIdx.x;
    int l2 = t & 31, l1_0 = t >> 5;
    float acc[4] = {0.f, 0.f, 0.f, 0.f};
    const float* cap = captions + (size_t)c * 32 * 1024;

    for (int kc = 0; kc < 16; kc++) {
        for (int i = t; i < 512; i += 256) {
            int ll = i >> 4, q = i & 15;
            float4 v = *(const float4*)(cap + ll * 1024 + kc * 64 + q * 4);
            caps[ll][q * 4 + 0] = v.x; caps[ll][q * 4 + 1] = v.y;
            caps[ll][q * 4 + 2] = v.z; caps[ll][q * 4 + 3] = v.w;
        }
        __syncthreads();
        #pragma unroll 4
        for (int k = 0; k < 64; k++) {
            float cv = caps[l2][k];
            #pragma unroll
            for (int i = 0; i < 4; i++) acc[i] += caps[l1_0 + 8 * i][k] * cv;
        }
        __syncthreads();
    }
    #pragma unroll
    for (int i = 0; i < 4; i++) G[l1_0 + 8 * i][l2] = acc[i];
    for (int i = t; i < 32 * 33; i += 256) ((float*)adj)[i] = 0.f;
    __syncthreads();

    if (t < 32) {
        float mx = -1e30f;
        for (int n = 0; n < 32; n++) mx = fmaxf(mx, LAM * G[t][n]);
        float sum = 0.f;
        for (int n = 0; n < 32; n++) { float p = __expf(LAM * G[t][n] - mx); G[t][n] = p; sum += p; }
        float inv = 1.f / sum;
        for (int n = 0; n < 32; n++) G[t][n] *= inv;
    }
    __syncthreads();
    if (t >= 1 && t < 30) {
        int d0 = depends[c * 60 + t * 2 + 0];
        int d1 = depends[c * 60 + t * 2 + 1];
        adj[d0][d1] = 1.f;
        adj[d1][d0] = 1.f;
    }
    __syncthreads();
    if (t < 32) adj[t][t] += 1.f;
    __syncthreads();
    if (t < 32) {
        float ss = 0.f, sw = 0.f;
        for (int n = 0; n < 32; n++) { float mm = adj[t][n] * G[t][n]; ss += mm * mm; }
        float inv = 1.f / (sqrtf(ss) + EPSF);
        for (int n = 0; n < 32; n++) sw += adj[t][n] * G[t][n] * adj[t][n];
        ws[OFF_S + c * 32 + t] = sw * inv;
    }
    for (int p = t; p < 1024; p += 256) {
        int l = p >> 5, f = p & 31;
        const float* cp = cap + (size_t)l * 1024 + f * 32;
        float q2 = 0.f;
        #pragma unroll
        for (int q = 0; q < 8; q++) {
            float4 v = *(const float4*)(cp + q * 4);
            q2 += v.x * v.x + v.y * v.y + v.z * v.z + v.w * v.w;
        }
        ws[OFF_QN + c * 1024 + p] = sqrtf(q2);
    }
}

// ---------------- k2a (fp32 fallback) ----------------
__global__ __launch_bounds__(256) void k2a(const float* __restrict__ A,
                                           const float* __restrict__ Bm,
                                           float* __restrict__ C,
                                           int n0, int NW) {
    __shared__ float As[16][132];
    __shared__ float Bs[16][68];
    int m0 = blockIdx.x * 128;
    int nb0 = n0 + blockIdx.y * 64;
    int t = threadIdx.x;
    int tm = t >> 4, tn = t & 15;
    float acc[8][4] = {};
    for (int kc = 0; kc < 64; kc++) {
        #pragma unroll
        for (int j = 0; j < 2; j++) {
            int idx = t + j * 256;
            int row = idx >> 2, kq = idx & 3;
            float4 v = *(const float4*)(A + (size_t)(m0 + row) * 1024 + kc * 16 + kq * 4);
            As[kq * 4 + 0][row] = v.x; As[kq * 4 + 1][row] = v.y;
            As[kq * 4 + 2][row] = v.z; As[kq * 4 + 3][row] = v.w;
        }
        {
            int row = t >> 2, kq = t & 3;
            float4 v = *(const float4*)(Bm + (size_t)(nb0 + row) * 1024 + kc * 16 + kq * 4);
            Bs[kq * 4 + 0][row] = v.x; Bs[kq * 4 + 1][row] = v.y;
            Bs[kq * 4 + 2][row] = v.z; Bs[kq * 4 + 3][row] = v.w;
        }
        __syncthreads();
        #pragma unroll
        for (int kk = 0; kk < 16; kk++) {
            float a0[4], a1[4], bb[4];
            *(float4*)a0 = *(float4*)&As[kk][tm * 8];
            *(float4*)a1 = *(float4*)&As[kk][tm * 8 + 4];
            *(float4*)bb = *(float4*)&Bs[kk][tn * 4];
            #pragma unroll
            for (int i = 0; i < 4; i++)
                #pragma unroll
                for (int j2 = 0; j2 < 4; j2++) {
                    acc[i][j2]     += a0[i] * bb[j2];
                    acc[i + 4][j2] += a1[i] * bb[j2];
                }
        }
        __syncthreads();
    }
    int cw0 = nb0 - n0 + tn * 4;
    #pragma unroll
    for (int i = 0; i < 8; i++) {
        float4 v = make_float4(acc[i][0], acc[i][1], acc[i][2], acc[i][3]);
        *(float4*)(C + (size_t)(m0 + tm * 8 + i) * NW + cw0) = v;
    }
}

// ---------------- k2bm v15: C=4 captions, B=2 b's, H=4 f-quarters; LDS-free softmax ------
// attn arrives pre-leaky+l2norm'd (k2a_mfma epilogue). Lane (l,hi) loads only the rows its
// B-frag needs (hi=0: {0-7,16-23,32-35}, hi=1: {8-15,24-31}; union = 0..35) and computes
// softmax in-register, combining max/sum via shfl_xor(32). No attn LDS, one barrier total.
// Demand: imgT 200MB (halved by C=4) + captions 268MB + attn 75MB = 543MB (vs 707 in v13).
// Grid stays 2048 = (fq 4)x(cg 16)x(bp 32); XCD = bp%8 keeps imgT L2-grouped.
__global__ __launch_bounds__(64) void k2bm(const ushort_t* __restrict__ imgT,
                                           const float* __restrict__ captions,
                                           const float* __restrict__ attn,
                                           const float* __restrict__ ws,
                                           float* __restrict__ ts_out) {
    int orig = blockIdx.x;
    int fq = orig >> 9;                         // 0..3 : f in [fq*8, fq*8+8)
    int cg = (orig >> 5) & 15;                  // 0..15 : captions c0..c0+3
    int bp = orig & 31;                         // XCD = bp%8
    int b0 = bp * 2, c0 = cg * 4;
    __shared__ float T[2][4][8][33];            // [bi][ci][fl][l]
    int t = threadIdx.x, l = t & 31, hi = t >> 5;

    // --- B-frags with in-register softmax over regions ---
    short8 bh[2][4][3], bl[2][4][3];
    #pragma unroll
    for (int bi = 0; bi < 2; bi++)
        #pragma unroll
        for (int ci = 0; ci < 4; ci++) {
            const float* ap = attn + ((size_t)(b0 + bi) * 36) * 2048 + (c0 + ci) * 32 + l;
            float av[3][8];
            float mx = -1e30f;
            #pragma unroll
            for (int k3 = 0; k3 < 3; k3++)
                #pragma unroll
                for (int j = 0; j < 8; j++) {
                    int r = k3 * 16 + hi * 8 + j;
                    float v = (r < 36) ? ap[(size_t)r * 2048] : -1e30f;
                    av[k3][j] = v;
                    mx = fmaxf(mx, v);
                }
            mx = fmaxf(mx, __shfl_xor(mx, 32)) * LAM;
            float sum = 0.f;
            #pragma unroll
            for (int k3 = 0; k3 < 3; k3++)
                #pragma unroll
                for (int j = 0; j < 8; j++) {
                    int r = k3 * 16 + hi * 8 + j;
                    float p = (r < 36) ? __expf(LAM * av[k3][j] - mx) : 0.f;
                    av[k3][j] = p;
                    sum += p;
                }
            sum += __shfl_xor(sum, 32);
            float inv = 1.f / sum;
            #pragma unroll
            for (int k3 = 0; k3 < 3; k3++) {
                union { short8 v; ushort_t u8[8]; } H, L;
                #pragma unroll
                for (int j = 0; j < 8; j++) {
                    float p = av[k3][j] * inv;
                    ushort_t hv = bf16_rne(p);
                    H.u8[j] = hv;
                    L.u8[j] = bf16_rne(p - bf16_f(hv));
                }
                bh[bi][ci][k3] = H.v;
                bl[bi][ci][k3] = L.v;
            }
        }

    const ushort_t* ibH0 = imgT + (size_t)b0 * 49152;   // ((f*3 + k3)*64 + lane)*8
    const ushort_t* ibL0 = ibH0 + IMGT2_EL;
    const ushort_t* ibH1 = ibH0 + 49152;
    const ushort_t* ibL1 = ibL0 + 49152;
    const float* qnp = ws + OFF_QN;
    float sv[4];
    #pragma unroll
    for (int ci = 0; ci < 4; ci++) sv[ci] = ws[OFF_S + (c0 + ci) * 32 + l];

    for (int fl = 0; fl < 8; fl++) {
        int f = fq * 8 + fl;
        // A-frags for BOTH b's (imgT; shared across the 4 captions)
        short8 aH0[3], aL0[3], aH1[3], aL1[3];
        #pragma unroll
        for (int k3 = 0; k3 < 3; k3++) {
            size_t off = ((size_t)(f * 3 + k3) * 64 + t) * 8;
            aH0[k3] = *(const short8*)(ibH0 + off);
            aL0[k3] = *(const short8*)(ibL0 + off);
            aH1[k3] = *(const short8*)(ibH1 + off);
            aL1[k3] = *(const short8*)(ibL1 + off);
        }
        #pragma unroll
        for (int ci = 0; ci < 4; ci++) {
            float4 cv[4];
            #pragma unroll
            for (int g = 0; g < 4; g++)
                cv[g] = *(const float4*)(captions + (size_t)(c0 + ci) * 32768
                         + (size_t)l * 1024 + f * 32 + g * 8 + hi * 4);
            f32x16 accA = {0.f,0.f,0.f,0.f,0.f,0.f,0.f,0.f,0.f,0.f,0.f,0.f,0.f,0.f,0.f,0.f};
            f32x16 accB = {0.f,0.f,0.f,0.f,0.f,0.f,0.f,0.f,0.f,0.f,0.f,0.f,0.f,0.f,0.f,0.f};
            #pragma unroll
            for (int k3 = 0; k3 < 3; k3++) {
                accA = __builtin_amdgcn_mfma_f32_32x32x16_bf16(aH0[k3], bh[0][ci][k3], accA, 0, 0, 0);
                accA = __builtin_amdgcn_mfma_f32_32x32x16_bf16(aH0[k3], bl[0][ci][k3], accA, 0, 0, 0);
                accA = __builtin_amdgcn_mfma_f32_32x32x16_bf16(aL0[k3], bh[0][ci][k3], accA, 0, 0, 0);
                accB = __builtin_amdgcn_mfma_f32_32x32x16_bf16(aH1[k3], bh[1][ci][k3], accB, 0, 0, 0);
                accB = __builtin_amdgcn_mfma_f32_32x32x16_bf16(aH1[k3], bl[1][ci][k3], accB, 0, 0, 0);
                accB = __builtin_amdgcn_mfma_f32_32x32x16_bf16(aL1[k3], bh[1][ci][k3], accB, 0, 0, 0);
            }
            // lane holds wctxT[e_loc=(reg&3)+8*(reg>>2)+4*hi][l]; cv[g] covers e_loc=g*8+4*hi+0..3
            float numA = 0.f, w2A = 0.f, numB = 0.f, w2B = 0.f;
            #pragma unroll
            for (int g = 0; g < 4; g++) {
                numA += cv[g].x * accA[g*4+0] + cv[g].y * accA[g*4+1]
                      + cv[g].z * accA[g*4+2] + cv[g].w * accA[g*4+3];
                w2A  += accA[g*4+0]*accA[g*4+0] + accA[g*4+1]*accA[g*4+1]
                      + accA[g*4+2]*accA[g*4+2] + accA[g*4+3]*accA[g*4+3];
                numB += cv[g].x * accB[g*4+0] + cv[g].y * accB[g*4+1]
                      + cv[g].z * accB[g*4+2] + cv[g].w * accB[g*4+3];
                w2B  += accB[g*4+0]*accB[g*4+0] + accB[g*4+1]*accB[g*4+1]
                      + accB[g*4+2]*accB[g*4+2] + accB[g*4+3]*accB[g*4+3];
            }
            numA += __shfl_xor(numA, 32); w2A += __shfl_xor(w2A, 32);
            numB += __shfl_xor(numB, 32); w2B += __shfl_xor(w2B, 32);
            if (hi == 0) {
                float qv = qnp[(c0 + ci) * 1024 + l * 32 + f];   // b-independent
                float denA = fmaxf(qv * sqrtf(w2A), EPSF);
                T[0][ci][fl][l] = (numA / denA) * sv[ci];
                float denB = fmaxf(qv * sqrtf(w2B), EPSF);
                T[1][ci][fl][l] = (numB / denB) * sv[ci];
            }
        }
    }
    __syncthreads();
    // burst: 2b x 4ci x 32l x 8f floats = 512 float4 items -> ts_out
    #pragma unroll
    for (int j = 0; j < 8; j++) {
        int id = t + j * 64;                    // 0..511
        int bi = id >> 8;
        int ci = (id >> 6) & 3;
        int rem = id & 63;
        int ll = rem >> 1, q = rem & 1;         // q*4 in [0,8)
        float4 v;
        v.x = T[bi][ci][q * 4 + 0][ll];
        v.y = T[bi][ci][q * 4 + 1][ll];
        v.z = T[bi][ci][q * 4 + 2][ll];
        v.w = T[bi][ci][q * 4 + 3][ll];
        *(float4*)(ts_out + ((size_t)(c0 + ci) * 64 + b0 + bi) * 1024 + ll * 32 + fq * 8 + q * 4) = v;
    }
}

// ---------------- k2b (fp32 fallback, validated R4 version) ----------------
__global__ __launch_bounds__(256) void k2b(const float* __restrict__ images,
                                           const float* __restrict__ captions,
                                           const float* __restrict__ attn,
                                           const float* __restrict__ ws,
                                           float* __restrict__ ts_out,
                                           int c0, int NW) {
    int b = blockIdx.x;
    int cw = blockIdx.y;
    int ca = c0 + cw * 2;
    __shared__ float A2[2][36][36];
    __shared__ float Ims[36][256];
    __shared__ float scs[2][32];
    const float* img = images + (size_t)b * 36 * 1024;
    int t = threadIdx.x;
    int el = t & 63;
    int lg = t >> 6;

    for (int i = t; i < 576; i += 256) {
        int r = i >> 4, q = i & 15;
        float4 v = *(const float4*)(attn + (size_t)(b * 36 + r) * NW + cw * 64 + q * 4);
        *(float4*)&A2[q >> 3][r][(q & 7) * 4] = v;
    }
    __syncthreads();
    if (t < 72) {
        int ci = t >= 36, r = t - 36 * ci;
        float ss = 0.f;
        #pragma unroll
        for (int l = 0; l < 32; l++) {
            float v = A2[ci][r][l];
            v = (v >= 0.f) ? v : 0.1f * v;
            A2[ci][r][l] = v; ss += v * v;
        }
        float inv = 1.f / (sqrtf(ss) + EPSF);
        #pragma unroll
        for (int l = 0; l < 32; l++) A2[ci][r][l] *= inv;
    }
    __syncthreads();
    if (t < 64) {
        int ci = t >> 5, l = t & 31;
        float mx = -1e30f;
        for (int r = 0; r < 36; r++) mx = fmaxf(mx, A2[ci][r][l]);
        mx *= LAM;
        float sum = 0.f;
        for (int r = 0; r < 36; r++) { float p = __expf(LAM * A2[ci][r][l] - mx); A2[ci][r][l] = p; sum += p; }
        float inv = 1.f / sum;
        for (int r = 0; r < 36; r++) A2[ci][r][l] *= inv;
    } else if (t >= 128 && t < 192) {
        int i = t - 128;
        scs[i >> 5][i & 31] = ws[OFF_S + (ca + (i >> 5)) * 32 + (i & 31)];
    }
    __syncthreads();

    const float* qn = ws + OFF_QN;
    for (int g = 0; g < 4; g++) {
        for (int i = t; i < 2304; i += 256) {
            int r = i >> 6, q = i & 63;
            *(float4*)&Ims[r][q * 4] = *(const float4*)(img + (size_t)r * 1024 + g * 256 + q * 4);
        }
        __syncthreads();

        float acc[2][8][4] = {};
        #pragma unroll 2
        for (int r = 0; r < 36; r++) {
            float4 iv = *(float4*)&Ims[r][el * 4];
            float ivv[4] = {iv.x, iv.y, iv.z, iv.w};
            #pragma unroll
            for (int ci = 0; ci < 2; ci++) {
                float av[8];
                *(float4*)&av[0] = *(float4*)&A2[ci][r][lg * 8];
                *(float4*)&av[4] = *(float4*)&A2[ci][r][lg * 8 + 4];
                #pragma unroll
                for (int i = 0; i < 8; i++)
                    #pragma unroll
                    for (int e = 0; e < 4; e++)
                        acc[ci][i][e] += av[i] * ivv[e];
            }
        }

        int fb = el >> 3;
        int f = g * 8 + fb;
        #pragma unroll
        for (int ci = 0; ci < 2; ci++) {
            int c = ca + ci;
            const float* cap = captions + (size_t)c * 32 * 1024 + g * 256;
            #pragma unroll
            for (int i = 0; i < 8; i++) {
                int l = lg * 8 + i;
                float4 cv = *(const float4*)(cap + (size_t)l * 1024 + el * 4);
                float num = cv.x * acc[ci][i][0] + cv.y * acc[ci][i][1]
                          + cv.z * acc[ci][i][2] + cv.w * acc[ci][i][3];
                float w2 = acc[ci][i][0] * acc[ci][i][0] + acc[ci][i][1] * acc[ci][i][1]
                         + acc[ci][i][2] * acc[ci][i][2] + acc[ci][i][3] * acc[ci][i][3];
                num += __shfl_down(num, 4); w2 += __shfl_down(w2, 4);
                num += __shfl_down(num, 2); w2 += __shfl_down(w2, 2);
                num += __shfl_down(num, 1); w2 += __shfl_down(w2, 1);
                if ((el & 7) == 0) {
                    float den = fmaxf(qn[c * 1024 + l * 32 + f] * sqrtf(w2), EPSF);
                    ts_out[(((size_t)c * 64 + b) * 32 + l) * 32 + f] = (num / den) * scs[ci][l];
                }
            }
        }
        __syncthreads();
    }
}

// ---------------- k3 (MFMA): similarities[b][c] = mean_l W2·tanh(ts@M1^T + b1) + b2 ----------------
__global__ __launch_bounds__(256) void k3(const float* __restrict__ ts_ws,
                                          const ushort_t* __restrict__ Mb,
                                          const float* __restrict__ b1,
                                          const float* __restrict__ W2,
                                          const float* __restrict__ b2,
                                          float* __restrict__ out_sim) {
    int c = blockIdx.x >> 6, b = blockIdx.x & 63;
    __shared__ ushort_t tsh[32][32], tsl[32][32];
    __shared__ float red[4];
    int t = threadIdx.x;
    const float* tsrc = ts_ws + (size_t)(c * 64 + b) * 1024;
    {
        int row = t >> 3, q = t & 7;
        float4 v = *(const float4*)(tsrc + row * 32 + q * 4);
        float x[4] = {v.x, v.y, v.z, v.w};
        ushort_t hh[4], ll[4];
        #pragma unroll
        for (int j = 0; j < 4; j++) {
            hh[j] = bf16_rne(x[j]);
            ll[j] = bf16_rne(x[j] - bf16_f(hh[j]));
        }
        *(uint2*)&tsh[row][q * 4] = make_uint2(pack2(hh[0], hh[1]), pack2(hh[2], hh[3]));
        *(uint2*)&tsl[row][q * 4] = make_uint2(pack2(ll[0], ll[1]), pack2(ll[2], ll[3]));
    }
    __syncthreads();
    int w = t >> 6, lane = t & 63, quad = lane >> 4, mn = lane & 15;
    const ushort_t* M1H = Mb + 65536;
    short8 ah[2], al[2];
    #pragma unroll
    for (int mt = 0; mt < 2; mt++) {
        ah[mt] = *(short8*)&tsh[mt * 16 + mn][quad * 8];
        al[mt] = *(short8*)&tsl[mt * 16 + mn][quad * 8];
    }
    float psum = 0.f;
    #pragma unroll
    for (int nt = 0; nt < 8; nt++) {
        int h = w * 128 + nt * 16 + mn;
        short8 bh = *(const short8*)(M1H + h * 32 + quad * 8);
        short8 bl = *(const short8*)(M1H + 16384 + h * 32 + quad * 8);
        float b1v = b1[h], w2v = W2[h];
        #pragma unroll
        for (int mt = 0; mt < 2; mt++) {
            float4v acc = (float4v){0.f, 0.f, 0.f, 0.f};
            acc = __builtin_amdgcn_mfma_f32_16x16x32_bf16(ah[mt], bh, acc, 0, 0, 0);
            acc = __builtin_amdgcn_mfma_f32_16x16x32_bf16(ah[mt], bl, acc, 0, 0, 0);
            acc = __builtin_amdgcn_mfma_f32_16x16x32_bf16(al[mt], bh, acc, 0, 0, 0);
            #pragma unroll
            for (int r = 0; r < 4; r++) {
                float x = fminf(fmaxf(acc[r] + b1v, -15.f), 15.f);
                float e2 = __expf(2.f * x);
                psum += (1.f - 2.f / (e2 + 1.f)) * w2v;
            }
        }
    }
    #pragma unroll
    for (int off = 32; off >= 1; off >>= 1) psum += __shfl_down(psum, off);
    if (lane == 0) red[w] = psum;
    __syncthreads();
    if (t == 0) out_sim[b * 64 + c] = b2[0] + (red[0] + red[1] + red[2] + red[3]) * (1.f / 32.f);
}

// ---------------- k4: w[b][c] = softmax over c ----------------
__global__ __launch_bounds__(64) void k4(const float* __restrict__ sim, float* __restrict__ w_ws) {
    int b = blockIdx.x, t = threadIdx.x;
    float v = sim[b * 64 + t];
    float mx = v;
    #pragma unroll
    for (int off = 32; off >= 1; off >>= 1) mx = fmaxf(mx, __shfl_xor(mx, off));
    float p = __expf(v - mx);
    float sum = p;
    #pragma unroll
    for (int off = 32; off >= 1; off >>= 1) sum += __shfl_xor(sum, off);
    w_ws[b * 64 + t] = p / sum;
}

// ---------------- k5 (MFMA): mu_word / sigma_word; block per (b,l), 256 threads ----------------
__global__ __launch_bounds__(256) void k5(const float* __restrict__ ts_ws,
                                          const float* __restrict__ ws,
                                          const float* __restrict__ b_mu,
                                          const float* __restrict__ b_lv,
                                          float* __restrict__ out) {
    int b = blockIdx.x >> 5, l = blockIdx.x & 31;
    int t = threadIdx.x;
    __shared__ ushort_t tsh[64][32], tsl[64][32];
    __shared__ float wls[64];
    {
        int cc = t >> 2, q = t & 3;
        const float* src = ts_ws + (((size_t)cc * 64 + b) * 32 + l) * 32 + q * 8;
        #pragma unroll
        for (int half = 0; half < 2; half++) {
            float4 v = *(const float4*)(src + half * 4);
            float x[4] = {v.x, v.y, v.z, v.w};
            ushort_t hh[4], ll[4];
            #pragma unroll
            for (int j = 0; j < 4; j++) {
                hh[j] = bf16_rne(x[j]);
                ll[j] = bf16_rne(x[j] - bf16_f(hh[j]));
            }
            *(uint2*)&tsh[cc][q * 8 + half * 4] = make_uint2(pack2(hh[0], hh[1]), pack2(hh[2], hh[3]));
            *(uint2*)&tsl[cc][q * 8 + half * 4] = make_uint2(pack2(ll[0], ll[1]), pack2(ll[2], ll[3]));
        }
    }
    if (t < 64) wls[t] = ws[OFF_W + b * 64 + t];
    __syncthreads();

    int w = t >> 6, lane = t & 63, quad = lane >> 4, mn = lane & 15;
    const ushort_t* Mb = (const ushort_t*)ws;
    const ushort_t* MmuH = Mb;
    const ushort_t* MlvH = Mb + 32768;
    short8 ah[4], al[4];
    #pragma unroll
    for (int mt = 0; mt < 4; mt++) {
        ah[mt] = *(short8*)&tsh[mt * 16 + mn][quad * 8];
        al[mt] = *(short8*)&tsl[mt * 16 + mn][quad * 8];
    }
    float pm[8], pq[8], pe[8];
    #pragma unroll
    for (int nt = 0; nt < 8; nt++) {
        int h = w * 128 + nt * 16 + mn;
        {
            short8 bh = *(const short8*)(MmuH + h * 32 + quad * 8);
            short8 bl = *(const short8*)(MmuH + 16384 + h * 32 + quad * 8);
            float bmv = b_mu[h];
            float am = 0.f, aq = 0.f;
            #pragma unroll
            for (int mt = 0; mt < 4; mt++) {
                float4v acc = (float4v){0.f, 0.f, 0.f, 0.f};
                acc = __builtin_amdgcn_mfma_f32_16x16x32_bf16(ah[mt], bh, acc, 0, 0, 0);
                acc = __builtin_amdgcn_mfma_f32_16x16x32_bf16(ah[mt], bl, acc, 0, 0, 0);
                acc = __builtin_amdgcn_mfma_f32_16x16x32_bf16(al[mt], bh, acc, 0, 0, 0);
                #pragma unroll
                for (int r = 0; r < 4; r++) {
                    int cc = mt * 16 + quad * 4 + r;
                    float mu = acc[r] + bmv;
                    float wv = wls[cc];
                    am += wv * mu;
                    aq += wv * mu * mu;
                }
            }
            am += __shfl_xor(am, 16); am += __shfl_xor(am, 32);
            aq += __shfl_xor(aq, 16); aq += __shfl_xor(aq, 32);
            pm[nt] = am; pq[nt] = aq;
        }
        {
            short8 bh = *(const short8*)(MlvH + h * 32 + quad * 8);
            short8 bl = *(const short8*)(MlvH + 16384 + h * 32 + quad * 8);
            float blv = b_lv[h];
            float ae = 0.f;
            #pragma unroll
            for (int mt = 0; mt < 4; mt++) {
                float4v acc = (float4v){0.f, 0.f, 0.f, 0.f};
                acc = __builtin_amdgcn_mfma_f32_16x16x32_bf16(ah[mt], bh, acc, 0, 0, 0);
                acc = __builtin_amdgcn_mfma_f32_16x16x32_bf16(ah[mt], bl, acc, 0, 0, 0);
                acc = __builtin_amdgcn_mfma_f32_16x16x32_bf16(al[mt], bh, acc, 0, 0, 0);
                #pragma unroll
                for (int r = 0; r < 4; r++) {
                    int cc = mt * 16 + quad * 4 + r;
                    ae += wls[cc] * __expf(acc[r] + blv);
                }
            }
            ae += __shfl_xor(ae, 16); ae += __shfl_xor(ae, 32);
            pe[nt] = ae;
        }
    }
    if (quad == 0) {
        #pragma unroll
        for (int nt = 0; nt < 8; nt++) {
            int h = w * 128 + nt * 16 + mn;
            size_t idx = (size_t)(b * 32 + l) * 512 + h;
            float m = pm[nt];
            out[4096 + idx] = m;
            float var = pe[nt] + pq[nt] - m * m;
            out[4096 + 64 * 32 * 512 + idx] = sqrtf(fmaxf(var, 1e-8f));
        }
    }
}

extern "C" void kernel_launch(void* const* d_in, const int* in_sizes, int n_in,
                              void* d_out, int out_size, void* d_ws, size_t ws_size,
                              hipStream_t stream) {
    const float* images   = (const float*)d_in[0];
    const float* captions = (const float*)d_in[1];
    const int*   depends  = (const int*)d_in[2];
    const float* Wgc = (const float*)d_in[3];
    const float* Wmu = (const float*)d_in[4];
    const float* bmu = (const float*)d_in[5];
    const float* Wlv = (const float*)d_in[6];
    const float* blv = (const float*)d_in[7];
    const float* W1  = (const float*)d_in[8];
    const float* b1  = (const float*)d_in[9];
    const float* W2  = (const float*)d_in[10];
    const float* b2  = (const float*)d_in[11];
    float* out = (float*)d_out;
    float* ws  = (float*)d_ws;

    hipLaunchKernelGGL(kpre, dim3(192), dim3(256), 0, stream, Wmu, Wlv, W1, Wgc, ws);
    hipLaunchKernelGGL(k1, dim3(64), dim3(256), 0, stream, captions, depends, ws);

    const size_t CVT_FLOATS = ((size_t)2 * N_IMG_EL + 2 * N_CAP_EL) / 2;
    size_t need_floats = (size_t)OFF_CVT + CVT_FLOATS;
    bool use_mfma = ws_size >= need_floats * 4;

    if (use_mfma) {
        ushort_t* cvt = (ushort_t*)(ws + OFF_CVT);
        hipLaunchKernelGGL(kcvt, dim3((N_IMG_EL + N_CAP_EL) / 4 / 256), dim3(256), 0, stream,
                           images, captions, cvt);
        hipLaunchKernelGGL(k2a_mfma, dim3(18, 32), dim3(256), 0, stream, cvt, ws + OFF_ATTN);
        // CVT region dead after k2a_mfma; reuse for 32x32x16-frag imgT2 hi/lo (12.6MB <= 17.8MB)
        hipLaunchKernelGGL(kcvt2, dim3(512), dim3(256), 0, stream, images, cvt);
        hipLaunchKernelGGL(k2bm, dim3(2048), dim3(64), 0, stream,
                           cvt, captions, ws + OFF_ATTN, ws, ws + OFF_TS);
    } else {
        int NW = 2048;
        while (NW > 64 && ((size_t)OFF_ATTN + (size_t)2304 * NW) * 4 > ws_size) NW >>= 1;
        for (int n0 = 0; n0 < 2048; n0 += NW) {
            hipLaunchKernelGGL(k2a, dim3(18, NW / 64), dim3(256), 0, stream,
                               images, captions, ws + OFF_ATTN, n0, NW);
            hipLaunchKernelGGL(k2b, dim3(64, NW / 64), dim3(256), 0, stream,
                               images, captions, ws + OFF_ATTN, ws, ws + OFF_TS, n0 / 32, NW);
        }
    }

    hipLaunchKernelGGL(k3, dim3(4096), dim3(256), 0, stream,
                       ws + OFF_TS, (const ushort_t*)ws, b1, W2, b2, out);
    hipLaunchKernelGGL(k4, dim3(64), dim3(64), 0, stream, out, ws + OFF_W);
    hipLaunchKernelGGL(k5, dim3(2048), dim3(256), 0, stream, ws + OFF_TS, ws, bmu, blv, out);
}

// Round 11
// 349.361 us; speedup vs baseline: 1.1746x; 1.1746x over previous
//
#include <hip/hip_runtime.h>
#include <math.h>

#define LAM 9.0f
#define EPSF 1e-8f

typedef unsigned int uint;
typedef unsigned short ushort_t;
typedef __attribute__((ext_vector_type(8))) short short8;
typedef __attribute__((ext_vector_type(4))) float float4v;
typedef __attribute__((ext_vector_type(16))) float f32x16;

// ws layout (floats)
#define OFF_MMU 0                       // ushort planes: [hi 16384][lo 16384] per matrix
#define OFF_MLV (512*32)
#define OFF_M1  (2*512*32)
#define OFF_S   (3*512*32)              // 49152 : s[c][l] (64*32)
#define OFF_W   (OFF_S + 64*32)         // 51200 : w[b][c] (64*64)
#define OFF_QN  (OFF_W + 64*64)         // 55296 : qn[c][l][f] (64*32*32)
#define OFF_TS  (OFF_QN + 64*32*32)     // 120832: tnode_s[c][b][l][f] (64*64*32*32)
#define OFF_ATTN (OFF_TS + 64*64*32*32) // attn [2304][NW]
#define OFF_CVT  (OFF_ATTN + 2304*2048) // hi/lo bf16 arrays (ushort); REUSED by imgT2 after k2a

#define N_IMG_EL 2359296                // 2304*1024
#define N_CAP_EL 2097152                // 2048*1024
// imgT2 per plane (ushorts), 32x32x16-A-frag order: 64b * 32estep * 3kstep * 64lane * 8
#define IMGT2_EL 3145728

__device__ __forceinline__ ushort_t bf16_rne(float x) {
    uint u = __float_as_uint(x);
    uint r = (u + 0x7fffu + ((u >> 16) & 1u)) >> 16;
    return (ushort_t)r;
}
__device__ __forceinline__ float bf16_f(ushort_t h) {
    return __uint_as_float(((uint)h) << 16);
}
__device__ __forceinline__ uint pack2(ushort_t a, ushort_t b) {
    return (uint)a | ((uint)b << 16);
}

// ---------------- kcvt: split images+captions into hi/lo bf16 (Markidis) ----------------
__global__ __launch_bounds__(256) void kcvt(const float* __restrict__ img,
                                            const float* __restrict__ cap,
                                            ushort_t* __restrict__ dst) {
    size_t i = (size_t)blockIdx.x * 256 + threadIdx.x;   // float4 index
    const float* src;
    ushort_t *H, *L;
    size_t base;
    if (i < (N_IMG_EL / 4)) {
        src = img; H = dst; L = dst + N_IMG_EL; base = i * 4;
    } else {
        src = cap; H = dst + 2 * (size_t)N_IMG_EL; L = H + N_CAP_EL; base = (i - N_IMG_EL / 4) * 4;
    }
    float4 v = *(const float4*)(src + base);
    float x[4] = {v.x, v.y, v.z, v.w};
    ushort_t hh[4], ll[4];
    #pragma unroll
    for (int j = 0; j < 4; j++) {
        hh[j] = bf16_rne(x[j]);
        ll[j] = bf16_rne(x[j] - bf16_f(hh[j]));
    }
    *(uint2*)(H + base) = make_uint2(pack2(hh[0], hh[1]), pack2(hh[2], hh[3]));
    *(uint2*)(L + base) = make_uint2(pack2(ll[0], ll[1]), pack2(ll[2], ll[3]));
}

// ---------------- kcvt2 v2: build imgT2 in 32x32x16 MFMA A-fragment order, hi/lo ----------
// A[m=e_loc][k=r]: lane holds m = lane&31, k-slice = (lane>>5)*8 + j (per kstep of 16).
// layout: plane*IMGT2_EL + (((b*32 + estep)*3 + ks3)*64 + lane)*8
// elem j = img[b][r = ks3*16 + (lane>>5)*8 + j][e = estep*32 + (lane&31)]  (0 for r>=36)
__global__ __launch_bounds__(256) void kcvt2(const float* __restrict__ img,
                                             ushort_t* __restrict__ dstH) {
    int b = blockIdx.x >> 3, ecg = blockIdx.x & 7;      // e-group: e = ecg*128 .. +127
    __shared__ float S[36][132];
    int t = threadIdx.x;
    for (int i = t; i < 1152; i += 256) {               // img[b][r][e-slice]
        int r = i >> 5, q = i & 31;
        *(float4*)&S[r][q * 4] = *(const float4*)(img + ((size_t)b * 36 + r) * 1024 + ecg * 128 + q * 4);
    }
    __syncthreads();
    int lane = t & 63, grp = t >> 6;
    int m = lane & 31, hi = lane >> 5;
    #pragma unroll
    for (int w2 = 0; w2 < 3; w2++) {
        int item = grp + w2 * 4;            // 0..11 = estepL(4) x ks3(3)
        int estepL = item / 3;
        int ks3 = item - estepL * 3;
        ushort_t hh[8], ll[8];
        #pragma unroll
        for (int j = 0; j < 8; j++) {
            int r = ks3 * 16 + hi * 8 + j;
            float v = (r < 36) ? S[r][estepL * 32 + m] : 0.f;
            hh[j] = bf16_rne(v);
            ll[j] = bf16_rne(v - bf16_f(hh[j]));
        }
        int estep = ecg * 4 + estepL;
        size_t off = ((((size_t)b * 32 + estep) * 3 + ks3) * 64 + lane) * 8;
        uint4 uh, ul;
        uh.x = pack2(hh[0], hh[1]); uh.y = pack2(hh[2], hh[3]);
        uh.z = pack2(hh[4], hh[5]); uh.w = pack2(hh[6], hh[7]);
        ul.x = pack2(ll[0], ll[1]); ul.y = pack2(ll[2], ll[3]);
        ul.z = pack2(ll[4], ll[5]); ul.w = pack2(ll[6], ll[7]);
        *(uint4*)(dstH + off) = uh;
        *(uint4*)(dstH + IMGT2_EL + off) = ul;
    }
}

// ---------------- k2a_mfma v3: attn GEMM + fused leaky-ReLU + per-(row,caption) l2norm ---
// Staging via global_load_lds width=16 (v14, verified). Epilogue applies leakyrelu(0.1)
// then x / (sqrt(sum_l x^2)+EPS) per (row, caption-32-col-group), reduced across the 16
// mn-lanes via shfl_xor. Verified correct in v15 (absmax unchanged). k2bm needs only softmax.
__global__ __launch_bounds__(256) void k2a_mfma(const ushort_t* __restrict__ cvt,
                                                float* __restrict__ C) {
    const ushort_t* imgH = cvt;
    const ushort_t* imgL = cvt + N_IMG_EL;
    const ushort_t* capH = cvt + 2 * (size_t)N_IMG_EL;
    const ushort_t* capL = capH + N_CAP_EL;
    __shared__ ushort_t Ah[128][32], Al[128][32], Bh[64][32], Bl[64][32];
    int t = threadIdx.x, w = t >> 6, lane = t & 63;
    int quad = lane >> 4, mn = lane & 15;
    int m0 = blockIdx.x * 128, n0 = blockIdx.y * 64;
    float4v acc[2][4];
    #pragma unroll
    for (int i = 0; i < 2; i++)
        #pragma unroll
        for (int j = 0; j < 4; j++) acc[i][j] = (float4v){0.f, 0.f, 0.f, 0.f};

    for (int kc = 0; kc < 32; kc++) {
        #pragma unroll
        for (int j = 0; j < 6; j++) {
            int ch = t + j * 256;                   // 1536 16B chunks; branch is wave-uniform
            const ushort_t* src;
            ushort_t* dst;
            if (ch < 512) {
                int row = ch >> 2, seg = ch & 3;
                src = imgH + (size_t)(m0 + row) * 1024 + kc * 32 + seg * 8;
                dst = &Ah[0][0] + ch * 8;
            } else if (ch < 1024) {
                int r2 = ch - 512, row = r2 >> 2, seg = r2 & 3;
                src = imgL + (size_t)(m0 + row) * 1024 + kc * 32 + seg * 8;
                dst = &Al[0][0] + r2 * 8;
            } else if (ch < 1280) {
                int r2 = ch - 1024, row = r2 >> 2, seg = r2 & 3;
                src = capH + (size_t)(n0 + row) * 1024 + kc * 32 + seg * 8;
                dst = &Bh[0][0] + r2 * 8;
            } else {
                int r2 = ch - 1280, row = r2 >> 2, seg = r2 & 3;
                src = capL + (size_t)(n0 + row) * 1024 + kc * 32 + seg * 8;
                dst = &Bl[0][0] + r2 * 8;
            }
            __builtin_amdgcn_global_load_lds(
                (const __attribute__((address_space(1))) uint*)src,
                (__attribute__((address_space(3))) uint*)dst, 16, 0, 0);
        }
        __syncthreads();
        short8 ah[2], al[2];
        #pragma unroll
        for (int tm = 0; tm < 2; tm++) {
            ah[tm] = *(short8*)&Ah[w * 32 + tm * 16 + mn][quad * 8];
            al[tm] = *(short8*)&Al[w * 32 + tm * 16 + mn][quad * 8];
        }
        #pragma unroll
        for (int nt = 0; nt < 4; nt++) {
            short8 bh = *(short8*)&Bh[nt * 16 + mn][quad * 8];
            short8 bl = *(short8*)&Bl[nt * 16 + mn][quad * 8];
            #pragma unroll
            for (int tm = 0; tm < 2; tm++) {
                acc[tm][nt] = __builtin_amdgcn_mfma_f32_16x16x32_bf16(ah[tm], bh, acc[tm][nt], 0, 0, 0);
                acc[tm][nt] = __builtin_amdgcn_mfma_f32_16x16x32_bf16(ah[tm], bl, acc[tm][nt], 0, 0, 0);
                acc[tm][nt] = __builtin_amdgcn_mfma_f32_16x16x32_bf16(al[tm], bh, acc[tm][nt], 0, 0, 0);
            }
        }
        __syncthreads();
    }
    // epilogue: leaky, then l2norm over cols 0-31 (cap A) and 32-63 (cap B) per row.
    #pragma unroll
    for (int tm = 0; tm < 2; tm++)
        #pragma unroll
        for (int nt = 0; nt < 4; nt++)
            #pragma unroll
            for (int r = 0; r < 4; r++) {
                float v = acc[tm][nt][r];
                acc[tm][nt][r] = (v >= 0.f) ? v : 0.1f * v;
            }
    float invA[2][4], invB[2][4];
    #pragma unroll
    for (int tm = 0; tm < 2; tm++)
        #pragma unroll
        for (int r = 0; r < 4; r++) {
            float ssA = acc[tm][0][r] * acc[tm][0][r] + acc[tm][1][r] * acc[tm][1][r];
            float ssB = acc[tm][2][r] * acc[tm][2][r] + acc[tm][3][r] * acc[tm][3][r];
            #pragma unroll
            for (int off = 1; off < 16; off <<= 1) {
                ssA += __shfl_xor(ssA, off);
                ssB += __shfl_xor(ssB, off);
            }
            invA[tm][r] = 1.f / (sqrtf(ssA) + EPSF);
            invB[tm][r] = 1.f / (sqrtf(ssB) + EPSF);
        }
    #pragma unroll
    for (int tm = 0; tm < 2; tm++)
        #pragma unroll
        for (int nt = 0; nt < 4; nt++)
            #pragma unroll
            for (int r = 0; r < 4; r++) {
                int mrow = m0 + w * 32 + tm * 16 + quad * 4 + r;
                int ncol = n0 + nt * 16 + mn;
                float sc = (nt < 2) ? invA[tm][r] : invB[tm][r];
                C[(size_t)mrow * 2048 + ncol] = acc[tm][nt][r] * sc;
            }
}

// ---------------- kpre: M_X = W_X @ W_gc (512x32); emit bf16 hi/lo planes ----------------
__global__ __launch_bounds__(256) void kpre(const float* __restrict__ Wmu,
                                            const float* __restrict__ Wlv,
                                            const float* __restrict__ W1,
                                            const float* __restrict__ Wgc,
                                            float* __restrict__ ws) {
    int m = blockIdx.x >> 6;            // 0..2
    int hg = blockIdx.x & 63;           // 0..63
    int h0 = hg * 8;
    const float* W = (m == 0) ? Wmu : (m == 1) ? Wlv : W1;
    __shared__ float Gs[64][32];
    __shared__ float Ws[8][68];
    int t = threadIdx.x;
    int h = t >> 5, f = t & 31;
    float acc = 0.f;
    for (int kc = 0; kc < 8; kc++) {
        for (int i = t; i < 512; i += 256) {
            int row = i >> 3, c4 = i & 7;
            *(float4*)&Gs[row][c4 * 4] = *(const float4*)(Wgc + (kc * 64 + row) * 32 + c4 * 4);
        }
        if (t < 128) {
            int hh = t >> 4, c4 = t & 15;
            *(float4*)&Ws[hh][c4 * 4] = *(const float4*)(W + (size_t)(h0 + hh) * 512 + kc * 64 + c4 * 4);
        }
        __syncthreads();
        #pragma unroll 4
        for (int k = 0; k < 64; k++) acc += Ws[h][k] * Gs[k][f];
        __syncthreads();
    }
    ushort_t* Mb = (ushort_t*)ws + m * 32768;       // [hi 16384][lo 16384]
    ushort_t hi = bf16_rne(acc);
    ushort_t lo = bf16_rne(acc - bf16_f(hi));
    Mb[(h0 + h) * 32 + f] = hi;
    Mb[16384 + (h0 + h) * 32 + f] = lo;
}

// ---------------- k1: per caption: words_sim -> adj -> s[c][l] ; + qn[c][l][f] ----------------
__global__ __launch_bounds__(256) void k1(const float* __restrict__ captions,
                                          const int* __restrict__ depends,
                                          float* __restrict__ ws) {
    int c = blockIdx.x;
    __shared__ float caps[32][65];
    __shared__ float G[32][33];
    __shared__ float adj[32][33];
    int t = threadIdx.x;
    int l2 = t & 31, l1_0 = t >> 5;
    float acc[4] = {0.f, 0.f, 0.f, 0.f};
    const float* cap = captions + (size_t)c * 32 * 1024;

    for (int kc = 0; kc < 16; kc++) {
        for (int i = t; i < 512; i += 256) {
            int ll = i >> 4, q = i & 15;
            float4 v = *(const float4*)(cap + ll * 1024 + kc * 64 + q * 4);
            caps[ll][q * 4 + 0] = v.x; caps[ll][q * 4 + 1] = v.y;
            caps[ll][q * 4 + 2] = v.z; caps[ll][q * 4 + 3] = v.w;
        }
        __syncthreads();
        #pragma unroll 4
        for (int k = 0; k < 64; k++) {
            float cv = caps[l2][k];
            #pragma unroll
            for (int i = 0; i < 4; i++) acc[i] += caps[l1_0 + 8 * i][k] * cv;
        }
        __syncthreads();
    }
    #pragma unroll
    for (int i = 0; i < 4; i++) G[l1_0 + 8 * i][l2] = acc[i];
    for (int i = t; i < 32 * 33; i += 256) ((float*)adj)[i] = 0.f;
    __syncthreads();

    if (t < 32) {
        float mx = -1e30f;
        for (int n = 0; n < 32; n++) mx = fmaxf(mx, LAM * G[t][n]);
        float sum = 0.f;
        for (int n = 0; n < 32; n++) { float p = __expf(LAM * G[t][n] - mx); G[t][n] = p; sum += p; }
        float inv = 1.f / sum;
        for (int n = 0; n < 32; n++) G[t][n] *= inv;
    }
    __syncthreads();
    if (t >= 1 && t < 30) {
        int d0 = depends[c * 60 + t * 2 + 0];
        int d1 = depends[c * 60 + t * 2 + 1];
        adj[d0][d1] = 1.f;
        adj[d1][d0] = 1.f;
    }
    __syncthreads();
    if (t < 32) adj[t][t] += 1.f;
    __syncthreads();
    if (t < 32) {
        float ss = 0.f, sw = 0.f;
        for (int n = 0; n < 32; n++) { float mm = adj[t][n] * G[t][n]; ss += mm * mm; }
        float inv = 1.f / (sqrtf(ss) + EPSF);
        for (int n = 0; n < 32; n++) sw += adj[t][n] * G[t][n] * adj[t][n];
        ws[OFF_S + c * 32 + t] = sw * inv;
    }
    for (int p = t; p < 1024; p += 256) {
        int l = p >> 5, f = p & 31;
        const float* cp = cap + (size_t)l * 1024 + f * 32;
        float q2 = 0.f;
        #pragma unroll
        for (int q = 0; q < 8; q++) {
            float4 v = *(const float4*)(cp + q * 4);
            q2 += v.x * v.x + v.y * v.y + v.z * v.z + v.w * v.w;
        }
        ws[OFF_QN + c * 1024 + p] = sqrtf(q2);
    }
}

// ---------------- k2a (fp32 fallback) ----------------
__global__ __launch_bounds__(256) void k2a(const float* __restrict__ A,
                                           const float* __restrict__ Bm,
                                           float* __restrict__ C,
                                           int n0, int NW) {
    __shared__ float As[16][132];
    __shared__ float Bs[16][68];
    int m0 = blockIdx.x * 128;
    int nb0 = n0 + blockIdx.y * 64;
    int t = threadIdx.x;
    int tm = t >> 4, tn = t & 15;
    float acc[8][4] = {};
    for (int kc = 0; kc < 64; kc++) {
        #pragma unroll
        for (int j = 0; j < 2; j++) {
            int idx = t + j * 256;
            int row = idx >> 2, kq = idx & 3;
            float4 v = *(const float4*)(A + (size_t)(m0 + row) * 1024 + kc * 16 + kq * 4);
            As[kq * 4 + 0][row] = v.x; As[kq * 4 + 1][row] = v.y;
            As[kq * 4 + 2][row] = v.z; As[kq * 4 + 3][row] = v.w;
        }
        {
            int row = t >> 2, kq = t & 3;
            float4 v = *(const float4*)(Bm + (size_t)(nb0 + row) * 1024 + kc * 16 + kq * 4);
            Bs[kq * 4 + 0][row] = v.x; Bs[kq * 4 + 1][row] = v.y;
            Bs[kq * 4 + 2][row] = v.z; Bs[kq * 4 + 3][row] = v.w;
        }
        __syncthreads();
        #pragma unroll
        for (int kk = 0; kk < 16; kk++) {
            float a0[4], a1[4], bb[4];
            *(float4*)a0 = *(float4*)&As[kk][tm * 8];
            *(float4*)a1 = *(float4*)&As[kk][tm * 8 + 4];
            *(float4*)bb = *(float4*)&Bs[kk][tn * 4];
            #pragma unroll
            for (int i = 0; i < 4; i++)
                #pragma unroll
                for (int j2 = 0; j2 < 4; j2++) {
                    acc[i][j2]     += a0[i] * bb[j2];
                    acc[i + 4][j2] += a1[i] * bb[j2];
                }
        }
        __syncthreads();
    }
    int cw0 = nb0 - n0 + tn * 4;
    #pragma unroll
    for (int i = 0; i < 8; i++) {
        float4 v = make_float4(acc[i][0], acc[i][1], acc[i][2], acc[i][3]);
        *(float4*)(C + (size_t)(m0 + tm * 8 + i) * NW + cw0) = v;
    }
}

// ---------------- k2bm v16: v13 structure (VERIFIED 79.7us) minus leaky/l2norm ------------
// attn arrives pre-leaky+l2norm'd from k2a_mfma v3 epilogue, so phase 1 is softmax only.
// Everything else identical to v13: B=2 b's, C=2 captions, fh f-halves, stride-33 LDS.
__global__ __launch_bounds__(64) void k2bm(const ushort_t* __restrict__ imgT,
                                           const float* __restrict__ captions,
                                           const float* __restrict__ attn,
                                           const float* __restrict__ ws,
                                           float* __restrict__ ts_out) {
    int orig = blockIdx.x;
    int fh = orig >> 10;                        // 0..1
    int rest = orig & 1023;
    int cpair = rest >> 5;                      // 0..31
    int bp = rest & 31;                         // 0..31 ; XCD = bp%8
    int b0 = bp * 2;
    int c0 = cpair * 2;
    __shared__ union {
        float A[2][2][36][33];                  // [bi][ci][r][l] attn tiles (phase 1), pad 33
        float T[2][2][16][33];                  // [bi][ci][fl][l] tnode half-tiles (phase 2)
    } u;
    int t = threadIdx.x;
    int l = t & 31, hi = t >> 5;

    // phase 0: load 4 attn tiles (2 b x 2 ci) — already leaky+l2norm'd
    for (int i = t; i < 1152; i += 64) {
        int bi = i >= 576;
        int i2 = i - bi * 576;
        int ci = i2 >= 288;
        int i3 = i2 - ci * 288;
        int r = i3 >> 3, q = i3 & 7;
        *(float4*)&u.A[bi][ci][r][q * 4] =
            *(const float4*)(attn + (size_t)((b0 + bi) * 36 + r) * 2048 + (c0 + ci) * 32 + q * 4);
    }
    __syncthreads();
    for (int i = t; i < 128; i += 64) {         // softmax over regions per (bi, ci, word)
        int bi = i >= 64;
        int i2 = i & 63;
        int ci = i2 >> 5, ll = i2 & 31;
        float mx = -1e30f;
        for (int r = 0; r < 36; r++) mx = fmaxf(mx, u.A[bi][ci][r][ll]);
        mx *= LAM;
        float sum = 0.f;
        for (int r = 0; r < 36; r++) { float p = __expf(LAM * u.A[bi][ci][r][ll] - mx); u.A[bi][ci][r][ll] = p; sum += p; }
        float inv = 1.f / sum;
        for (int r = 0; r < 36; r++) u.A[bi][ci][r][ll] *= inv;
    }
    __syncthreads();

    // B-frags (k=r, n=l), 32x32x16 layout: n=lane&31, k=(lane>>5)*8+j
    short8 bh[2][2][3], bl[2][2][3];            // [bi][ci][kstep]
    #pragma unroll
    for (int bi = 0; bi < 2; bi++)
        #pragma unroll
        for (int ci = 0; ci < 2; ci++)
            #pragma unroll
            for (int k3 = 0; k3 < 3; k3++) {
                union { short8 v; ushort_t u8[8]; } H, L;
                #pragma unroll
                for (int j = 0; j < 8; j++) {
                    int r = k3 * 16 + hi * 8 + j;
                    float v = (r < 36) ? u.A[bi][ci][r][l] : 0.f;
                    ushort_t hv = bf16_rne(v);
                    H.u8[j] = hv;
                    L.u8[j] = bf16_rne(v - bf16_f(hv));
                }
                bh[bi][ci][k3] = H.v;
                bl[bi][ci][k3] = L.v;
            }
    __syncthreads();                            // A dead; union space becomes T

    const ushort_t* ibH0 = imgT + (size_t)b0 * 49152;   // ((f*3 + k3)*64 + lane)*8
    const ushort_t* ibL0 = ibH0 + IMGT2_EL;
    const ushort_t* ibH1 = ibH0 + 49152;
    const ushort_t* ibL1 = ibL0 + 49152;
    const float* qnp = ws + OFF_QN;
    float sv[2];
    sv[0] = ws[OFF_S + c0 * 32 + l];
    sv[1] = ws[OFF_S + (c0 + 1) * 32 + l];
    const float* capb[2];
    capb[0] = captions + (size_t)c0 * 32768 + (size_t)l * 1024 + hi * 4;
    capb[1] = capb[0] + 32768;

    for (int fl = 0; fl < 16; fl++) {
        int f = fh * 16 + fl;
        // A-frags for BOTH b's, all k-steps (imgT; shared across the 2 captions)
        short8 aA[2][3], aB[2][3];              // [plane hi/lo][k3]
        #pragma unroll
        for (int k3 = 0; k3 < 3; k3++) {
            size_t off = ((size_t)(f * 3 + k3) * 64 + t) * 8;
            aA[0][k3] = *(const short8*)(ibH0 + off);
            aA[1][k3] = *(const short8*)(ibL0 + off);
            aB[0][k3] = *(const short8*)(ibH1 + off);
            aB[1][k3] = *(const short8*)(ibL1 + off);
        }
        #pragma unroll
        for (int ci = 0; ci < 2; ci++) {
            // caption values loaded ONCE, used for both b's (the demand halving)
            float4 cv[4];
            #pragma unroll
            for (int g = 0; g < 4; g++) cv[g] = *(const float4*)(capb[ci] + f * 32 + g * 8);
            f32x16 accA = {0.f,0.f,0.f,0.f,0.f,0.f,0.f,0.f,0.f,0.f,0.f,0.f,0.f,0.f,0.f,0.f};
            f32x16 accB = {0.f,0.f,0.f,0.f,0.f,0.f,0.f,0.f,0.f,0.f,0.f,0.f,0.f,0.f,0.f,0.f};
            #pragma unroll
            for (int k3 = 0; k3 < 3; k3++) {
                accA = __builtin_amdgcn_mfma_f32_32x32x16_bf16(aA[0][k3], bh[0][ci][k3], accA, 0, 0, 0);
                accA = __builtin_amdgcn_mfma_f32_32x32x16_bf16(aA[0][k3], bl[0][ci][k3], accA, 0, 0, 0);
                accA = __builtin_amdgcn_mfma_f32_32x32x16_bf16(aA[1][k3], bh[0][ci][k3], accA, 0, 0, 0);
                accB = __builtin_amdgcn_mfma_f32_32x32x16_bf16(aB[0][k3], bh[1][ci][k3], accB, 0, 0, 0);
                accB = __builtin_amdgcn_mfma_f32_32x32x16_bf16(aB[0][k3], bl[1][ci][k3], accB, 0, 0, 0);
                accB = __builtin_amdgcn_mfma_f32_32x32x16_bf16(aB[1][k3], bh[1][ci][k3], accB, 0, 0, 0);
            }
            // lane holds wctxT[e_loc=(reg&3)+8*(reg>>2)+4*hi][l]; cv[g] covers e_loc=g*8+4*hi+0..3
            float numA = 0.f, w2A = 0.f, numB = 0.f, w2B = 0.f;
            #pragma unroll
            for (int g = 0; g < 4; g++) {
                numA += cv[g].x * accA[g*4+0] + cv[g].y * accA[g*4+1]
                      + cv[g].z * accA[g*4+2] + cv[g].w * accA[g*4+3];
                w2A  += accA[g*4+0]*accA[g*4+0] + accA[g*4+1]*accA[g*4+1]
                      + accA[g*4+2]*accA[g*4+2] + accA[g*4+3]*accA[g*4+3];
                numB += cv[g].x * accB[g*4+0] + cv[g].y * accB[g*4+1]
                      + cv[g].z * accB[g*4+2] + cv[g].w * accB[g*4+3];
                w2B  += accB[g*4+0]*accB[g*4+0] + accB[g*4+1]*accB[g*4+1]
                      + accB[g*4+2]*accB[g*4+2] + accB[g*4+3]*accB[g*4+3];
            }
            numA += __shfl_xor(numA, 32); w2A += __shfl_xor(w2A, 32);
            numB += __shfl_xor(numB, 32); w2B += __shfl_xor(w2B, 32);
            if (hi == 0) {
                float qv = qnp[(c0 + ci) * 1024 + l * 32 + f];   // b-independent
                float denA = fmaxf(qv * sqrtf(w2A), EPSF);
                u.T[0][ci][fl][l] = (numA / denA) * sv[ci];
                float denB = fmaxf(qv * sqrtf(w2B), EPSF);
                u.T[1][ci][fl][l] = (numB / denB) * sv[ci];
            }
        }
    }
    __syncthreads();
    // burst: 2b x 2ci x 32l x 16f floats -> ts_out (transpose-read from T)
    #pragma unroll
    for (int j = 0; j < 8; j++) {
        int id = t + j * 64;                    // 0..511 float4-items
        int bi = id >> 8;
        int ci = (id >> 7) & 1;
        int r2 = id & 127;
        int ll = r2 >> 2, q = r2 & 3;
        float4 v;
        v.x = u.T[bi][ci][q * 4 + 0][ll];
        v.y = u.T[bi][ci][q * 4 + 1][ll];
        v.z = u.T[bi][ci][q * 4 + 2][ll];
        v.w = u.T[bi][ci][q * 4 + 3][ll];
        *(float4*)(ts_out + ((size_t)(c0 + ci) * 64 + b0 + bi) * 1024 + ll * 32 + fh * 16 + q * 4) = v;
    }
}

// ---------------- k2b (fp32 fallback, validated R4 version) ----------------
__global__ __launch_bounds__(256) void k2b(const float* __restrict__ images,
                                           const float* __restrict__ captions,
                                           const float* __restrict__ attn,
                                           const float* __restrict__ ws,
                                           float* __restrict__ ts_out,
                                           int c0, int NW) {
    int b = blockIdx.x;
    int cw = blockIdx.y;
    int ca = c0 + cw * 2;
    __shared__ float A2[2][36][36];
    __shared__ float Ims[36][256];
    __shared__ float scs[2][32];
    const float* img = images + (size_t)b * 36 * 1024;
    int t = threadIdx.x;
    int el = t & 63;
    int lg = t >> 6;

    for (int i = t; i < 576; i += 256) {
        int r = i >> 4, q = i & 15;
        float4 v = *(const float4*)(attn + (size_t)(b * 36 + r) * NW + cw * 64 + q * 4);
        *(float4*)&A2[q >> 3][r][(q & 7) * 4] = v;
    }
    __syncthreads();
    if (t < 72) {
        int ci = t >= 36, r = t - 36 * ci;
        float ss = 0.f;
        #pragma unroll
        for (int l = 0; l < 32; l++) {
            float v = A2[ci][r][l];
            v = (v >= 0.f) ? v : 0.1f * v;
            A2[ci][r][l] = v; ss += v * v;
        }
        float inv = 1.f / (sqrtf(ss) + EPSF);
        #pragma unroll
        for (int l = 0; l < 32; l++) A2[ci][r][l] *= inv;
    }
    __syncthreads();
    if (t < 64) {
        int ci = t >> 5, l = t & 31;
        float mx = -1e30f;
        for (int r = 0; r < 36; r++) mx = fmaxf(mx, A2[ci][r][l]);
        mx *= LAM;
        float sum = 0.f;
        for (int r = 0; r < 36; r++) { float p = __expf(LAM * A2[ci][r][l] - mx); A2[ci][r][l] = p; sum += p; }
        float inv = 1.f / sum;
        for (int r = 0; r < 36; r++) A2[ci][r][l] *= inv;
    } else if (t >= 128 && t < 192) {
        int i = t - 128;
        scs[i >> 5][i & 31] = ws[OFF_S + (ca + (i >> 5)) * 32 + (i & 31)];
    }
    __syncthreads();

    const float* qn = ws + OFF_QN;
    for (int g = 0; g < 4; g++) {
        for (int i = t; i < 2304; i += 256) {
            int r = i >> 6, q = i & 63;
            *(float4*)&Ims[r][q * 4] = *(const float4*)(img + (size_t)r * 1024 + g * 256 + q * 4);
        }
        __syncthreads();

        float acc[2][8][4] = {};
        #pragma unroll 2
        for (int r = 0; r < 36; r++) {
            float4 iv = *(float4*)&Ims[r][el * 4];
            float ivv[4] = {iv.x, iv.y, iv.z, iv.w};
            #pragma unroll
            for (int ci = 0; ci < 2; ci++) {
                float av[8];
                *(float4*)&av[0] = *(float4*)&A2[ci][r][lg * 8];
                *(float4*)&av[4] = *(float4*)&A2[ci][r][lg * 8 + 4];
                #pragma unroll
                for (int i = 0; i < 8; i++)
                    #pragma unroll
                    for (int e = 0; e < 4; e++)
                        acc[ci][i][e] += av[i] * ivv[e];
            }
        }

        int fb = el >> 3;
        int f = g * 8 + fb;
        #pragma unroll
        for (int ci = 0; ci < 2; ci++) {
            int c = ca + ci;
            const float* cap = captions + (size_t)c * 32 * 1024 + g * 256;
            #pragma unroll
            for (int i = 0; i < 8; i++) {
                int l = lg * 8 + i;
                float4 cv = *(const float4*)(cap + (size_t)l * 1024 + el * 4);
                float num = cv.x * acc[ci][i][0] + cv.y * acc[ci][i][1]
                          + cv.z * acc[ci][i][2] + cv.w * acc[ci][i][3];
                float w2 = acc[ci][i][0] * acc[ci][i][0] + acc[ci][i][1] * acc[ci][i][1]
                         + acc[ci][i][2] * acc[ci][i][2] + acc[ci][i][3] * acc[ci][i][3];
                num += __shfl_down(num, 4); w2 += __shfl_down(w2, 4);
                num += __shfl_down(num, 2); w2 += __shfl_down(w2, 2);
                num += __shfl_down(num, 1); w2 += __shfl_down(w2, 1);
                if ((el & 7) == 0) {
                    float den = fmaxf(qn[c * 1024 + l * 32 + f] * sqrtf(w2), EPSF);
                    ts_out[(((size_t)c * 64 + b) * 32 + l) * 32 + f] = (num / den) * scs[ci][l];
                }
            }
        }
        __syncthreads();
    }
}

// ---------------- k3 (MFMA): similarities[b][c] = mean_l W2·tanh(ts@M1^T + b1) + b2 ----------------
__global__ __launch_bounds__(256) void k3(const float* __restrict__ ts_ws,
                                          const ushort_t* __restrict__ Mb,
                                          const float* __restrict__ b1,
                                          const float* __restrict__ W2,
                                          const float* __restrict__ b2,
                                          float* __restrict__ out_sim) {
    int c = blockIdx.x >> 6, b = blockIdx.x & 63;
    __shared__ ushort_t tsh[32][32], tsl[32][32];
    __shared__ float red[4];
    int t = threadIdx.x;
    const float* tsrc = ts_ws + (size_t)(c * 64 + b) * 1024;
    {
        int row = t >> 3, q = t & 7;
        float4 v = *(const float4*)(tsrc + row * 32 + q * 4);
        float x[4] = {v.x, v.y, v.z, v.w};
        ushort_t hh[4], ll[4];
        #pragma unroll
        for (int j = 0; j < 4; j++) {
            hh[j] = bf16_rne(x[j]);
            ll[j] = bf16_rne(x[j] - bf16_f(hh[j]));
        }
        *(uint2*)&tsh[row][q * 4] = make_uint2(pack2(hh[0], hh[1]), pack2(hh[2], hh[3]));
        *(uint2*)&tsl[row][q * 4] = make_uint2(pack2(ll[0], ll[1]), pack2(ll[2], ll[3]));
    }
    __syncthreads();
    int w = t >> 6, lane = t & 63, quad = lane >> 4, mn = lane & 15;
    const ushort_t* M1H = Mb + 65536;
    short8 ah[2], al[2];
    #pragma unroll
    for (int mt = 0; mt < 2; mt++) {
        ah[mt] = *(short8*)&tsh[mt * 16 + mn][quad * 8];
        al[mt] = *(short8*)&tsl[mt * 16 + mn][quad * 8];
    }
    float psum = 0.f;
    #pragma unroll
    for (int nt = 0; nt < 8; nt++) {
        int h = w * 128 + nt * 16 + mn;
        short8 bh = *(const short8*)(M1H + h * 32 + quad * 8);
        short8 bl = *(const short8*)(M1H + 16384 + h * 32 + quad * 8);
        float b1v = b1[h], w2v = W2[h];
        #pragma unroll
        for (int mt = 0; mt < 2; mt++) {
            float4v acc = (float4v){0.f, 0.f, 0.f, 0.f};
            acc = __builtin_amdgcn_mfma_f32_16x16x32_bf16(ah[mt], bh, acc, 0, 0, 0);
            acc = __builtin_amdgcn_mfma_f32_16x16x32_bf16(ah[mt], bl, acc, 0, 0, 0);
            acc = __builtin_amdgcn_mfma_f32_16x16x32_bf16(al[mt], bh, acc, 0, 0, 0);
            #pragma unroll
            for (int r = 0; r < 4; r++) {
                float x = fminf(fmaxf(acc[r] + b1v, -15.f), 15.f);
                float e2 = __expf(2.f * x);
                psum += (1.f - 2.f / (e2 + 1.f)) * w2v;
            }
        }
    }
    #pragma unroll
    for (int off = 32; off >= 1; off >>= 1) psum += __shfl_down(psum, off);
    if (lane == 0) red[w] = psum;
    __syncthreads();
    if (t == 0) out_sim[b * 64 + c] = b2[0] + (red[0] + red[1] + red[2] + red[3]) * (1.f / 32.f);
}

// ---------------- k4: w[b][c] = softmax over c ----------------
__global__ __launch_bounds__(64) void k4(const float* __restrict__ sim, float* __restrict__ w_ws) {
    int b = blockIdx.x, t = threadIdx.x;
    float v = sim[b * 64 + t];
    float mx = v;
    #pragma unroll
    for (int off = 32; off >= 1; off >>= 1) mx = fmaxf(mx, __shfl_xor(mx, off));
    float p = __expf(v - mx);
    float sum = p;
    #pragma unroll
    for (int off = 32; off >= 1; off >>= 1) sum += __shfl_xor(sum, off);
    w_ws[b * 64 + t] = p / sum;
}

// ---------------- k5 (MFMA): mu_word / sigma_word; block per (b,l), 256 threads ----------------
__global__ __launch_bounds__(256) void k5(const float* __restrict__ ts_ws,
                                          const float* __restrict__ ws,
                                          const float* __restrict__ b_mu,
                                          const float* __restrict__ b_lv,
                                          float* __restrict__ out) {
    int b = blockIdx.x >> 5, l = blockIdx.x & 31;
    int t = threadIdx.x;
    __shared__ ushort_t tsh[64][32], tsl[64][32];
    __shared__ float wls[64];
    {
        int cc = t >> 2, q = t & 3;
        const float* src = ts_ws + (((size_t)cc * 64 + b) * 32 + l) * 32 + q * 8;
        #pragma unroll
        for (int half = 0; half < 2; half++) {
            float4 v = *(const float4*)(src + half * 4);
            float x[4] = {v.x, v.y, v.z, v.w};
            ushort_t hh[4], ll[4];
            #pragma unroll
            for (int j = 0; j < 4; j++) {
                hh[j] = bf16_rne(x[j]);
                ll[j] = bf16_rne(x[j] - bf16_f(hh[j]));
            }
            *(uint2*)&tsh[cc][q * 8 + half * 4] = make_uint2(pack2(hh[0], hh[1]), pack2(hh[2], hh[3]));
            *(uint2*)&tsl[cc][q * 8 + half * 4] = make_uint2(pack2(ll[0], ll[1]), pack2(ll[2], ll[3]));
        }
    }
    if (t < 64) wls[t] = ws[OFF_W + b * 64 + t];
    __syncthreads();

    int w = t >> 6, lane = t & 63, quad = lane >> 4, mn = lane & 15;
    const ushort_t* Mb = (const ushort_t*)ws;
    const ushort_t* MmuH = Mb;
    const ushort_t* MlvH = Mb + 32768;
    short8 ah[4], al[4];
    #pragma unroll
    for (int mt = 0; mt < 4; mt++) {
        ah[mt] = *(short8*)&tsh[mt * 16 + mn][quad * 8];
        al[mt] = *(short8*)&tsl[mt * 16 + mn][quad * 8];
    }
    float pm[8], pq[8], pe[8];
    #pragma unroll
    for (int nt = 0; nt < 8; nt++) {
        int h = w * 128 + nt * 16 + mn;
        {
            short8 bh = *(const short8*)(MmuH + h * 32 + quad * 8);
            short8 bl = *(const short8*)(MmuH + 16384 + h * 32 + quad * 8);
            float bmv = b_mu[h];
            float am = 0.f, aq = 0.f;
            #pragma unroll
            for (int mt = 0; mt < 4; mt++) {
                float4v acc = (float4v){0.f, 0.f, 0.f, 0.f};
                acc = __builtin_amdgcn_mfma_f32_16x16x32_bf16(ah[mt], bh, acc, 0, 0, 0);
                acc = __builtin_amdgcn_mfma_f32_16x16x32_bf16(ah[mt], bl, acc, 0, 0, 0);
                acc = __builtin_amdgcn_mfma_f32_16x16x32_bf16(al[mt], bh, acc, 0, 0, 0);
                #pragma unroll
                for (int r = 0; r < 4; r++) {
                    int cc = mt * 16 + quad * 4 + r;
                    float mu = acc[r] + bmv;
                    float wv = wls[cc];
                    am += wv * mu;
                    aq += wv * mu * mu;
                }
            }
            am += __shfl_xor(am, 16); am += __shfl_xor(am, 32);
            aq += __shfl_xor(aq, 16); aq += __shfl_xor(aq, 32);
            pm[nt] = am; pq[nt] = aq;
        }
        {
            short8 bh = *(const short8*)(MlvH + h * 32 + quad * 8);
            short8 bl = *(const short8*)(MlvH + 16384 + h * 32 + quad * 8);
            float blv = b_lv[h];
            float ae = 0.f;
            #pragma unroll
            for (int mt = 0; mt < 4; mt++) {
                float4v acc = (float4v){0.f, 0.f, 0.f, 0.f};
                acc = __builtin_amdgcn_mfma_f32_16x16x32_bf16(ah[mt], bh, acc, 0, 0, 0);
                acc = __builtin_amdgcn_mfma_f32_16x16x32_bf16(ah[mt], bl, acc, 0, 0, 0);
                acc = __builtin_amdgcn_mfma_f32_16x16x32_bf16(al[mt], bh, acc, 0, 0, 0);
                #pragma unroll
                for (int r = 0; r < 4; r++) {
                    int cc = mt * 16 + quad * 4 + r;
                    ae += wls[cc] * __expf(acc[r] + blv);
                }
            }
            ae += __shfl_xor(ae, 16); ae += __shfl_xor(ae, 32);
            pe[nt] = ae;
        }
    }
    if (quad == 0) {
        #pragma unroll
        for (int nt = 0; nt < 8; nt++) {
            int h = w * 128 + nt * 16 + mn;
            size_t idx = (size_t)(b * 32 + l) * 512 + h;
            float m = pm[nt];
            out[4096 + idx] = m;
            float var = pe[nt] + pq[nt] - m * m;
            out[4096 + 64 * 32 * 512 + idx] = sqrtf(fmaxf(var, 1e-8f));
        }
    }
}

extern "C" void kernel_launch(void* const* d_in, const int* in_sizes, int n_in,
                              void* d_out, int out_size, void* d_ws, size_t ws_size,
                              hipStream_t stream) {
    const float* images   = (const float*)d_in[0];
    const float* captions = (const float*)d_in[1];
    const int*   depends  = (const int*)d_in[2];
    const float* Wgc = (const float*)d_in[3];
    const float* Wmu = (const float*)d_in[4];
    const float* bmu = (const float*)d_in[5];
    const float* Wlv = (const float*)d_in[6];
    const float* blv = (const float*)d_in[7];
    const float* W1  = (const float*)d_in[8];
    const float* b1  = (const float*)d_in[9];
    const float* W2  = (const float*)d_in[10];
    const float* b2  = (const float*)d_in[11];
    float* out = (float*)d_out;
    float* ws  = (float*)d_ws;

    hipLaunchKernelGGL(kpre, dim3(192), dim3(256), 0, stream, Wmu, Wlv, W1, Wgc, ws);
    hipLaunchKernelGGL(k1, dim3(64), dim3(256), 0, stream, captions, depends, ws);

    const size_t CVT_FLOATS = ((size_t)2 * N_IMG_EL + 2 * N_CAP_EL) / 2;
    size_t need_floats = (size_t)OFF_CVT + CVT_FLOATS;
    bool use_mfma = ws_size >= need_floats * 4;

    if (use_mfma) {
        ushort_t* cvt = (ushort_t*)(ws + OFF_CVT);
        hipLaunchKernelGGL(kcvt, dim3((N_IMG_EL + N_CAP_EL) / 4 / 256), dim3(256), 0, stream,
                           images, captions, cvt);
        hipLaunchKernelGGL(k2a_mfma, dim3(18, 32), dim3(256), 0, stream, cvt, ws + OFF_ATTN);
        // CVT region dead after k2a_mfma; reuse for 32x32x16-frag imgT2 hi/lo (12.6MB <= 17.8MB)
        hipLaunchKernelGGL(kcvt2, dim3(512), dim3(256), 0, stream, images, cvt);
        hipLaunchKernelGGL(k2bm, dim3(2048), dim3(64), 0, stream,
                           cvt, captions, ws + OFF_ATTN, ws, ws + OFF_TS);
    } else {
        int NW = 2048;
        while (NW > 64 && ((size_t)OFF_ATTN + (size_t)2304 * NW) * 4 > ws_size) NW >>= 1;
        for (int n0 = 0; n0 < 2048; n0 += NW) {
            hipLaunchKernelGGL(k2a, dim3(18, NW / 64), dim3(256), 0, stream,
                               images, captions, ws + OFF_ATTN, n0, NW);
            hipLaunchKernelGGL(k2b, dim3(64, NW / 64), dim3(256), 0, stream,
                               images, captions, ws + OFF_ATTN, ws, ws + OFF_TS, n0 / 32, NW);
        }
    }

    hipLaunchKernelGGL(k3, dim3(4096), dim3(256), 0, stream,
                       ws + OFF_TS, (const ushort_t*)ws, b1, W2, b2, out);
    hipLaunchKernelGGL(k4, dim3(64), dim3(64), 0, stream, out, ws + OFF_W);
    hipLaunchKernelGGL(k5, dim3(2048), dim3(256), 0, stream, ws + OFF_TS, ws, bmu, blv, out);
}

// Round 12
// 347.007 us; speedup vs baseline: 1.1826x; 1.0068x over previous
//
#include <hip/hip_runtime.h>
#include <math.h>

#define LAM 9.0f
#define EPSF 1e-8f

typedef unsigned int uint;
typedef unsigned short ushort_t;
typedef __attribute__((ext_vector_type(8))) short short8;
typedef __attribute__((ext_vector_type(4))) float float4v;
typedef __attribute__((ext_vector_type(16))) float f32x16;

// ws layout (floats)
#define OFF_MMU 0                       // ushort planes: [hi 16384][lo 16384] per matrix
#define OFF_MLV (512*32)
#define OFF_M1  (2*512*32)
#define OFF_S   (3*512*32)              // 49152 : s[c][l] (64*32)
#define OFF_W   (OFF_S + 64*32)         // 51200 : w[b][c] (64*64)
#define OFF_QN  (OFF_W + 64*64)         // 55296 : qn[c][l][f] (64*32*32)
#define OFF_TS  (OFF_QN + 64*32*32)     // 120832: tnode_s[c][b][l][f] (64*64*32*32)
#define OFF_ATTN (OFF_TS + 64*64*32*32) // attn [2304][NW]
#define OFF_CVT  (OFF_ATTN + 2304*2048) // hi/lo bf16 arrays (ushort); REUSED by imgT2 after k2a

#define N_IMG_EL 2359296                // 2304*1024
#define N_CAP_EL 2097152                // 2048*1024
// imgT2 per plane (ushorts), 32x32x16-A-frag order: 64b * 32estep * 3kstep * 64lane * 8
#define IMGT2_EL 3145728

__device__ __forceinline__ ushort_t bf16_rne(float x) {
    uint u = __float_as_uint(x);
    uint r = (u + 0x7fffu + ((u >> 16) & 1u)) >> 16;
    return (ushort_t)r;
}
__device__ __forceinline__ float bf16_f(ushort_t h) {
    return __uint_as_float(((uint)h) << 16);
}
__device__ __forceinline__ uint pack2(ushort_t a, ushort_t b) {
    return (uint)a | ((uint)b << 16);
}

// ---------------- kcvt v2: split images+captions into hi/lo bf16 + fused qn --------------
// qn[c][l][f] = ||cap[c][l][f*32:(f+1)*32]|| computed via 8-lane shfl reduce (each thread
// holds 4 consecutive floats; 8 consecutive threads = one f-group; alignment exact since
// caption range starts at thread 589824 and blocks are 256 threads).
__global__ __launch_bounds__(256) void kcvt(const float* __restrict__ img,
                                            const float* __restrict__ cap,
                                            ushort_t* __restrict__ dst,
                                            float* __restrict__ ws) {
    size_t i = (size_t)blockIdx.x * 256 + threadIdx.x;   // float4 index
    const float* src;
    ushort_t *H, *L;
    size_t base;
    bool is_cap = (i >= (N_IMG_EL / 4));
    if (!is_cap) {
        src = img; H = dst; L = dst + N_IMG_EL; base = i * 4;
    } else {
        src = cap; H = dst + 2 * (size_t)N_IMG_EL; L = H + N_CAP_EL; base = (i - N_IMG_EL / 4) * 4;
    }
    float4 v = *(const float4*)(src + base);
    float x[4] = {v.x, v.y, v.z, v.w};
    ushort_t hh[4], ll[4];
    #pragma unroll
    for (int j = 0; j < 4; j++) {
        hh[j] = bf16_rne(x[j]);
        ll[j] = bf16_rne(x[j] - bf16_f(hh[j]));
    }
    *(uint2*)(H + base) = make_uint2(pack2(hh[0], hh[1]), pack2(hh[2], hh[3]));
    *(uint2*)(L + base) = make_uint2(pack2(ll[0], ll[1]), pack2(ll[2], ll[3]));
    if (is_cap) {
        float q2 = x[0] * x[0] + x[1] * x[1] + x[2] * x[2] + x[3] * x[3];
        q2 += __shfl_xor(q2, 1);
        q2 += __shfl_xor(q2, 2);
        q2 += __shfl_xor(q2, 4);
        if ((threadIdx.x & 7) == 0) {
            size_t e = base;                // caption element index
            int c = (int)(e >> 15);
            int rem = (int)(e & 32767);
            int l = rem >> 10;
            int f = (rem & 1023) >> 5;
            ws[OFF_QN + c * 1024 + l * 32 + f] = sqrtf(q2);
        }
    }
}

// ---------------- kcvt2 v2: build imgT2 in 32x32x16 MFMA A-fragment order, hi/lo ----------
// A[m=e_loc][k=r]: lane holds m = lane&31, k-slice = (lane>>5)*8 + j (per kstep of 16).
// layout: plane*IMGT2_EL + (((b*32 + estep)*3 + ks3)*64 + lane)*8
// elem j = img[b][r = ks3*16 + (lane>>5)*8 + j][e = estep*32 + (lane&31)]  (0 for r>=36)
__global__ __launch_bounds__(256) void kcvt2(const float* __restrict__ img,
                                             ushort_t* __restrict__ dstH) {
    int b = blockIdx.x >> 3, ecg = blockIdx.x & 7;      // e-group: e = ecg*128 .. +127
    __shared__ float S[36][132];
    int t = threadIdx.x;
    for (int i = t; i < 1152; i += 256) {               // img[b][r][e-slice]
        int r = i >> 5, q = i & 31;
        *(float4*)&S[r][q * 4] = *(const float4*)(img + ((size_t)b * 36 + r) * 1024 + ecg * 128 + q * 4);
    }
    __syncthreads();
    int lane = t & 63, grp = t >> 6;
    int m = lane & 31, hi = lane >> 5;
    #pragma unroll
    for (int w2 = 0; w2 < 3; w2++) {
        int item = grp + w2 * 4;            // 0..11 = estepL(4) x ks3(3)
        int estepL = item / 3;
        int ks3 = item - estepL * 3;
        ushort_t hh[8], ll[8];
        #pragma unroll
        for (int j = 0; j < 8; j++) {
            int r = ks3 * 16 + hi * 8 + j;
            float v = (r < 36) ? S[r][estepL * 32 + m] : 0.f;
            hh[j] = bf16_rne(v);
            ll[j] = bf16_rne(v - bf16_f(hh[j]));
        }
        int estep = ecg * 4 + estepL;
        size_t off = ((((size_t)b * 32 + estep) * 3 + ks3) * 64 + lane) * 8;
        uint4 uh, ul;
        uh.x = pack2(hh[0], hh[1]); uh.y = pack2(hh[2], hh[3]);
        uh.z = pack2(hh[4], hh[5]); uh.w = pack2(hh[6], hh[7]);
        ul.x = pack2(ll[0], ll[1]); ul.y = pack2(ll[2], ll[3]);
        ul.z = pack2(ll[4], ll[5]); ul.w = pack2(ll[6], ll[7]);
        *(uint4*)(dstH + off) = uh;
        *(uint4*)(dstH + IMGT2_EL + off) = ul;
    }
}

// ---------------- k2a_mfma v4: v3 + XCD-local grid (dim3(32,18); n fastest) --------------
// Old grid (18,32) m-fastest: XCD=(m+18n)%8 scattered A-panel sharers across XCDs -> each
// A panel (512KB) re-fetched from L3 by 32 n-blocks (~300MB) and B panels by 18 (~150MB).
// New grid n-fastest: XCD=n%8 -> B-panel n served by ONE XCD's L2 (151->8MB); A panel read
// once per XCD (300->74MB). Pure index swap, no correctness risk.
__global__ __launch_bounds__(256) void k2a_mfma(const ushort_t* __restrict__ cvt,
                                                float* __restrict__ C) {
    const ushort_t* imgH = cvt;
    const ushort_t* imgL = cvt + N_IMG_EL;
    const ushort_t* capH = cvt + 2 * (size_t)N_IMG_EL;
    const ushort_t* capL = capH + N_CAP_EL;
    __shared__ ushort_t Ah[128][32], Al[128][32], Bh[64][32], Bl[64][32];
    int t = threadIdx.x, w = t >> 6, lane = t & 63;
    int quad = lane >> 4, mn = lane & 15;
    int m0 = blockIdx.y * 128, n0 = blockIdx.x * 64;
    float4v acc[2][4];
    #pragma unroll
    for (int i = 0; i < 2; i++)
        #pragma unroll
        for (int j = 0; j < 4; j++) acc[i][j] = (float4v){0.f, 0.f, 0.f, 0.f};

    for (int kc = 0; kc < 32; kc++) {
        #pragma unroll
        for (int j = 0; j < 6; j++) {
            int ch = t + j * 256;                   // 1536 16B chunks; branch is wave-uniform
            const ushort_t* src;
            ushort_t* dst;
            if (ch < 512) {
                int row = ch >> 2, seg = ch & 3;
                src = imgH + (size_t)(m0 + row) * 1024 + kc * 32 + seg * 8;
                dst = &Ah[0][0] + ch * 8;
            } else if (ch < 1024) {
                int r2 = ch - 512, row = r2 >> 2, seg = r2 & 3;
                src = imgL + (size_t)(m0 + row) * 1024 + kc * 32 + seg * 8;
                dst = &Al[0][0] + r2 * 8;
            } else if (ch < 1280) {
                int r2 = ch - 1024, row = r2 >> 2, seg = r2 & 3;
                src = capH + (size_t)(n0 + row) * 1024 + kc * 32 + seg * 8;
                dst = &Bh[0][0] + r2 * 8;
            } else {
                int r2 = ch - 1280, row = r2 >> 2, seg = r2 & 3;
                src = capL + (size_t)(n0 + row) * 1024 + kc * 32 + seg * 8;
                dst = &Bl[0][0] + r2 * 8;
            }
            __builtin_amdgcn_global_load_lds(
                (const __attribute__((address_space(1))) uint*)src,
                (__attribute__((address_space(3))) uint*)dst, 16, 0, 0);
        }
        __syncthreads();
        short8 ah[2], al[2];
        #pragma unroll
        for (int tm = 0; tm < 2; tm++) {
            ah[tm] = *(short8*)&Ah[w * 32 + tm * 16 + mn][quad * 8];
            al[tm] = *(short8*)&Al[w * 32 + tm * 16 + mn][quad * 8];
        }
        #pragma unroll
        for (int nt = 0; nt < 4; nt++) {
            short8 bh = *(short8*)&Bh[nt * 16 + mn][quad * 8];
            short8 bl = *(short8*)&Bl[nt * 16 + mn][quad * 8];
            #pragma unroll
            for (int tm = 0; tm < 2; tm++) {
                acc[tm][nt] = __builtin_amdgcn_mfma_f32_16x16x32_bf16(ah[tm], bh, acc[tm][nt], 0, 0, 0);
                acc[tm][nt] = __builtin_amdgcn_mfma_f32_16x16x32_bf16(ah[tm], bl, acc[tm][nt], 0, 0, 0);
                acc[tm][nt] = __builtin_amdgcn_mfma_f32_16x16x32_bf16(al[tm], bh, acc[tm][nt], 0, 0, 0);
            }
        }
        __syncthreads();
    }
    // epilogue: leaky, then l2norm over cols 0-31 (cap A) and 32-63 (cap B) per row.
    #pragma unroll
    for (int tm = 0; tm < 2; tm++)
        #pragma unroll
        for (int nt = 0; nt < 4; nt++)
            #pragma unroll
            for (int r = 0; r < 4; r++) {
                float v = acc[tm][nt][r];
                acc[tm][nt][r] = (v >= 0.f) ? v : 0.1f * v;
            }
    float invA[2][4], invB[2][4];
    #pragma unroll
    for (int tm = 0; tm < 2; tm++)
        #pragma unroll
        for (int r = 0; r < 4; r++) {
            float ssA = acc[tm][0][r] * acc[tm][0][r] + acc[tm][1][r] * acc[tm][1][r];
            float ssB = acc[tm][2][r] * acc[tm][2][r] + acc[tm][3][r] * acc[tm][3][r];
            #pragma unroll
            for (int off = 1; off < 16; off <<= 1) {
                ssA += __shfl_xor(ssA, off);
                ssB += __shfl_xor(ssB, off);
            }
            invA[tm][r] = 1.f / (sqrtf(ssA) + EPSF);
            invB[tm][r] = 1.f / (sqrtf(ssB) + EPSF);
        }
    #pragma unroll
    for (int tm = 0; tm < 2; tm++)
        #pragma unroll
        for (int nt = 0; nt < 4; nt++)
            #pragma unroll
            for (int r = 0; r < 4; r++) {
                int mrow = m0 + w * 32 + tm * 16 + quad * 4 + r;
                int ncol = n0 + nt * 16 + mn;
                float sc = (nt < 2) ? invA[tm][r] : invB[tm][r];
                C[(size_t)mrow * 2048 + ncol] = acc[tm][nt][r] * sc;
            }
}

// ---------------- kpre: M_X = W_X @ W_gc (512x32); emit bf16 hi/lo planes ----------------
__global__ __launch_bounds__(256) void kpre(const float* __restrict__ Wmu,
                                            const float* __restrict__ Wlv,
                                            const float* __restrict__ W1,
                                            const float* __restrict__ Wgc,
                                            float* __restrict__ ws) {
    int m = blockIdx.x >> 6;            // 0..2
    int hg = blockIdx.x & 63;           // 0..63
    int h0 = hg * 8;
    const float* W = (m == 0) ? Wmu : (m == 1) ? Wlv : W1;
    __shared__ float Gs[64][32];
    __shared__ float Ws[8][68];
    int t = threadIdx.x;
    int h = t >> 5, f = t & 31;
    float acc = 0.f;
    for (int kc = 0; kc < 8; kc++) {
        for (int i = t; i < 512; i += 256) {
            int row = i >> 3, c4 = i & 7;
            *(float4*)&Gs[row][c4 * 4] = *(const float4*)(Wgc + (kc * 64 + row) * 32 + c4 * 4);
        }
        if (t < 128) {
            int hh = t >> 4, c4 = t & 15;
            *(float4*)&Ws[hh][c4 * 4] = *(const float4*)(W + (size_t)(h0 + hh) * 512 + kc * 64 + c4 * 4);
        }
        __syncthreads();
        #pragma unroll 4
        for (int k = 0; k < 64; k++) acc += Ws[h][k] * Gs[k][f];
        __syncthreads();
    }
    ushort_t* Mb = (ushort_t*)ws + m * 32768;       // [hi 16384][lo 16384]
    ushort_t hi = bf16_rne(acc);
    ushort_t lo = bf16_rne(acc - bf16_f(hi));
    Mb[(h0 + h) * 32 + f] = hi;
    Mb[16384 + (h0 + h) * 32 + f] = lo;
}

// ---------------- k1 v2: words_sim -> adj -> s[c][l]; qn only if do_qn (fallback path) ---
__global__ __launch_bounds__(256) void k1(const float* __restrict__ captions,
                                          const int* __restrict__ depends,
                                          float* __restrict__ ws,
                                          int do_qn) {
    int c = blockIdx.x;
    __shared__ float caps[32][65];
    __shared__ float G[32][33];
    __shared__ float adj[32][33];
    int t = threadIdx.x;
    int l2 = t & 31, l1_0 = t >> 5;
    float acc[4] = {0.f, 0.f, 0.f, 0.f};
    const float* cap = captions + (size_t)c * 32 * 1024;

    for (int kc = 0; kc < 16; kc++) {
        for (int i = t; i < 512; i += 256) {
            int ll = i >> 4, q = i & 15;
            float4 v = *(const float4*)(cap + ll * 1024 + kc * 64 + q * 4);
            caps[ll][q * 4 + 0] = v.x; caps[ll][q * 4 + 1] = v.y;
            caps[ll][q * 4 + 2] = v.z; caps[ll][q * 4 + 3] = v.w;
        }
        __syncthreads();
        #pragma unroll 4
        for (int k = 0; k < 64; k++) {
            float cv = caps[l2][k];
            #pragma unroll
            for (int i = 0; i < 4; i++) acc[i] += caps[l1_0 + 8 * i][k] * cv;
        }
        __syncthreads();
    }
    #pragma unroll
    for (int i = 0; i < 4; i++) G[l1_0 + 8 * i][l2] = acc[i];
    for (int i = t; i < 32 * 33; i += 256) ((float*)adj)[i] = 0.f;
    __syncthreads();

    if (t < 32) {
        float mx = -1e30f;
        for (int n = 0; n < 32; n++) mx = fmaxf(mx, LAM * G[t][n]);
        float sum = 0.f;
        for (int n = 0; n < 32; n++) { float p = __expf(LAM * G[t][n] - mx); G[t][n] = p; sum += p; }
        float inv = 1.f / sum;
        for (int n = 0; n < 32; n++) G[t][n] *= inv;
    }
    __syncthreads();
    if (t >= 1 && t < 30) {
        int d0 = depends[c * 60 + t * 2 + 0];
        int d1 = depends[c * 60 + t * 2 + 1];
        adj[d0][d1] = 1.f;
        adj[d1][d0] = 1.f;
    }
    __syncthreads();
    if (t < 32) adj[t][t] += 1.f;
    __syncthreads();
    if (t < 32) {
        float ss = 0.f, sw = 0.f;
        for (int n = 0; n < 32; n++) { float mm = adj[t][n] * G[t][n]; ss += mm * mm; }
        float inv = 1.f / (sqrtf(ss) + EPSF);
        for (int n = 0; n < 32; n++) sw += adj[t][n] * G[t][n] * adj[t][n];
        ws[OFF_S + c * 32 + t] = sw * inv;
    }
    if (do_qn) {
        for (int p = t; p < 1024; p += 256) {
            int l = p >> 5, f = p & 31;
            const float* cp = cap + (size_t)l * 1024 + f * 32;
            float q2 = 0.f;
            #pragma unroll
            for (int q = 0; q < 8; q++) {
                float4 v = *(const float4*)(cp + q * 4);
                q2 += v.x * v.x + v.y * v.y + v.z * v.z + v.w * v.w;
            }
            ws[OFF_QN + c * 1024 + p] = sqrtf(q2);
        }
    }
}

// ---------------- k2a (fp32 fallback) ----------------
__global__ __launch_bounds__(256) void k2a(const float* __restrict__ A,
                                           const float* __restrict__ Bm,
                                           float* __restrict__ C,
                                           int n0, int NW) {
    __shared__ float As[16][132];
    __shared__ float Bs[16][68];
    int m0 = blockIdx.x * 128;
    int nb0 = n0 + blockIdx.y * 64;
    int t = threadIdx.x;
    int tm = t >> 4, tn = t & 15;
    float acc[8][4] = {};
    for (int kc = 0; kc < 64; kc++) {
        #pragma unroll
        for (int j = 0; j < 2; j++) {
            int idx = t + j * 256;
            int row = idx >> 2, kq = idx & 3;
            float4 v = *(const float4*)(A + (size_t)(m0 + row) * 1024 + kc * 16 + kq * 4);
            As[kq * 4 + 0][row] = v.x; As[kq * 4 + 1][row] = v.y;
            As[kq * 4 + 2][row] = v.z; As[kq * 4 + 3][row] = v.w;
        }
        {
            int row = t >> 2, kq = t & 3;
            float4 v = *(const float4*)(Bm + (size_t)(nb0 + row) * 1024 + kc * 16 + kq * 4);
            Bs[kq * 4 + 0][row] = v.x; Bs[kq * 4 + 1][row] = v.y;
            Bs[kq * 4 + 2][row] = v.z; Bs[kq * 4 + 3][row] = v.w;
        }
        __syncthreads();
        #pragma unroll
        for (int kk = 0; kk < 16; kk++) {
            float a0[4], a1[4], bb[4];
            *(float4*)a0 = *(float4*)&As[kk][tm * 8];
            *(float4*)a1 = *(float4*)&As[kk][tm * 8 + 4];
            *(float4*)bb = *(float4*)&Bs[kk][tn * 4];
            #pragma unroll
            for (int i = 0; i < 4; i++)
                #pragma unroll
                for (int j2 = 0; j2 < 4; j2++) {
                    acc[i][j2]     += a0[i] * bb[j2];
                    acc[i + 4][j2] += a1[i] * bb[j2];
                }
        }
        __syncthreads();
    }
    int cw0 = nb0 - n0 + tn * 4;
    #pragma unroll
    for (int i = 0; i < 8; i++) {
        float4 v = make_float4(acc[i][0], acc[i][1], acc[i][2], acc[i][3]);
        *(float4*)(C + (size_t)(m0 + tm * 8 + i) * NW + cw0) = v;
    }
}

// ---------------- k2bm v16: v13 structure minus leaky/l2norm (VERIFIED 75.3us) ------------
__global__ __launch_bounds__(64) void k2bm(const ushort_t* __restrict__ imgT,
                                           const float* __restrict__ captions,
                                           const float* __restrict__ attn,
                                           const float* __restrict__ ws,
                                           float* __restrict__ ts_out) {
    int orig = blockIdx.x;
    int fh = orig >> 10;                        // 0..1
    int rest = orig & 1023;
    int cpair = rest >> 5;                      // 0..31
    int bp = rest & 31;                         // 0..31 ; XCD = bp%8
    int b0 = bp * 2;
    int c0 = cpair * 2;
    __shared__ union {
        float A[2][2][36][33];                  // [bi][ci][r][l] attn tiles (phase 1), pad 33
        float T[2][2][16][33];                  // [bi][ci][fl][l] tnode half-tiles (phase 2)
    } u;
    int t = threadIdx.x;
    int l = t & 31, hi = t >> 5;

    // phase 0: load 4 attn tiles (2 b x 2 ci) — already leaky+l2norm'd
    for (int i = t; i < 1152; i += 64) {
        int bi = i >= 576;
        int i2 = i - bi * 576;
        int ci = i2 >= 288;
        int i3 = i2 - ci * 288;
        int r = i3 >> 3, q = i3 & 7;
        *(float4*)&u.A[bi][ci][r][q * 4] =
            *(const float4*)(attn + (size_t)((b0 + bi) * 36 + r) * 2048 + (c0 + ci) * 32 + q * 4);
    }
    __syncthreads();
    for (int i = t; i < 128; i += 64) {         // softmax over regions per (bi, ci, word)
        int bi = i >= 64;
        int i2 = i & 63;
        int ci = i2 >> 5, ll = i2 & 31;
        float mx = -1e30f;
        for (int r = 0; r < 36; r++) mx = fmaxf(mx, u.A[bi][ci][r][ll]);
        mx *= LAM;
        float sum = 0.f;
        for (int r = 0; r < 36; r++) { float p = __expf(LAM * u.A[bi][ci][r][ll] - mx); u.A[bi][ci][r][ll] = p; sum += p; }
        float inv = 1.f / sum;
        for (int r = 0; r < 36; r++) u.A[bi][ci][r][ll] *= inv;
    }
    __syncthreads();

    // B-frags (k=r, n=l), 32x32x16 layout: n=lane&31, k=(lane>>5)*8+j
    short8 bh[2][2][3], bl[2][2][3];            // [bi][ci][kstep]
    #pragma unroll
    for (int bi = 0; bi < 2; bi++)
        #pragma unroll
        for (int ci = 0; ci < 2; ci++)
            #pragma unroll
            for (int k3 = 0; k3 < 3; k3++) {
                union { short8 v; ushort_t u8[8]; } H, L;
                #pragma unroll
                for (int j = 0; j < 8; j++) {
                    int r = k3 * 16 + hi * 8 + j;
                    float v = (r < 36) ? u.A[bi][ci][r][l] : 0.f;
                    ushort_t hv = bf16_rne(v);
                    H.u8[j] = hv;
                    L.u8[j] = bf16_rne(v - bf16_f(hv));
                }
                bh[bi][ci][k3] = H.v;
                bl[bi][ci][k3] = L.v;
            }
    __syncthreads();                            // A dead; union space becomes T

    const ushort_t* ibH0 = imgT + (size_t)b0 * 49152;   // ((f*3 + k3)*64 + lane)*8
    const ushort_t* ibL0 = ibH0 + IMGT2_EL;
    const ushort_t* ibH1 = ibH0 + 49152;
    const ushort_t* ibL1 = ibL0 + 49152;
    const float* qnp = ws + OFF_QN;
    float sv[2];
    sv[0] = ws[OFF_S + c0 * 32 + l];
    sv[1] = ws[OFF_S + (c0 + 1) * 32 + l];
    const float* capb[2];
    capb[0] = captions + (size_t)c0 * 32768 + (size_t)l * 1024 + hi * 4;
    capb[1] = capb[0] + 32768;

    for (int fl = 0; fl < 16; fl++) {
        int f = fh * 16 + fl;
        // A-frags for BOTH b's, all k-steps (imgT; shared across the 2 captions)
        short8 aA[2][3], aB[2][3];              // [plane hi/lo][k3]
        #pragma unroll
        for (int k3 = 0; k3 < 3; k3++) {
            size_t off = ((size_t)(f * 3 + k3) * 64 + t) * 8;
            aA[0][k3] = *(const short8*)(ibH0 + off);
            aA[1][k3] = *(const short8*)(ibL0 + off);
            aB[0][k3] = *(const short8*)(ibH1 + off);
            aB[1][k3] = *(const short8*)(ibL1 + off);
        }
        #pragma unroll
        for (int ci = 0; ci < 2; ci++) {
            // caption values loaded ONCE, used for both b's (the demand halving)
            float4 cv[4];
            #pragma unroll
            for (int g = 0; g < 4; g++) cv[g] = *(const float4*)(capb[ci] + f * 32 + g * 8);
            f32x16 accA = {0.f,0.f,0.f,0.f,0.f,0.f,0.f,0.f,0.f,0.f,0.f,0.f,0.f,0.f,0.f,0.f};
            f32x16 accB = {0.f,0.f,0.f,0.f,0.f,0.f,0.f,0.f,0.f,0.f,0.f,0.f,0.f,0.f,0.f,0.f};
            #pragma unroll
            for (int k3 = 0; k3 < 3; k3++) {
                accA = __builtin_amdgcn_mfma_f32_32x32x16_bf16(aA[0][k3], bh[0][ci][k3], accA, 0, 0, 0);
                accA = __builtin_amdgcn_mfma_f32_32x32x16_bf16(aA[0][k3], bl[0][ci][k3], accA, 0, 0, 0);
                accA = __builtin_amdgcn_mfma_f32_32x32x16_bf16(aA[1][k3], bh[0][ci][k3], accA, 0, 0, 0);
                accB = __builtin_amdgcn_mfma_f32_32x32x16_bf16(aB[0][k3], bh[1][ci][k3], accB, 0, 0, 0);
                accB = __builtin_amdgcn_mfma_f32_32x32x16_bf16(aB[0][k3], bl[1][ci][k3], accB, 0, 0, 0);
                accB = __builtin_amdgcn_mfma_f32_32x32x16_bf16(aB[1][k3], bh[1][ci][k3], accB, 0, 0, 0);
            }
            // lane holds wctxT[e_loc=(reg&3)+8*(reg>>2)+4*hi][l]; cv[g] covers e_loc=g*8+4*hi+0..3
            float numA = 0.f, w2A = 0.f, numB = 0.f, w2B = 0.f;
            #pragma unroll
            for (int g = 0; g < 4; g++) {
                numA += cv[g].x * accA[g*4+0] + cv[g].y * accA[g*4+1]
                      + cv[g].z * accA[g*4+2] + cv[g].w * accA[g*4+3];
                w2A  += accA[g*4+0]*accA[g*4+0] + accA[g*4+1]*accA[g*4+1]
                      + accA[g*4+2]*accA[g*4+2] + accA[g*4+3]*accA[g*4+3];
                numB += cv[g].x * accB[g*4+0] + cv[g].y * accB[g*4+1]
                      + cv[g].z * accB[g*4+2] + cv[g].w * accB[g*4+3];
                w2B  += accB[g*4+0]*accB[g*4+0] + accB[g*4+1]*accB[g*4+1]
                      + accB[g*4+2]*accB[g*4+2] + accB[g*4+3]*accB[g*4+3];
            }
            numA += __shfl_xor(numA, 32); w2A += __shfl_xor(w2A, 32);
            numB += __shfl_xor(numB, 32); w2B += __shfl_xor(w2B, 32);
            if (hi == 0) {
                float qv = qnp[(c0 + ci) * 1024 + l * 32 + f];   // b-independent
                float denA = fmaxf(qv * sqrtf(w2A), EPSF);
                u.T[0][ci][fl][l] = (numA / denA) * sv[ci];
                float denB = fmaxf(qv * sqrtf(w2B), EPSF);
                u.T[1][ci][fl][l] = (numB / denB) * sv[ci];
            }
        }
    }
    __syncthreads();
    // burst: 2b x 2ci x 32l x 16f floats -> ts_out (transpose-read from T)
    #pragma unroll
    for (int j = 0; j < 8; j++) {
        int id = t + j * 64;                    // 0..511 float4-items
        int bi = id >> 8;
        int ci = (id >> 7) & 1;
        int r2 = id & 127;
        int ll = r2 >> 2, q = r2 & 3;
        float4 v;
        v.x = u.T[bi][ci][q * 4 + 0][ll];
        v.y = u.T[bi][ci][q * 4 + 1][ll];
        v.z = u.T[bi][ci][q * 4 + 2][ll];
        v.w = u.T[bi][ci][q * 4 + 3][ll];
        *(float4*)(ts_out + ((size_t)(c0 + ci) * 64 + b0 + bi) * 1024 + ll * 32 + fh * 16 + q * 4) = v;
    }
}

// ---------------- k2b (fp32 fallback, validated R4 version) ----------------
__global__ __launch_bounds__(256) void k2b(const float* __restrict__ images,
                                           const float* __restrict__ captions,
                                           const float* __restrict__ attn,
                                           const float* __restrict__ ws,
                                           float* __restrict__ ts_out,
                                           int c0, int NW) {
    int b = blockIdx.x;
    int cw = blockIdx.y;
    int ca = c0 + cw * 2;
    __shared__ float A2[2][36][36];
    __shared__ float Ims[36][256];
    __shared__ float scs[2][32];
    const float* img = images + (size_t)b * 36 * 1024;
    int t = threadIdx.x;
    int el = t & 63;
    int lg = t >> 6;

    for (int i = t; i < 576; i += 256) {
        int r = i >> 4, q = i & 15;
        float4 v = *(const float4*)(attn + (size_t)(b * 36 + r) * NW + cw * 64 + q * 4);
        *(float4*)&A2[q >> 3][r][(q & 7) * 4] = v;
    }
    __syncthreads();
    if (t < 72) {
        int ci = t >= 36, r = t - 36 * ci;
        float ss = 0.f;
        #pragma unroll
        for (int l = 0; l < 32; l++) {
            float v = A2[ci][r][l];
            v = (v >= 0.f) ? v : 0.1f * v;
            A2[ci][r][l] = v; ss += v * v;
        }
        float inv = 1.f / (sqrtf(ss) + EPSF);
        #pragma unroll
        for (int l = 0; l < 32; l++) A2[ci][r][l] *= inv;
    }
    __syncthreads();
    if (t < 64) {
        int ci = t >> 5, l = t & 31;
        float mx = -1e30f;
        for (int r = 0; r < 36; r++) mx = fmaxf(mx, A2[ci][r][l]);
        mx *= LAM;
        float sum = 0.f;
        for (int r = 0; r < 36; r++) { float p = __expf(LAM * A2[ci][r][l] - mx); A2[ci][r][l] = p; sum += p; }
        float inv = 1.f / sum;
        for (int r = 0; r < 36; r++) A2[ci][r][l] *= inv;
    } else if (t >= 128 && t < 192) {
        int i = t - 128;
        scs[i >> 5][i & 31] = ws[OFF_S + (ca + (i >> 5)) * 32 + (i & 31)];
    }
    __syncthreads();

    const float* qn = ws + OFF_QN;
    for (int g = 0; g < 4; g++) {
        for (int i = t; i < 2304; i += 256) {
            int r = i >> 6, q = i & 63;
            *(float4*)&Ims[r][q * 4] = *(const float4*)(img + (size_t)r * 1024 + g * 256 + q * 4);
        }
        __syncthreads();

        float acc[2][8][4] = {};
        #pragma unroll 2
        for (int r = 0; r < 36; r++) {
            float4 iv = *(float4*)&Ims[r][el * 4];
            float ivv[4] = {iv.x, iv.y, iv.z, iv.w};
            #pragma unroll
            for (int ci = 0; ci < 2; ci++) {
                float av[8];
                *(float4*)&av[0] = *(float4*)&A2[ci][r][lg * 8];
                *(float4*)&av[4] = *(float4*)&A2[ci][r][lg * 8 + 4];
                #pragma unroll
                for (int i = 0; i < 8; i++)
                    #pragma unroll
                    for (int e = 0; e < 4; e++)
                        acc[ci][i][e] += av[i] * ivv[e];
            }
        }

        int fb = el >> 3;
        int f = g * 8 + fb;
        #pragma unroll
        for (int ci = 0; ci < 2; ci++) {
            int c = ca + ci;
            const float* cap = captions + (size_t)c * 32 * 1024 + g * 256;
            #pragma unroll
            for (int i = 0; i < 8; i++) {
                int l = lg * 8 + i;
                float4 cv = *(const float4*)(cap + (size_t)l * 1024 + el * 4);
                float num = cv.x * acc[ci][i][0] + cv.y * acc[ci][i][1]
                          + cv.z * acc[ci][i][2] + cv.w * acc[ci][i][3];
                float w2 = acc[ci][i][0] * acc[ci][i][0] + acc[ci][i][1] * acc[ci][i][1]
                         + acc[ci][i][2] * acc[ci][i][2] + acc[ci][i][3] * acc[ci][i][3];
                num += __shfl_down(num, 4); w2 += __shfl_down(w2, 4);
                num += __shfl_down(num, 2); w2 += __shfl_down(w2, 2);
                num += __shfl_down(num, 1); w2 += __shfl_down(w2, 1);
                if ((el & 7) == 0) {
                    float den = fmaxf(qn[c * 1024 + l * 32 + f] * sqrtf(w2), EPSF);
                    ts_out[(((size_t)c * 64 + b) * 32 + l) * 32 + f] = (num / den) * scs[ci][l];
                }
            }
        }
        __syncthreads();
    }
}

// ---------------- k3 (MFMA): similarities[b][c] = mean_l W2·tanh(ts@M1^T + b1) + b2 ----------------
__global__ __launch_bounds__(256) void k3(const float* __restrict__ ts_ws,
                                          const ushort_t* __restrict__ Mb,
                                          const float* __restrict__ b1,
                                          const float* __restrict__ W2,
                                          const float* __restrict__ b2,
                                          float* __restrict__ out_sim) {
    int c = blockIdx.x >> 6, b = blockIdx.x & 63;
    __shared__ ushort_t tsh[32][32], tsl[32][32];
    __shared__ float red[4];
    int t = threadIdx.x;
    const float* tsrc = ts_ws + (size_t)(c * 64 + b) * 1024;
    {
        int row = t >> 3, q = t & 7;
        float4 v = *(const float4*)(tsrc + row * 32 + q * 4);
        float x[4] = {v.x, v.y, v.z, v.w};
        ushort_t hh[4], ll[4];
        #pragma unroll
        for (int j = 0; j < 4; j++) {
            hh[j] = bf16_rne(x[j]);
            ll[j] = bf16_rne(x[j] - bf16_f(hh[j]));
        }
        *(uint2*)&tsh[row][q * 4] = make_uint2(pack2(hh[0], hh[1]), pack2(hh[2], hh[3]));
        *(uint2*)&tsl[row][q * 4] = make_uint2(pack2(ll[0], ll[1]), pack2(ll[2], ll[3]));
    }
    __syncthreads();
    int w = t >> 6, lane = t & 63, quad = lane >> 4, mn = lane & 15;
    const ushort_t* M1H = Mb + 65536;
    short8 ah[2], al[2];
    #pragma unroll
    for (int mt = 0; mt < 2; mt++) {
        ah[mt] = *(short8*)&tsh[mt * 16 + mn][quad * 8];
        al[mt] = *(short8*)&tsl[mt * 16 + mn][quad * 8];
    }
    float psum = 0.f;
    #pragma unroll
    for (int nt = 0; nt < 8; nt++) {
        int h = w * 128 + nt * 16 + mn;
        short8 bh = *(const short8*)(M1H + h * 32 + quad * 8);
        short8 bl = *(const short8*)(M1H + 16384 + h * 32 + quad * 8);
        float b1v = b1[h], w2v = W2[h];
        #pragma unroll
        for (int mt = 0; mt < 2; mt++) {
            float4v acc = (float4v){0.f, 0.f, 0.f, 0.f};
            acc = __builtin_amdgcn_mfma_f32_16x16x32_bf16(ah[mt], bh, acc, 0, 0, 0);
            acc = __builtin_amdgcn_mfma_f32_16x16x32_bf16(ah[mt], bl, acc, 0, 0, 0);
            acc = __builtin_amdgcn_mfma_f32_16x16x32_bf16(al[mt], bh, acc, 0, 0, 0);
            #pragma unroll
            for (int r = 0; r < 4; r++) {
                float x = fminf(fmaxf(acc[r] + b1v, -15.f), 15.f);
                float e2 = __expf(2.f * x);
                psum += (1.f - 2.f / (e2 + 1.f)) * w2v;
            }
        }
    }
    #pragma unroll
    for (int off = 32; off >= 1; off >>= 1) psum += __shfl_down(psum, off);
    if (lane == 0) red[w] = psum;
    __syncthreads();
    if (t == 0) out_sim[b * 64 + c] = b2[0] + (red[0] + red[1] + red[2] + red[3]) * (1.f / 32.f);
}

// ---------------- k4: w[b][c] = softmax over c ----------------
__global__ __launch_bounds__(64) void k4(const float* __restrict__ sim, float* __restrict__ w_ws) {
    int b = blockIdx.x, t = threadIdx.x;
    float v = sim[b * 64 + t];
    float mx = v;
    #pragma unroll
    for (int off = 32; off >= 1; off >>= 1) mx = fmaxf(mx, __shfl_xor(mx, off));
    float p = __expf(v - mx);
    float sum = p;
    #pragma unroll
    for (int off = 32; off >= 1; off >>= 1) sum += __shfl_xor(sum, off);
    w_ws[b * 64 + t] = p / sum;
}

// ---------------- k5 (MFMA): mu_word / sigma_word; block per (b,l), 256 threads ----------------
__global__ __launch_bounds__(256) void k5(const float* __restrict__ ts_ws,
                                          const float* __restrict__ ws,
                                          const float* __restrict__ b_mu,
                                          const float* __restrict__ b_lv,
                                          float* __restrict__ out) {
    int b = blockIdx.x >> 5, l = blockIdx.x & 31;
    int t = threadIdx.x;
    __shared__ ushort_t tsh[64][32], tsl[64][32];
    __shared__ float wls[64];
    {
        int cc = t >> 2, q = t & 3;
        const float* src = ts_ws + (((size_t)cc * 64 + b) * 32 + l) * 32 + q * 8;
        #pragma unroll
        for (int half = 0; half < 2; half++) {
            float4 v = *(const float4*)(src + half * 4);
            float x[4] = {v.x, v.y, v.z, v.w};
            ushort_t hh[4], ll[4];
            #pragma unroll
            for (int j = 0; j < 4; j++) {
                hh[j] = bf16_rne(x[j]);
                ll[j] = bf16_rne(x[j] - bf16_f(hh[j]));
            }
            *(uint2*)&tsh[cc][q * 8 + half * 4] = make_uint2(pack2(hh[0], hh[1]), pack2(hh[2], hh[3]));
            *(uint2*)&tsl[cc][q * 8 + half * 4] = make_uint2(pack2(ll[0], ll[1]), pack2(ll[2], ll[3]));
        }
    }
    if (t < 64) wls[t] = ws[OFF_W + b * 64 + t];
    __syncthreads();

    int w = t >> 6, lane = t & 63, quad = lane >> 4, mn = lane & 15;
    const ushort_t* Mb = (const ushort_t*)ws;
    const ushort_t* MmuH = Mb;
    const ushort_t* MlvH = Mb + 32768;
    short8 ah[4], al[4];
    #pragma unroll
    for (int mt = 0; mt < 4; mt++) {
        ah[mt] = *(short8*)&tsh[mt * 16 + mn][quad * 8];
        al[mt] = *(short8*)&tsl[mt * 16 + mn][quad * 8];
    }
    float pm[8], pq[8], pe[8];
    #pragma unroll
    for (int nt = 0; nt < 8; nt++) {
        int h = w * 128 + nt * 16 + mn;
        {
            short8 bh = *(const short8*)(MmuH + h * 32 + quad * 8);
            short8 bl = *(const short8*)(MmuH + 16384 + h * 32 + quad * 8);
            float bmv = b_mu[h];
            float am = 0.f, aq = 0.f;
            #pragma unroll
            for (int mt = 0; mt < 4; mt++) {
                float4v acc = (float4v){0.f, 0.f, 0.f, 0.f};
                acc = __builtin_amdgcn_mfma_f32_16x16x32_bf16(ah[mt], bh, acc, 0, 0, 0);
                acc = __builtin_amdgcn_mfma_f32_16x16x32_bf16(ah[mt], bl, acc, 0, 0, 0);
                acc = __builtin_amdgcn_mfma_f32_16x16x32_bf16(al[mt], bh, acc, 0, 0, 0);
                #pragma unroll
                for (int r = 0; r < 4; r++) {
                    int cc = mt * 16 + quad * 4 + r;
                    float mu = acc[r] + bmv;
                    float wv = wls[cc];
                    am += wv * mu;
                    aq += wv * mu * mu;
                }
            }
            am += __shfl_xor(am, 16); am += __shfl_xor(am, 32);
            aq += __shfl_xor(aq, 16); aq += __shfl_xor(aq, 32);
            pm[nt] = am; pq[nt] = aq;
        }
        {
            short8 bh = *(const short8*)(MlvH + h * 32 + quad * 8);
            short8 bl = *(const short8*)(MlvH + 16384 + h * 32 + quad * 8);
            float blv = b_lv[h];
            float ae = 0.f;
            #pragma unroll
            for (int mt = 0; mt < 4; mt++) {
                float4v acc = (float4v){0.f, 0.f, 0.f, 0.f};
                acc = __builtin_amdgcn_mfma_f32_16x16x32_bf16(ah[mt], bh, acc, 0, 0, 0);
                acc = __builtin_amdgcn_mfma_f32_16x16x32_bf16(ah[mt], bl, acc, 0, 0, 0);
                acc = __builtin_amdgcn_mfma_f32_16x16x32_bf16(al[mt], bh, acc, 0, 0, 0);
                #pragma unroll
                for (int r = 0; r < 4; r++) {
                    int cc = mt * 16 + quad * 4 + r;
                    ae += wls[cc] * __expf(acc[r] + blv);
                }
            }
            ae += __shfl_xor(ae, 16); ae += __shfl_xor(ae, 32);
            pe[nt] = ae;
        }
    }
    if (quad == 0) {
        #pragma unroll
        for (int nt = 0; nt < 8; nt++) {
            int h = w * 128 + nt * 16 + mn;
            size_t idx = (size_t)(b * 32 + l) * 512 + h;
            float m = pm[nt];
            out[4096 + idx] = m;
            float var = pe[nt] + pq[nt] - m * m;
            out[4096 + 64 * 32 * 512 + idx] = sqrtf(fmaxf(var, 1e-8f));
        }
    }
}

extern "C" void kernel_launch(void* const* d_in, const int* in_sizes, int n_in,
                              void* d_out, int out_size, void* d_ws, size_t ws_size,
                              hipStream_t stream) {
    const float* images   = (const float*)d_in[0];
    const float* captions = (const float*)d_in[1];
    const int*   depends  = (const int*)d_in[2];
    const float* Wgc = (const float*)d_in[3];
    const float* Wmu = (const float*)d_in[4];
    const float* bmu = (const float*)d_in[5];
    const float* Wlv = (const float*)d_in[6];
    const float* blv = (const float*)d_in[7];
    const float* W1  = (const float*)d_in[8];
    const float* b1  = (const float*)d_in[9];
    const float* W2  = (const float*)d_in[10];
    const float* b2  = (const float*)d_in[11];
    float* out = (float*)d_out;
    float* ws  = (float*)d_ws;

    const size_t CVT_FLOATS = ((size_t)2 * N_IMG_EL + 2 * N_CAP_EL) / 2;
    size_t need_floats = (size_t)OFF_CVT + CVT_FLOATS;
    bool use_mfma = ws_size >= need_floats * 4;

    hipLaunchKernelGGL(kpre, dim3(192), dim3(256), 0, stream, Wmu, Wlv, W1, Wgc, ws);
    hipLaunchKernelGGL(k1, dim3(64), dim3(256), 0, stream, captions, depends, ws,
                       use_mfma ? 0 : 1);

    if (use_mfma) {
        ushort_t* cvt = (ushort_t*)(ws + OFF_CVT);
        hipLaunchKernelGGL(kcvt, dim3((N_IMG_EL + N_CAP_EL) / 4 / 256), dim3(256), 0, stream,
                           images, captions, cvt, ws);
        hipLaunchKernelGGL(k2a_mfma, dim3(32, 18), dim3(256), 0, stream, cvt, ws + OFF_ATTN);
        // CVT region dead after k2a_mfma; reuse for 32x32x16-frag imgT2 hi/lo (12.6MB <= 17.8MB)
        hipLaunchKernelGGL(kcvt2, dim3(512), dim3(256), 0, stream, images, cvt);
        hipLaunchKernelGGL(k2bm, dim3(2048), dim3(64), 0, stream,
                           cvt, captions, ws + OFF_ATTN, ws, ws + OFF_TS);
    } else {
        int NW = 2048;
        while (NW > 64 && ((size_t)OFF_ATTN + (size_t)2304 * NW) * 4 > ws_size) NW >>= 1;
        for (int n0 = 0; n0 < 2048; n0 += NW) {
            hipLaunchKernelGGL(k2a, dim3(18, NW / 64), dim3(256), 0, stream,
                               images, captions, ws + OFF_ATTN, n0, NW);
            hipLaunchKernelGGL(k2b, dim3(64, NW / 64), dim3(256), 0, stream,
                               images, captions, ws + OFF_ATTN, ws, ws + OFF_TS, n0 / 32, NW);
        }
    }

    hipLaunchKernelGGL(k3, dim3(4096), dim3(256), 0, stream,
                       ws + OFF_TS, (const ushort_t*)ws, b1, W2, b2, out);
    hipLaunchKernelGGL(k4, dim3(64), dim3(64), 0, stream, out, ws + OFF_W);
    hipLaunchKernelGGL(k5, dim3(2048), dim3(256), 0, stream, ws + OFF_TS, ws, bmu, blv, out);
}

// Round 13
// 332.188 us; speedup vs baseline: 1.2353x; 1.0446x over previous
//
#include <hip/hip_runtime.h>
#include <math.h>

#define LAM 9.0f
#define EPSF 1e-8f

typedef unsigned int uint;
typedef unsigned short ushort_t;
typedef __attribute__((ext_vector_type(8))) short short8;
typedef __attribute__((ext_vector_type(4))) float float4v;
typedef __attribute__((ext_vector_type(16))) float f32x16;

// ws layout (floats)
#define OFF_MMU 0                       // ushort planes: [hi 16384][lo 16384] per matrix
#define OFF_MLV (512*32)
#define OFF_M1  (2*512*32)
#define OFF_S   (3*512*32)              // 49152 : s[c][l] (64*32)
#define OFF_W   (OFF_S + 64*32)         // 51200 : (dead; k4 folded into k5)
#define OFF_QN  (OFF_W + 64*64)         // 55296 : qn[c][l][f] (64*32*32)
#define OFF_TS  (OFF_QN + 64*32*32)     // 120832: tnode_s[c][b][l][f] (64*64*32*32)
#define OFF_ATTN (OFF_TS + 64*64*32*32) // attn [2304][NW]
#define OFF_CVT  (OFF_ATTN + 2304*2048) // hi/lo bf16 arrays (ushort); REUSED by imgT2 after k2a

#define N_IMG_EL 2359296                // 2304*1024
#define N_CAP_EL 2097152                // 2048*1024
// imgT2 per plane (ushorts), 32x32x16-A-frag order: 64b * 32estep * 3kstep * 64lane * 8
#define IMGT2_EL 3145728

__device__ __forceinline__ ushort_t bf16_rne(float x) {
    uint u = __float_as_uint(x);
    uint r = (u + 0x7fffu + ((u >> 16) & 1u)) >> 16;
    return (ushort_t)r;
}
__device__ __forceinline__ float bf16_f(ushort_t h) {
    return __uint_as_float(((uint)h) << 16);
}
__device__ __forceinline__ uint pack2(ushort_t a, ushort_t b) {
    return (uint)a | ((uint)b << 16);
}

// ---------------- kcvt v2: split images+captions into hi/lo bf16 + fused qn --------------
__global__ __launch_bounds__(256) void kcvt(const float* __restrict__ img,
                                            const float* __restrict__ cap,
                                            ushort_t* __restrict__ dst,
                                            float* __restrict__ ws) {
    size_t i = (size_t)blockIdx.x * 256 + threadIdx.x;   // float4 index
    const float* src;
    ushort_t *H, *L;
    size_t base;
    bool is_cap = (i >= (N_IMG_EL / 4));
    if (!is_cap) {
        src = img; H = dst; L = dst + N_IMG_EL; base = i * 4;
    } else {
        src = cap; H = dst + 2 * (size_t)N_IMG_EL; L = H + N_CAP_EL; base = (i - N_IMG_EL / 4) * 4;
    }
    float4 v = *(const float4*)(src + base);
    float x[4] = {v.x, v.y, v.z, v.w};
    ushort_t hh[4], ll[4];
    #pragma unroll
    for (int j = 0; j < 4; j++) {
        hh[j] = bf16_rne(x[j]);
        ll[j] = bf16_rne(x[j] - bf16_f(hh[j]));
    }
    *(uint2*)(H + base) = make_uint2(pack2(hh[0], hh[1]), pack2(hh[2], hh[3]));
    *(uint2*)(L + base) = make_uint2(pack2(ll[0], ll[1]), pack2(ll[2], ll[3]));
    if (is_cap) {
        float q2 = x[0] * x[0] + x[1] * x[1] + x[2] * x[2] + x[3] * x[3];
        q2 += __shfl_xor(q2, 1);
        q2 += __shfl_xor(q2, 2);
        q2 += __shfl_xor(q2, 4);
        if ((threadIdx.x & 7) == 0) {
            size_t e = base;                // caption element index
            int c = (int)(e >> 15);
            int rem = (int)(e & 32767);
            int l = rem >> 10;
            int f = (rem & 1023) >> 5;
            ws[OFF_QN + c * 1024 + l * 32 + f] = sqrtf(q2);
        }
    }
}

// ---------------- kcvt2 v2: build imgT2 in 32x32x16 MFMA A-fragment order, hi/lo ----------
__global__ __launch_bounds__(256) void kcvt2(const float* __restrict__ img,
                                             ushort_t* __restrict__ dstH) {
    int b = blockIdx.x >> 3, ecg = blockIdx.x & 7;      // e-group: e = ecg*128 .. +127
    __shared__ float S[36][132];
    int t = threadIdx.x;
    for (int i = t; i < 1152; i += 256) {               // img[b][r][e-slice]
        int r = i >> 5, q = i & 31;
        *(float4*)&S[r][q * 4] = *(const float4*)(img + ((size_t)b * 36 + r) * 1024 + ecg * 128 + q * 4);
    }
    __syncthreads();
    int lane = t & 63, grp = t >> 6;
    int m = lane & 31, hi = lane >> 5;
    #pragma unroll
    for (int w2 = 0; w2 < 3; w2++) {
        int item = grp + w2 * 4;            // 0..11 = estepL(4) x ks3(3)
        int estepL = item / 3;
        int ks3 = item - estepL * 3;
        ushort_t hh[8], ll[8];
        #pragma unroll
        for (int j = 0; j < 8; j++) {
            int r = ks3 * 16 + hi * 8 + j;
            float v = (r < 36) ? S[r][estepL * 32 + m] : 0.f;
            hh[j] = bf16_rne(v);
            ll[j] = bf16_rne(v - bf16_f(hh[j]));
        }
        int estep = ecg * 4 + estepL;
        size_t off = ((((size_t)b * 32 + estep) * 3 + ks3) * 64 + lane) * 8;
        uint4 uh, ul;
        uh.x = pack2(hh[0], hh[1]); uh.y = pack2(hh[2], hh[3]);
        uh.z = pack2(hh[4], hh[5]); uh.w = pack2(hh[6], hh[7]);
        ul.x = pack2(ll[0], ll[1]); ul.y = pack2(ll[2], ll[3]);
        ul.z = pack2(ll[4], ll[5]); ul.w = pack2(ll[6], ll[7]);
        *(uint4*)(dstH + off) = uh;
        *(uint4*)(dstH + IMGT2_EL + off) = ul;
    }
}

// ---------------- k2a_mfma v4: GEMM + fused leaky+l2norm, gload_lds, XCD-local grid ------
__global__ __launch_bounds__(256) void k2a_mfma(const ushort_t* __restrict__ cvt,
                                                float* __restrict__ C) {
    const ushort_t* imgH = cvt;
    const ushort_t* imgL = cvt + N_IMG_EL;
    const ushort_t* capH = cvt + 2 * (size_t)N_IMG_EL;
    const ushort_t* capL = capH + N_CAP_EL;
    __shared__ ushort_t Ah[128][32], Al[128][32], Bh[64][32], Bl[64][32];
    int t = threadIdx.x, w = t >> 6, lane = t & 63;
    int quad = lane >> 4, mn = lane & 15;
    int m0 = blockIdx.y * 128, n0 = blockIdx.x * 64;
    float4v acc[2][4];
    #pragma unroll
    for (int i = 0; i < 2; i++)
        #pragma unroll
        for (int j = 0; j < 4; j++) acc[i][j] = (float4v){0.f, 0.f, 0.f, 0.f};

    for (int kc = 0; kc < 32; kc++) {
        #pragma unroll
        for (int j = 0; j < 6; j++) {
            int ch = t + j * 256;                   // 1536 16B chunks; branch is wave-uniform
            const ushort_t* src;
            ushort_t* dst;
            if (ch < 512) {
                int row = ch >> 2, seg = ch & 3;
                src = imgH + (size_t)(m0 + row) * 1024 + kc * 32 + seg * 8;
                dst = &Ah[0][0] + ch * 8;
            } else if (ch < 1024) {
                int r2 = ch - 512, row = r2 >> 2, seg = r2 & 3;
                src = imgL + (size_t)(m0 + row) * 1024 + kc * 32 + seg * 8;
                dst = &Al[0][0] + r2 * 8;
            } else if (ch < 1280) {
                int r2 = ch - 1024, row = r2 >> 2, seg = r2 & 3;
                src = capH + (size_t)(n0 + row) * 1024 + kc * 32 + seg * 8;
                dst = &Bh[0][0] + r2 * 8;
            } else {
                int r2 = ch - 1280, row = r2 >> 2, seg = r2 & 3;
                src = capL + (size_t)(n0 + row) * 1024 + kc * 32 + seg * 8;
                dst = &Bl[0][0] + r2 * 8;
            }
            __builtin_amdgcn_global_load_lds(
                (const __attribute__((address_space(1))) uint*)src,
                (__attribute__((address_space(3))) uint*)dst, 16, 0, 0);
        }
        __syncthreads();
        short8 ah[2], al[2];
        #pragma unroll
        for (int tm = 0; tm < 2; tm++) {
            ah[tm] = *(short8*)&Ah[w * 32 + tm * 16 + mn][quad * 8];
            al[tm] = *(short8*)&Al[w * 32 + tm * 16 + mn][quad * 8];
        }
        #pragma unroll
        for (int nt = 0; nt < 4; nt++) {
            short8 bh = *(short8*)&Bh[nt * 16 + mn][quad * 8];
            short8 bl = *(short8*)&Bl[nt * 16 + mn][quad * 8];
            #pragma unroll
            for (int tm = 0; tm < 2; tm++) {
                acc[tm][nt] = __builtin_amdgcn_mfma_f32_16x16x32_bf16(ah[tm], bh, acc[tm][nt], 0, 0, 0);
                acc[tm][nt] = __builtin_amdgcn_mfma_f32_16x16x32_bf16(ah[tm], bl, acc[tm][nt], 0, 0, 0);
                acc[tm][nt] = __builtin_amdgcn_mfma_f32_16x16x32_bf16(al[tm], bh, acc[tm][nt], 0, 0, 0);
            }
        }
        __syncthreads();
    }
    // epilogue: leaky, then l2norm over cols 0-31 (cap A) and 32-63 (cap B) per row.
    #pragma unroll
    for (int tm = 0; tm < 2; tm++)
        #pragma unroll
        for (int nt = 0; nt < 4; nt++)
            #pragma unroll
            for (int r = 0; r < 4; r++) {
                float v = acc[tm][nt][r];
                acc[tm][nt][r] = (v >= 0.f) ? v : 0.1f * v;
            }
    float invA[2][4], invB[2][4];
    #pragma unroll
    for (int tm = 0; tm < 2; tm++)
        #pragma unroll
        for (int r = 0; r < 4; r++) {
            float ssA = acc[tm][0][r] * acc[tm][0][r] + acc[tm][1][r] * acc[tm][1][r];
            float ssB = acc[tm][2][r] * acc[tm][2][r] + acc[tm][3][r] * acc[tm][3][r];
            #pragma unroll
            for (int off = 1; off < 16; off <<= 1) {
                ssA += __shfl_xor(ssA, off);
                ssB += __shfl_xor(ssB, off);
            }
            invA[tm][r] = 1.f / (sqrtf(ssA) + EPSF);
            invB[tm][r] = 1.f / (sqrtf(ssB) + EPSF);
        }
    #pragma unroll
    for (int tm = 0; tm < 2; tm++)
        #pragma unroll
        for (int nt = 0; nt < 4; nt++)
            #pragma unroll
            for (int r = 0; r < 4; r++) {
                int mrow = m0 + w * 32 + tm * 16 + quad * 4 + r;
                int ncol = n0 + nt * 16 + mn;
                float sc = (nt < 2) ? invA[tm][r] : invB[tm][r];
                C[(size_t)mrow * 2048 + ncol] = acc[tm][nt][r] * sc;
            }
}

// ---------------- kpre1: fused kpre (blocks 0-191) + k1 (blocks 192-255) -----------------
__global__ __launch_bounds__(256) void kpre1(const float* __restrict__ Wmu,
                                             const float* __restrict__ Wlv,
                                             const float* __restrict__ W1,
                                             const float* __restrict__ Wgc,
                                             const float* __restrict__ captions,
                                             const int* __restrict__ depends,
                                             float* __restrict__ ws,
                                             int do_qn) {
    int t = threadIdx.x;
    if (blockIdx.x < 192) {
        // ---- kpre path ----
        int m = blockIdx.x >> 6;            // 0..2
        int hg = blockIdx.x & 63;           // 0..63
        int h0 = hg * 8;
        const float* W = (m == 0) ? Wmu : (m == 1) ? Wlv : W1;
        __shared__ float Gs[64][32];
        __shared__ float Ws[8][68];
        int h = t >> 5, f = t & 31;
        float acc = 0.f;
        for (int kc = 0; kc < 8; kc++) {
            for (int i = t; i < 512; i += 256) {
                int row = i >> 3, c4 = i & 7;
                *(float4*)&Gs[row][c4 * 4] = *(const float4*)(Wgc + (kc * 64 + row) * 32 + c4 * 4);
            }
            if (t < 128) {
                int hh = t >> 4, c4 = t & 15;
                *(float4*)&Ws[hh][c4 * 4] = *(const float4*)(W + (size_t)(h0 + hh) * 512 + kc * 64 + c4 * 4);
            }
            __syncthreads();
            #pragma unroll 4
            for (int k = 0; k < 64; k++) acc += Ws[h][k] * Gs[k][f];
            __syncthreads();
        }
        ushort_t* Mb = (ushort_t*)ws + m * 32768;       // [hi 16384][lo 16384]
        ushort_t hi = bf16_rne(acc);
        ushort_t lo = bf16_rne(acc - bf16_f(hi));
        Mb[(h0 + h) * 32 + f] = hi;
        Mb[16384 + (h0 + h) * 32 + f] = lo;
        return;
    }
    // ---- k1 path ----
    int c = blockIdx.x - 192;
    __shared__ float caps[32][65];
    __shared__ float G[32][33];
    __shared__ float adj[32][33];
    int l2 = t & 31, l1_0 = t >> 5;
    float acc[4] = {0.f, 0.f, 0.f, 0.f};
    const float* cap = captions + (size_t)c * 32 * 1024;

    for (int kc = 0; kc < 16; kc++) {
        for (int i = t; i < 512; i += 256) {
            int ll = i >> 4, q = i & 15;
            float4 v = *(const float4*)(cap + ll * 1024 + kc * 64 + q * 4);
            caps[ll][q * 4 + 0] = v.x; caps[ll][q * 4 + 1] = v.y;
            caps[ll][q * 4 + 2] = v.z; caps[ll][q * 4 + 3] = v.w;
        }
        __syncthreads();
        #pragma unroll 4
        for (int k = 0; k < 64; k++) {
            float cv = caps[l2][k];
            #pragma unroll
            for (int i = 0; i < 4; i++) acc[i] += caps[l1_0 + 8 * i][k] * cv;
        }
        __syncthreads();
    }
    #pragma unroll
    for (int i = 0; i < 4; i++) G[l1_0 + 8 * i][l2] = acc[i];
    for (int i = t; i < 32 * 33; i += 256) ((float*)adj)[i] = 0.f;
    __syncthreads();

    if (t < 32) {
        float mx = -1e30f;
        for (int n = 0; n < 32; n++) mx = fmaxf(mx, LAM * G[t][n]);
        float sum = 0.f;
        for (int n = 0; n < 32; n++) { float p = __expf(LAM * G[t][n] - mx); G[t][n] = p; sum += p; }
        float inv = 1.f / sum;
        for (int n = 0; n < 32; n++) G[t][n] *= inv;
    }
    __syncthreads();
    if (t >= 1 && t < 30) {
        int d0 = depends[c * 60 + t * 2 + 0];
        int d1 = depends[c * 60 + t * 2 + 1];
        adj[d0][d1] = 1.f;
        adj[d1][d0] = 1.f;
    }
    __syncthreads();
    if (t < 32) adj[t][t] += 1.f;
    __syncthreads();
    if (t < 32) {
        float ss = 0.f, sw = 0.f;
        for (int n = 0; n < 32; n++) { float mm = adj[t][n] * G[t][n]; ss += mm * mm; }
        float inv = 1.f / (sqrtf(ss) + EPSF);
        for (int n = 0; n < 32; n++) sw += adj[t][n] * G[t][n] * adj[t][n];
        ws[OFF_S + c * 32 + t] = sw * inv;
    }
    if (do_qn) {
        for (int p = t; p < 1024; p += 256) {
            int l = p >> 5, f = p & 31;
            const float* cp = cap + (size_t)l * 1024 + f * 32;
            float q2 = 0.f;
            #pragma unroll
            for (int q = 0; q < 8; q++) {
                float4 v = *(const float4*)(cp + q * 4);
                q2 += v.x * v.x + v.y * v.y + v.z * v.z + v.w * v.w;
            }
            ws[OFF_QN + c * 1024 + p] = sqrtf(q2);
        }
    }
}

// ---------------- k2a (fp32 fallback) ----------------
__global__ __launch_bounds__(256) void k2a(const float* __restrict__ A,
                                           const float* __restrict__ Bm,
                                           float* __restrict__ C,
                                           int n0, int NW) {
    __shared__ float As[16][132];
    __shared__ float Bs[16][68];
    int m0 = blockIdx.x * 128;
    int nb0 = n0 + blockIdx.y * 64;
    int t = threadIdx.x;
    int tm = t >> 4, tn = t & 15;
    float acc[8][4] = {};
    for (int kc = 0; kc < 64; kc++) {
        #pragma unroll
        for (int j = 0; j < 2; j++) {
            int idx = t + j * 256;
            int row = idx >> 2, kq = idx & 3;
            float4 v = *(const float4*)(A + (size_t)(m0 + row) * 1024 + kc * 16 + kq * 4);
            As[kq * 4 + 0][row] = v.x; As[kq * 4 + 1][row] = v.y;
            As[kq * 4 + 2][row] = v.z; As[kq * 4 + 3][row] = v.w;
        }
        {
            int row = t >> 2, kq = t & 3;
            float4 v = *(const float4*)(Bm + (size_t)(nb0 + row) * 1024 + kc * 16 + kq * 4);
            Bs[kq * 4 + 0][row] = v.x; Bs[kq * 4 + 1][row] = v.y;
            Bs[kq * 4 + 2][row] = v.z; Bs[kq * 4 + 3][row] = v.w;
        }
        __syncthreads();
        #pragma unroll
        for (int kk = 0; kk < 16; kk++) {
            float a0[4], a1[4], bb[4];
            *(float4*)a0 = *(float4*)&As[kk][tm * 8];
            *(float4*)a1 = *(float4*)&As[kk][tm * 8 + 4];
            *(float4*)bb = *(float4*)&Bs[kk][tn * 4];
            #pragma unroll
            for (int i = 0; i < 4; i++)
                #pragma unroll
                for (int j2 = 0; j2 < 4; j2++) {
                    acc[i][j2]     += a0[i] * bb[j2];
                    acc[i + 4][j2] += a1[i] * bb[j2];
                }
        }
        __syncthreads();
    }
    int cw0 = nb0 - n0 + tn * 4;
    #pragma unroll
    for (int i = 0; i < 8; i++) {
        float4 v = make_float4(acc[i][0], acc[i][1], acc[i][2], acc[i][3]);
        *(float4*)(C + (size_t)(m0 + tm * 8 + i) * NW + cw0) = v;
    }
}

// ---------------- k2bm v16: v13 structure minus leaky/l2norm (VERIFIED 75.3us) ------------
__global__ __launch_bounds__(64) void k2bm(const ushort_t* __restrict__ imgT,
                                           const float* __restrict__ captions,
                                           const float* __restrict__ attn,
                                           const float* __restrict__ ws,
                                           float* __restrict__ ts_out) {
    int orig = blockIdx.x;
    int fh = orig >> 10;                        // 0..1
    int rest = orig & 1023;
    int cpair = rest >> 5;                      // 0..31
    int bp = rest & 31;                         // 0..31 ; XCD = bp%8
    int b0 = bp * 2;
    int c0 = cpair * 2;
    __shared__ union {
        float A[2][2][36][33];                  // [bi][ci][r][l] attn tiles (phase 1), pad 33
        float T[2][2][16][33];                  // [bi][ci][fl][l] tnode half-tiles (phase 2)
    } u;
    int t = threadIdx.x;
    int l = t & 31, hi = t >> 5;

    // phase 0: load 4 attn tiles (2 b x 2 ci) — already leaky+l2norm'd
    for (int i = t; i < 1152; i += 64) {
        int bi = i >= 576;
        int i2 = i - bi * 576;
        int ci = i2 >= 288;
        int i3 = i2 - ci * 288;
        int r = i3 >> 3, q = i3 & 7;
        *(float4*)&u.A[bi][ci][r][q * 4] =
            *(const float4*)(attn + (size_t)((b0 + bi) * 36 + r) * 2048 + (c0 + ci) * 32 + q * 4);
    }
    __syncthreads();
    for (int i = t; i < 128; i += 64) {         // softmax over regions per (bi, ci, word)
        int bi = i >= 64;
        int i2 = i & 63;
        int ci = i2 >> 5, ll = i2 & 31;
        float mx = -1e30f;
        for (int r = 0; r < 36; r++) mx = fmaxf(mx, u.A[bi][ci][r][ll]);
        mx *= LAM;
        float sum = 0.f;
        for (int r = 0; r < 36; r++) { float p = __expf(LAM * u.A[bi][ci][r][ll] - mx); u.A[bi][ci][r][ll] = p; sum += p; }
        float inv = 1.f / sum;
        for (int r = 0; r < 36; r++) u.A[bi][ci][r][ll] *= inv;
    }
    __syncthreads();

    // B-frags (k=r, n=l), 32x32x16 layout: n=lane&31, k=(lane>>5)*8+j
    short8 bh[2][2][3], bl[2][2][3];            // [bi][ci][kstep]
    #pragma unroll
    for (int bi = 0; bi < 2; bi++)
        #pragma unroll
        for (int ci = 0; ci < 2; ci++)
            #pragma unroll
            for (int k3 = 0; k3 < 3; k3++) {
                union { short8 v; ushort_t u8[8]; } H, L;
                #pragma unroll
                for (int j = 0; j < 8; j++) {
                    int r = k3 * 16 + hi * 8 + j;
                    float v = (r < 36) ? u.A[bi][ci][r][l] : 0.f;
                    ushort_t hv = bf16_rne(v);
                    H.u8[j] = hv;
                    L.u8[j] = bf16_rne(v - bf16_f(hv));
                }
                bh[bi][ci][k3] = H.v;
                bl[bi][ci][k3] = L.v;
            }
    __syncthreads();                            // A dead; union space becomes T

    const ushort_t* ibH0 = imgT + (size_t)b0 * 49152;   // ((f*3 + k3)*64 + lane)*8
    const ushort_t* ibL0 = ibH0 + IMGT2_EL;
    const ushort_t* ibH1 = ibH0 + 49152;
    const ushort_t* ibL1 = ibL0 + 49152;
    const float* qnp = ws + OFF_QN;
    float sv[2];
    sv[0] = ws[OFF_S + c0 * 32 + l];
    sv[1] = ws[OFF_S + (c0 + 1) * 32 + l];
    const float* capb[2];
    capb[0] = captions + (size_t)c0 * 32768 + (size_t)l * 1024 + hi * 4;
    capb[1] = capb[0] + 32768;

    for (int fl = 0; fl < 16; fl++) {
        int f = fh * 16 + fl;
        // A-frags for BOTH b's, all k-steps (imgT; shared across the 2 captions)
        short8 aA[2][3], aB[2][3];              // [plane hi/lo][k3]
        #pragma unroll
        for (int k3 = 0; k3 < 3; k3++) {
            size_t off = ((size_t)(f * 3 + k3) * 64 + t) * 8;
            aA[0][k3] = *(const short8*)(ibH0 + off);
            aA[1][k3] = *(const short8*)(ibL0 + off);
            aB[0][k3] = *(const short8*)(ibH1 + off);
            aB[1][k3] = *(const short8*)(ibL1 + off);
        }
        #pragma unroll
        for (int ci = 0; ci < 2; ci++) {
            // caption values loaded ONCE, used for both b's (the demand halving)
            float4 cv[4];
            #pragma unroll
            for (int g = 0; g < 4; g++) cv[g] = *(const float4*)(capb[ci] + f * 32 + g * 8);
            f32x16 accA = {0.f,0.f,0.f,0.f,0.f,0.f,0.f,0.f,0.f,0.f,0.f,0.f,0.f,0.f,0.f,0.f};
            f32x16 accB = {0.f,0.f,0.f,0.f,0.f,0.f,0.f,0.f,0.f,0.f,0.f,0.f,0.f,0.f,0.f,0.f};
            #pragma unroll
            for (int k3 = 0; k3 < 3; k3++) {
                accA = __builtin_amdgcn_mfma_f32_32x32x16_bf16(aA[0][k3], bh[0][ci][k3], accA, 0, 0, 0);
                accA = __builtin_amdgcn_mfma_f32_32x32x16_bf16(aA[0][k3], bl[0][ci][k3], accA, 0, 0, 0);
                accA = __builtin_amdgcn_mfma_f32_32x32x16_bf16(aA[1][k3], bh[0][ci][k3], accA, 0, 0, 0);
                accB = __builtin_amdgcn_mfma_f32_32x32x16_bf16(aB[0][k3], bh[1][ci][k3], accB, 0, 0, 0);
                accB = __builtin_amdgcn_mfma_f32_32x32x16_bf16(aB[0][k3], bl[1][ci][k3], accB, 0, 0, 0);
                accB = __builtin_amdgcn_mfma_f32_32x32x16_bf16(aB[1][k3], bh[1][ci][k3], accB, 0, 0, 0);
            }
            // lane holds wctxT[e_loc=(reg&3)+8*(reg>>2)+4*hi][l]; cv[g] covers e_loc=g*8+4*hi+0..3
            float numA = 0.f, w2A = 0.f, numB = 0.f, w2B = 0.f;
            #pragma unroll
            for (int g = 0; g < 4; g++) {
                numA += cv[g].x * accA[g*4+0] + cv[g].y * accA[g*4+1]
                      + cv[g].z * accA[g*4+2] + cv[g].w * accA[g*4+3];
                w2A  += accA[g*4+0]*accA[g*4+0] + accA[g*4+1]*accA[g*4+1]
                      + accA[g*4+2]*accA[g*4+2] + accA[g*4+3]*accA[g*4+3];
                numB += cv[g].x * accB[g*4+0] + cv[g].y * accB[g*4+1]
                      + cv[g].z * accB[g*4+2] + cv[g].w * accB[g*4+3];
                w2B  += accB[g*4+0]*accB[g*4+0] + accB[g*4+1]*accB[g*4+1]
                      + accB[g*4+2]*accB[g*4+2] + accB[g*4+3]*accB[g*4+3];
            }
            numA += __shfl_xor(numA, 32); w2A += __shfl_xor(w2A, 32);
            numB += __shfl_xor(numB, 32); w2B += __shfl_xor(w2B, 32);
            if (hi == 0) {
                float qv = qnp[(c0 + ci) * 1024 + l * 32 + f];   // b-independent
                float denA = fmaxf(qv * sqrtf(w2A), EPSF);
                u.T[0][ci][fl][l] = (numA / denA) * sv[ci];
                float denB = fmaxf(qv * sqrtf(w2B), EPSF);
                u.T[1][ci][fl][l] = (numB / denB) * sv[ci];
            }
        }
    }
    __syncthreads();
    // burst: 2b x 2ci x 32l x 16f floats -> ts_out (transpose-read from T)
    #pragma unroll
    for (int j = 0; j < 8; j++) {
        int id = t + j * 64;                    // 0..511 float4-items
        int bi = id >> 8;
        int ci = (id >> 7) & 1;
        int r2 = id & 127;
        int ll = r2 >> 2, q = r2 & 3;
        float4 v;
        v.x = u.T[bi][ci][q * 4 + 0][ll];
        v.y = u.T[bi][ci][q * 4 + 1][ll];
        v.z = u.T[bi][ci][q * 4 + 2][ll];
        v.w = u.T[bi][ci][q * 4 + 3][ll];
        *(float4*)(ts_out + ((size_t)(c0 + ci) * 64 + b0 + bi) * 1024 + ll * 32 + fh * 16 + q * 4) = v;
    }
}

// ---------------- k2b (fp32 fallback, validated R4 version) ----------------
__global__ __launch_bounds__(256) void k2b(const float* __restrict__ images,
                                           const float* __restrict__ captions,
                                           const float* __restrict__ attn,
                                           const float* __restrict__ ws,
                                           float* __restrict__ ts_out,
                                           int c0, int NW) {
    int b = blockIdx.x;
    int cw = blockIdx.y;
    int ca = c0 + cw * 2;
    __shared__ float A2[2][36][36];
    __shared__ float Ims[36][256];
    __shared__ float scs[2][32];
    const float* img = images + (size_t)b * 36 * 1024;
    int t = threadIdx.x;
    int el = t & 63;
    int lg = t >> 6;

    for (int i = t; i < 576; i += 256) {
        int r = i >> 4, q = i & 15;
        float4 v = *(const float4*)(attn + (size_t)(b * 36 + r) * NW + cw * 64 + q * 4);
        *(float4*)&A2[q >> 3][r][(q & 7) * 4] = v;
    }
    __syncthreads();
    if (t < 72) {
        int ci = t >= 36, r = t - 36 * ci;
        float ss = 0.f;
        #pragma unroll
        for (int l = 0; l < 32; l++) {
            float v = A2[ci][r][l];
            v = (v >= 0.f) ? v : 0.1f * v;
            A2[ci][r][l] = v; ss += v * v;
        }
        float inv = 1.f / (sqrtf(ss) + EPSF);
        #pragma unroll
        for (int l = 0; l < 32; l++) A2[ci][r][l] *= inv;
    }
    __syncthreads();
    if (t < 64) {
        int ci = t >> 5, l = t & 31;
        float mx = -1e30f;
        for (int r = 0; r < 36; r++) mx = fmaxf(mx, A2[ci][r][l]);
        mx *= LAM;
        float sum = 0.f;
        for (int r = 0; r < 36; r++) { float p = __expf(LAM * A2[ci][r][l] - mx); A2[ci][r][l] = p; sum += p; }
        float inv = 1.f / sum;
        for (int r = 0; r < 36; r++) A2[ci][r][l] *= inv;
    } else if (t >= 128 && t < 192) {
        int i = t - 128;
        scs[i >> 5][i & 31] = ws[OFF_S + (ca + (i >> 5)) * 32 + (i & 31)];
    }
    __syncthreads();

    const float* qn = ws + OFF_QN;
    for (int g = 0; g < 4; g++) {
        for (int i = t; i < 2304; i += 256) {
            int r = i >> 6, q = i & 63;
            *(float4*)&Ims[r][q * 4] = *(const float4*)(img + (size_t)r * 1024 + g * 256 + q * 4);
        }
        __syncthreads();

        float acc[2][8][4] = {};
        #pragma unroll 2
        for (int r = 0; r < 36; r++) {
            float4 iv = *(float4*)&Ims[r][el * 4];
            float ivv[4] = {iv.x, iv.y, iv.z, iv.w};
            #pragma unroll
            for (int ci = 0; ci < 2; ci++) {
                float av[8];
                *(float4*)&av[0] = *(float4*)&A2[ci][r][lg * 8];
                *(float4*)&av[4] = *(float4*)&A2[ci][r][lg * 8 + 4];
                #pragma unroll
                for (int i = 0; i < 8; i++)
                    #pragma unroll
                    for (int e = 0; e < 4; e++)
                        acc[ci][i][e] += av[i] * ivv[e];
            }
        }

        int fb = el >> 3;
        int f = g * 8 + fb;
        #pragma unroll
        for (int ci = 0; ci < 2; ci++) {
            int c = ca + ci;
            const float* cap = captions + (size_t)c * 32 * 1024 + g * 256;
            #pragma unroll
            for (int i = 0; i < 8; i++) {
                int l = lg * 8 + i;
                float4 cv = *(const float4*)(cap + (size_t)l * 1024 + el * 4);
                float num = cv.x * acc[ci][i][0] + cv.y * acc[ci][i][1]
                          + cv.z * acc[ci][i][2] + cv.w * acc[ci][i][3];
                float w2 = acc[ci][i][0] * acc[ci][i][0] + acc[ci][i][1] * acc[ci][i][1]
                         + acc[ci][i][2] * acc[ci][i][2] + acc[ci][i][3] * acc[ci][i][3];
                num += __shfl_down(num, 4); w2 += __shfl_down(w2, 4);
                num += __shfl_down(num, 2); w2 += __shfl_down(w2, 2);
                num += __shfl_down(num, 1); w2 += __shfl_down(w2, 1);
                if ((el & 7) == 0) {
                    float den = fmaxf(qn[c * 1024 + l * 32 + f] * sqrtf(w2), EPSF);
                    ts_out[(((size_t)c * 64 + b) * 32 + l) * 32 + f] = (num / den) * scs[ci][l];
                }
            }
        }
        __syncthreads();
    }
}

// ---------------- k3 (MFMA): similarities[b][c] = mean_l W2·tanh(ts@M1^T + b1) + b2 ----------------
__global__ __launch_bounds__(256) void k3(const float* __restrict__ ts_ws,
                                          const ushort_t* __restrict__ Mb,
                                          const float* __restrict__ b1,
                                          const float* __restrict__ W2,
                                          const float* __restrict__ b2,
                                          float* __restrict__ out_sim) {
    int c = blockIdx.x >> 6, b = blockIdx.x & 63;
    __shared__ ushort_t tsh[32][32], tsl[32][32];
    __shared__ float red[4];
    int t = threadIdx.x;
    const float* tsrc = ts_ws + (size_t)(c * 64 + b) * 1024;
    {
        int row = t >> 3, q = t & 7;
        float4 v = *(const float4*)(tsrc + row * 32 + q * 4);
        float x[4] = {v.x, v.y, v.z, v.w};
        ushort_t hh[4], ll[4];
        #pragma unroll
        for (int j = 0; j < 4; j++) {
            hh[j] = bf16_rne(x[j]);
            ll[j] = bf16_rne(x[j] - bf16_f(hh[j]));
        }
        *(uint2*)&tsh[row][q * 4] = make_uint2(pack2(hh[0], hh[1]), pack2(hh[2], hh[3]));
        *(uint2*)&tsl[row][q * 4] = make_uint2(pack2(ll[0], ll[1]), pack2(ll[2], ll[3]));
    }
    __syncthreads();
    int w = t >> 6, lane = t & 63, quad = lane >> 4, mn = lane & 15;
    const ushort_t* M1H = Mb + 65536;
    short8 ah[2], al[2];
    #pragma unroll
    for (int mt = 0; mt < 2; mt++) {
        ah[mt] = *(short8*)&tsh[mt * 16 + mn][quad * 8];
        al[mt] = *(short8*)&tsl[mt * 16 + mn][quad * 8];
    }
    float psum = 0.f;
    #pragma unroll
    for (int nt = 0; nt < 8; nt++) {
        int h = w * 128 + nt * 16 + mn;
        short8 bh = *(const short8*)(M1H + h * 32 + quad * 8);
        short8 bl = *(const short8*)(M1H + 16384 + h * 32 + quad * 8);
        float b1v = b1[h], w2v = W2[h];
        #pragma unroll
        for (int mt = 0; mt < 2; mt++) {
            float4v acc = (float4v){0.f, 0.f, 0.f, 0.f};
            acc = __builtin_amdgcn_mfma_f32_16x16x32_bf16(ah[mt], bh, acc, 0, 0, 0);
            acc = __builtin_amdgcn_mfma_f32_16x16x32_bf16(ah[mt], bl, acc, 0, 0, 0);
            acc = __builtin_amdgcn_mfma_f32_16x16x32_bf16(al[mt], bh, acc, 0, 0, 0);
            #pragma unroll
            for (int r = 0; r < 4; r++) {
                float x = fminf(fmaxf(acc[r] + b1v, -15.f), 15.f);
                float e2 = __expf(2.f * x);
                psum += (1.f - 2.f / (e2 + 1.f)) * w2v;
            }
        }
    }
    #pragma unroll
    for (int off = 32; off >= 1; off >>= 1) psum += __shfl_down(psum, off);
    if (lane == 0) red[w] = psum;
    __syncthreads();
    if (t == 0) out_sim[b * 64 + c] = b2[0] + (red[0] + red[1] + red[2] + red[3]) * (1.f / 32.f);
}

// ---------------- k5 v2 (MFMA): k4 softmax folded in; block per (b,l), 256 threads --------
__global__ __launch_bounds__(256) void k5(const float* __restrict__ ts_ws,
                                          const float* __restrict__ ws,
                                          const float* __restrict__ b_mu,
                                          const float* __restrict__ b_lv,
                                          float* __restrict__ out) {
    int b = blockIdx.x >> 5, l = blockIdx.x & 31;
    int t = threadIdx.x;
    __shared__ ushort_t tsh[64][32], tsl[64][32];
    __shared__ float wls[64];
    {
        int cc = t >> 2, q = t & 3;
        const float* src = ts_ws + (((size_t)cc * 64 + b) * 32 + l) * 32 + q * 8;
        #pragma unroll
        for (int half = 0; half < 2; half++) {
            float4 v = *(const float4*)(src + half * 4);
            float x[4] = {v.x, v.y, v.z, v.w};
            ushort_t hh[4], ll[4];
            #pragma unroll
            for (int j = 0; j < 4; j++) {
                hh[j] = bf16_rne(x[j]);
                ll[j] = bf16_rne(x[j] - bf16_f(hh[j]));
            }
            *(uint2*)&tsh[cc][q * 8 + half * 4] = make_uint2(pack2(hh[0], hh[1]), pack2(hh[2], hh[3]));
            *(uint2*)&tsl[cc][q * 8 + half * 4] = make_uint2(pack2(ll[0], ll[1]), pack2(ll[2], ll[3]));
        }
    }
    if (t < 64) {                                // folded k4: softmax over c for this b
        float v = out[b * 64 + t];
        float mx = v;
        #pragma unroll
        for (int off = 32; off >= 1; off >>= 1) mx = fmaxf(mx, __shfl_xor(mx, off));
        float p = __expf(v - mx);
        float sum = p;
        #pragma unroll
        for (int off = 32; off >= 1; off >>= 1) sum += __shfl_xor(sum, off);
        wls[t] = p / sum;
    }
    __syncthreads();

    int w = t >> 6, lane = t & 63, quad = lane >> 4, mn = lane & 15;
    const ushort_t* Mb = (const ushort_t*)ws;
    const ushort_t* MmuH = Mb;
    const ushort_t* MlvH = Mb + 32768;
    short8 ah[4], al[4];
    #pragma unroll
    for (int mt = 0; mt < 4; mt++) {
        ah[mt] = *(short8*)&tsh[mt * 16 + mn][quad * 8];
        al[mt] = *(short8*)&tsl[mt * 16 + mn][quad * 8];
    }
    float pm[8], pq[8], pe[8];
    #pragma unroll
    for (int nt = 0; nt < 8; nt++) {
        int h = w * 128 + nt * 16 + mn;
        {
            short8 bh = *(const short8*)(MmuH + h * 32 + quad * 8);
            short8 bl = *(const short8*)(MmuH + 16384 + h * 32 + quad * 8);
            float bmv = b_mu[h];
            float am = 0.f, aq = 0.f;
            #pragma unroll
            for (int mt = 0; mt < 4; mt++) {
                float4v acc = (float4v){0.f, 0.f, 0.f, 0.f};
                acc = __builtin_amdgcn_mfma_f32_16x16x32_bf16(ah[mt], bh, acc, 0, 0, 0);
                acc = __builtin_amdgcn_mfma_f32_16x16x32_bf16(ah[mt], bl, acc, 0, 0, 0);
                acc = __builtin_amdgcn_mfma_f32_16x16x32_bf16(al[mt], bh, acc, 0, 0, 0);
                #pragma unroll
                for (int r = 0; r < 4; r++) {
                    int cc = mt * 16 + quad * 4 + r;
                    float mu = acc[r] + bmv;
                    float wv = wls[cc];
                    am += wv * mu;
                    aq += wv * mu * mu;
                }
            }
            am += __shfl_xor(am, 16); am += __shfl_xor(am, 32);
            aq += __shfl_xor(aq, 16); aq += __shfl_xor(aq, 32);
            pm[nt] = am; pq[nt] = aq;
        }
        {
            short8 bh = *(const short8*)(MlvH + h * 32 + quad * 8);
            short8 bl = *(const short8*)(MlvH + 16384 + h * 32 + quad * 8);
            float blv = b_lv[h];
            float ae = 0.f;
            #pragma unroll
            for (int mt = 0; mt < 4; mt++) {
                float4v acc = (float4v){0.f, 0.f, 0.f, 0.f};
                acc = __builtin_amdgcn_mfma_f32_16x16x32_bf16(ah[mt], bh, acc, 0, 0, 0);
                acc = __builtin_amdgcn_mfma_f32_16x16x32_bf16(ah[mt], bl, acc, 0, 0, 0);
                acc = __builtin_amdgcn_mfma_f32_16x16x32_bf16(al[mt], bh, acc, 0, 0, 0);
                #pragma unroll
                for (int r = 0; r < 4; r++) {
                    int cc = mt * 16 + quad * 4 + r;
                    ae += wls[cc] * __expf(acc[r] + blv);
                }
            }
            ae += __shfl_xor(ae, 16); ae += __shfl_xor(ae, 32);
            pe[nt] = ae;
        }
    }
    if (quad == 0) {
        #pragma unroll
        for (int nt = 0; nt < 8; nt++) {
            int h = w * 128 + nt * 16 + mn;
            size_t idx = (size_t)(b * 32 + l) * 512 + h;
            float m = pm[nt];
            out[4096 + idx] = m;
            float var = pe[nt] + pq[nt] - m * m;
            out[4096 + 64 * 32 * 512 + idx] = sqrtf(fmaxf(var, 1e-8f));
        }
    }
}

extern "C" void kernel_launch(void* const* d_in, const int* in_sizes, int n_in,
                              void* d_out, int out_size, void* d_ws, size_t ws_size,
                              hipStream_t stream) {
    const float* images   = (const float*)d_in[0];
    const float* captions = (const float*)d_in[1];
    const int*   depends  = (const int*)d_in[2];
    const float* Wgc = (const float*)d_in[3];
    const float* Wmu = (const float*)d_in[4];
    const float* bmu = (const float*)d_in[5];
    const float* Wlv = (const float*)d_in[6];
    const float* blv = (const float*)d_in[7];
    const float* W1  = (const float*)d_in[8];
    const float* b1  = (const float*)d_in[9];
    const float* W2  = (const float*)d_in[10];
    const float* b2  = (const float*)d_in[11];
    float* out = (float*)d_out;
    float* ws  = (float*)d_ws;

    const size_t CVT_FLOATS = ((size_t)2 * N_IMG_EL + 2 * N_CAP_EL) / 2;
    size_t need_floats = (size_t)OFF_CVT + CVT_FLOATS;
    bool use_mfma = ws_size >= need_floats * 4;

    hipLaunchKernelGGL(kpre1, dim3(256), dim3(256), 0, stream,
                       Wmu, Wlv, W1, Wgc, captions, depends, ws, use_mfma ? 0 : 1);

    if (use_mfma) {
        ushort_t* cvt = (ushort_t*)(ws + OFF_CVT);
        hipLaunchKernelGGL(kcvt, dim3((N_IMG_EL + N_CAP_EL) / 4 / 256), dim3(256), 0, stream,
                           images, captions, cvt, ws);
        hipLaunchKernelGGL(k2a_mfma, dim3(32, 18), dim3(256), 0, stream, cvt, ws + OFF_ATTN);
        // CVT region dead after k2a_mfma; reuse for 32x32x16-frag imgT2 hi/lo (12.6MB <= 17.8MB)
        hipLaunchKernelGGL(kcvt2, dim3(512), dim3(256), 0, stream, images, cvt);
        hipLaunchKernelGGL(k2bm, dim3(2048), dim3(64), 0, stream,
                           cvt, captions, ws + OFF_ATTN, ws, ws + OFF_TS);
    } else {
        int NW = 2048;
        while (NW > 64 && ((size_t)OFF_ATTN + (size_t)2304 * NW) * 4 > ws_size) NW >>= 1;
        for (int n0 = 0; n0 < 2048; n0 += NW) {
            hipLaunchKernelGGL(k2a, dim3(18, NW / 64), dim3(256), 0, stream,
                               images, captions, ws + OFF_ATTN, n0, NW);
            hipLaunchKernelGGL(k2b, dim3(64, NW / 64), dim3(256), 0, stream,
                               images, captions, ws + OFF_ATTN, ws, ws + OFF_TS, n0 / 32, NW);
        }
    }

    hipLaunchKernelGGL(k3, dim3(4096), dim3(256), 0, stream,
                       ws + OFF_TS, (const ushort_t*)ws, b1, W2, b2, out);
    hipLaunchKernelGGL(k5, dim3(2048), dim3(256), 0, stream, ws + OFF_TS, ws, bmu, blv, out);
}

// Round 14
// 327.040 us; speedup vs baseline: 1.2548x; 1.0157x over previous
//
#include <hip/hip_runtime.h>
#include <math.h>

#define LAM 9.0f
#define EPSF 1e-8f

typedef unsigned int uint;
typedef unsigned short ushort_t;
typedef __attribute__((ext_vector_type(8))) short short8;
typedef __attribute__((ext_vector_type(4))) float float4v;
typedef __attribute__((ext_vector_type(16))) float f32x16;

// ws layout (floats)
#define OFF_MMU 0                       // ushort planes: [hi 16384][lo 16384] per matrix
#define OFF_MLV (512*32)
#define OFF_M1  (2*512*32)
#define OFF_S   (3*512*32)              // 49152 : s[c][l] (64*32)
#define OFF_W   (OFF_S + 64*32)         // 51200 : (dead; k4 folded into k5)
#define OFF_QN  (OFF_W + 64*64)         // 55296 : qn[c][l][f] (64*32*32)
#define OFF_TS  (OFF_QN + 64*32*32)     // 120832: tnode_s[c][b][l][f] (64*64*32*32)
#define OFF_ATTN (OFF_TS + 64*64*32*32) // attn [2304][NW]
#define OFF_CVT  (OFF_ATTN + 2304*2048) // hi/lo bf16 arrays (ushort)

#define N_IMG_EL 2359296                // 2304*1024
#define N_CAP_EL 2097152                // 2048*1024
#define CVT_FLOATS (((size_t)2 * N_IMG_EL + 2 * N_CAP_EL) / 2)
#define OFF_IMGT2 ((size_t)OFF_CVT + CVT_FLOATS)   // separate imgT2 buffer (fused path)
// imgT2 per plane (ushorts), 32x32x16-A-frag order: 64b * 32estep * 3kstep * 64lane * 8
#define IMGT2_EL 3145728

#define KCVT_BLOCKS  4352               // (N_IMG_EL+N_CAP_EL)/4/256
#define KCVT2_BLOCKS 512
#define KPRE1_BLOCKS 256

__device__ __forceinline__ ushort_t bf16_rne(float x) {
    uint u = __float_as_uint(x);
    uint r = (u + 0x7fffu + ((u >> 16) & 1u)) >> 16;
    return (ushort_t)r;
}
__device__ __forceinline__ float bf16_f(ushort_t h) {
    return __uint_as_float(((uint)h) << 16);
}
__device__ __forceinline__ uint pack2(ushort_t a, ushort_t b) {
    return (uint)a | ((uint)b << 16);
}

// ================= device helpers (shared by standalone + fused kernels) =================
__device__ void kcvt_body(int blk, const float* __restrict__ img,
                          const float* __restrict__ cap,
                          ushort_t* __restrict__ dst, float* __restrict__ ws) {
    size_t i = (size_t)blk * 256 + threadIdx.x;   // float4 index
    const float* src;
    ushort_t *H, *L;
    size_t base;
    bool is_cap = (i >= (N_IMG_EL / 4));
    if (!is_cap) {
        src = img; H = dst; L = dst + N_IMG_EL; base = i * 4;
    } else {
        src = cap; H = dst + 2 * (size_t)N_IMG_EL; L = H + N_CAP_EL; base = (i - N_IMG_EL / 4) * 4;
    }
    float4 v = *(const float4*)(src + base);
    float x[4] = {v.x, v.y, v.z, v.w};
    ushort_t hh[4], ll[4];
    #pragma unroll
    for (int j = 0; j < 4; j++) {
        hh[j] = bf16_rne(x[j]);
        ll[j] = bf16_rne(x[j] - bf16_f(hh[j]));
    }
    *(uint2*)(H + base) = make_uint2(pack2(hh[0], hh[1]), pack2(hh[2], hh[3]));
    *(uint2*)(L + base) = make_uint2(pack2(ll[0], ll[1]), pack2(ll[2], ll[3]));
    if (is_cap) {
        float q2 = x[0] * x[0] + x[1] * x[1] + x[2] * x[2] + x[3] * x[3];
        q2 += __shfl_xor(q2, 1);
        q2 += __shfl_xor(q2, 2);
        q2 += __shfl_xor(q2, 4);
        if ((threadIdx.x & 7) == 0) {
            size_t e = base;                // caption element index
            int c = (int)(e >> 15);
            int rem = (int)(e & 32767);
            int l = rem >> 10;
            int f = (rem & 1023) >> 5;
            ws[OFF_QN + c * 1024 + l * 32 + f] = sqrtf(q2);
        }
    }
}

__device__ void kcvt2_body(int blk, const float* __restrict__ img,
                           ushort_t* __restrict__ dstH) {
    int b = blk >> 3, ecg = blk & 7;                    // e-group: e = ecg*128 .. +127
    __shared__ float S[36][132];
    int t = threadIdx.x;
    for (int i = t; i < 1152; i += 256) {               // img[b][r][e-slice]
        int r = i >> 5, q = i & 31;
        *(float4*)&S[r][q * 4] = *(const float4*)(img + ((size_t)b * 36 + r) * 1024 + ecg * 128 + q * 4);
    }
    __syncthreads();
    int lane = t & 63, grp = t >> 6;
    int m = lane & 31, hi = lane >> 5;
    #pragma unroll
    for (int w2 = 0; w2 < 3; w2++) {
        int item = grp + w2 * 4;            // 0..11 = estepL(4) x ks3(3)
        int estepL = item / 3;
        int ks3 = item - estepL * 3;
        ushort_t hh[8], ll[8];
        #pragma unroll
        for (int j = 0; j < 8; j++) {
            int r = ks3 * 16 + hi * 8 + j;
            float v = (r < 36) ? S[r][estepL * 32 + m] : 0.f;
            hh[j] = bf16_rne(v);
            ll[j] = bf16_rne(v - bf16_f(hh[j]));
        }
        int estep = ecg * 4 + estepL;
        size_t off = ((((size_t)b * 32 + estep) * 3 + ks3) * 64 + lane) * 8;
        uint4 uh, ul;
        uh.x = pack2(hh[0], hh[1]); uh.y = pack2(hh[2], hh[3]);
        uh.z = pack2(hh[4], hh[5]); uh.w = pack2(hh[6], hh[7]);
        ul.x = pack2(ll[0], ll[1]); ul.y = pack2(ll[2], ll[3]);
        ul.z = pack2(ll[4], ll[5]); ul.w = pack2(ll[6], ll[7]);
        *(uint4*)(dstH + off) = uh;
        *(uint4*)(dstH + IMGT2_EL + off) = ul;
    }
}

__device__ void kpre1_body(int blk, const float* __restrict__ Wmu,
                           const float* __restrict__ Wlv,
                           const float* __restrict__ W1,
                           const float* __restrict__ Wgc,
                           const float* __restrict__ captions,
                           const int* __restrict__ depends,
                           float* __restrict__ ws, int do_qn) {
    int t = threadIdx.x;
    if (blk < 192) {
        // ---- kpre path ----
        int m = blk >> 6;                   // 0..2
        int hg = blk & 63;                  // 0..63
        int h0 = hg * 8;
        const float* W = (m == 0) ? Wmu : (m == 1) ? Wlv : W1;
        __shared__ float Gs[64][32];
        __shared__ float Ws[8][68];
        int h = t >> 5, f = t & 31;
        float acc = 0.f;
        for (int kc = 0; kc < 8; kc++) {
            for (int i = t; i < 512; i += 256) {
                int row = i >> 3, c4 = i & 7;
                *(float4*)&Gs[row][c4 * 4] = *(const float4*)(Wgc + (kc * 64 + row) * 32 + c4 * 4);
            }
            if (t < 128) {
                int hh = t >> 4, c4 = t & 15;
                *(float4*)&Ws[hh][c4 * 4] = *(const float4*)(W + (size_t)(h0 + hh) * 512 + kc * 64 + c4 * 4);
            }
            __syncthreads();
            #pragma unroll 4
            for (int k = 0; k < 64; k++) acc += Ws[h][k] * Gs[k][f];
            __syncthreads();
        }
        ushort_t* Mb = (ushort_t*)ws + m * 32768;       // [hi 16384][lo 16384]
        ushort_t hi = bf16_rne(acc);
        ushort_t lo = bf16_rne(acc - bf16_f(hi));
        Mb[(h0 + h) * 32 + f] = hi;
        Mb[16384 + (h0 + h) * 32 + f] = lo;
        return;
    }
    // ---- k1 path ----
    int c = blk - 192;
    __shared__ float caps[32][65];
    __shared__ float G[32][33];
    __shared__ float adj[32][33];
    int l2 = t & 31, l1_0 = t >> 5;
    float acc[4] = {0.f, 0.f, 0.f, 0.f};
    const float* cap = captions + (size_t)c * 32 * 1024;

    for (int kc = 0; kc < 16; kc++) {
        for (int i = t; i < 512; i += 256) {
            int ll = i >> 4, q = i & 15;
            float4 v = *(const float4*)(cap + ll * 1024 + kc * 64 + q * 4);
            caps[ll][q * 4 + 0] = v.x; caps[ll][q * 4 + 1] = v.y;
            caps[ll][q * 4 + 2] = v.z; caps[ll][q * 4 + 3] = v.w;
        }
        __syncthreads();
        #pragma unroll 4
        for (int k = 0; k < 64; k++) {
            float cv = caps[l2][k];
            #pragma unroll
            for (int i = 0; i < 4; i++) acc[i] += caps[l1_0 + 8 * i][k] * cv;
        }
        __syncthreads();
    }
    #pragma unroll
    for (int i = 0; i < 4; i++) G[l1_0 + 8 * i][l2] = acc[i];
    for (int i = t; i < 32 * 33; i += 256) ((float*)adj)[i] = 0.f;
    __syncthreads();

    if (t < 32) {
        float mx = -1e30f;
        for (int n = 0; n < 32; n++) mx = fmaxf(mx, LAM * G[t][n]);
        float sum = 0.f;
        for (int n = 0; n < 32; n++) { float p = __expf(LAM * G[t][n] - mx); G[t][n] = p; sum += p; }
        float inv = 1.f / sum;
        for (int n = 0; n < 32; n++) G[t][n] *= inv;
    }
    __syncthreads();
    if (t >= 1 && t < 30) {
        int d0 = depends[c * 60 + t * 2 + 0];
        int d1 = depends[c * 60 + t * 2 + 1];
        adj[d0][d1] = 1.f;
        adj[d1][d0] = 1.f;
    }
    __syncthreads();
    if (t < 32) adj[t][t] += 1.f;
    __syncthreads();
    if (t < 32) {
        float ss = 0.f, sw = 0.f;
        for (int n = 0; n < 32; n++) { float mm = adj[t][n] * G[t][n]; ss += mm * mm; }
        float inv = 1.f / (sqrtf(ss) + EPSF);
        for (int n = 0; n < 32; n++) sw += adj[t][n] * G[t][n] * adj[t][n];
        ws[OFF_S + c * 32 + t] = sw * inv;
    }
    if (do_qn) {
        for (int p = t; p < 1024; p += 256) {
            int l = p >> 5, f = p & 31;
            const float* cp = cap + (size_t)l * 1024 + f * 32;
            float q2 = 0.f;
            #pragma unroll
            for (int q = 0; q < 8; q++) {
                float4 v = *(const float4*)(cp + q * 4);
                q2 += v.x * v.x + v.y * v.y + v.z * v.z + v.w * v.w;
            }
            ws[OFF_QN + c * 1024 + p] = sqrtf(q2);
        }
    }
}

// ---------------- kfuse: kcvt (0..4351) + kcvt2 (4352..4863) + kpre1 (4864..5119) --------
// All three paths read only kernel inputs and write disjoint ws regions -> one launch.
// Requires separate imgT2 buffer at OFF_IMGT2 (runtime ws_size-gated on host).
__global__ __launch_bounds__(256) void kfuse(const float* __restrict__ img,
                                             const float* __restrict__ cap,
                                             ushort_t* __restrict__ cvt,
                                             ushort_t* __restrict__ imgT2,
                                             const float* __restrict__ Wmu,
                                             const float* __restrict__ Wlv,
                                             const float* __restrict__ W1,
                                             const float* __restrict__ Wgc,
                                             const int* __restrict__ depends,
                                             float* __restrict__ ws) {
    int blk = blockIdx.x;
    if (blk < KCVT_BLOCKS) {
        kcvt_body(blk, img, cap, cvt, ws);
    } else if (blk < KCVT_BLOCKS + KCVT2_BLOCKS) {
        kcvt2_body(blk - KCVT_BLOCKS, img, imgT2);
    } else {
        kpre1_body(blk - KCVT_BLOCKS - KCVT2_BLOCKS, Wmu, Wlv, W1, Wgc, cap, depends, ws, 0);
    }
}

// ---------------- standalone wrappers (fallback path) ----------------
__global__ __launch_bounds__(256) void kcvt(const float* __restrict__ img,
                                            const float* __restrict__ cap,
                                            ushort_t* __restrict__ dst,
                                            float* __restrict__ ws) {
    kcvt_body(blockIdx.x, img, cap, dst, ws);
}
__global__ __launch_bounds__(256) void kcvt2(const float* __restrict__ img,
                                             ushort_t* __restrict__ dstH) {
    kcvt2_body(blockIdx.x, img, dstH);
}
__global__ __launch_bounds__(256) void kpre1(const float* __restrict__ Wmu,
                                             const float* __restrict__ Wlv,
                                             const float* __restrict__ W1,
                                             const float* __restrict__ Wgc,
                                             const float* __restrict__ captions,
                                             const int* __restrict__ depends,
                                             float* __restrict__ ws,
                                             int do_qn) {
    kpre1_body(blockIdx.x, Wmu, Wlv, W1, Wgc, captions, depends, ws, do_qn);
}

// ---------------- k2a_mfma v4: GEMM + fused leaky+l2norm, gload_lds, XCD-local grid ------
__global__ __launch_bounds__(256) void k2a_mfma(const ushort_t* __restrict__ cvt,
                                                float* __restrict__ C) {
    const ushort_t* imgH = cvt;
    const ushort_t* imgL = cvt + N_IMG_EL;
    const ushort_t* capH = cvt + 2 * (size_t)N_IMG_EL;
    const ushort_t* capL = capH + N_CAP_EL;
    __shared__ ushort_t Ah[128][32], Al[128][32], Bh[64][32], Bl[64][32];
    int t = threadIdx.x, w = t >> 6, lane = t & 63;
    int quad = lane >> 4, mn = lane & 15;
    int m0 = blockIdx.y * 128, n0 = blockIdx.x * 64;
    float4v acc[2][4];
    #pragma unroll
    for (int i = 0; i < 2; i++)
        #pragma unroll
        for (int j = 0; j < 4; j++) acc[i][j] = (float4v){0.f, 0.f, 0.f, 0.f};

    for (int kc = 0; kc < 32; kc++) {
        #pragma unroll
        for (int j = 0; j < 6; j++) {
            int ch = t + j * 256;                   // 1536 16B chunks; branch is wave-uniform
            const ushort_t* src;
            ushort_t* dst;
            if (ch < 512) {
                int row = ch >> 2, seg = ch & 3;
                src = imgH + (size_t)(m0 + row) * 1024 + kc * 32 + seg * 8;
                dst = &Ah[0][0] + ch * 8;
            } else if (ch < 1024) {
                int r2 = ch - 512, row = r2 >> 2, seg = r2 & 3;
                src = imgL + (size_t)(m0 + row) * 1024 + kc * 32 + seg * 8;
                dst = &Al[0][0] + r2 * 8;
            } else if (ch < 1280) {
                int r2 = ch - 1024, row = r2 >> 2, seg = r2 & 3;
                src = capH + (size_t)(n0 + row) * 1024 + kc * 32 + seg * 8;
                dst = &Bh[0][0] + r2 * 8;
            } else {
                int r2 = ch - 1280, row = r2 >> 2, seg = r2 & 3;
                src = capL + (size_t)(n0 + row) * 1024 + kc * 32 + seg * 8;
                dst = &Bl[0][0] + r2 * 8;
            }
            __builtin_amdgcn_global_load_lds(
                (const __attribute__((address_space(1))) uint*)src,
                (__attribute__((address_space(3))) uint*)dst, 16, 0, 0);
        }
        __syncthreads();
        short8 ah[2], al[2];
        #pragma unroll
        for (int tm = 0; tm < 2; tm++) {
            ah[tm] = *(short8*)&Ah[w * 32 + tm * 16 + mn][quad * 8];
            al[tm] = *(short8*)&Al[w * 32 + tm * 16 + mn][quad * 8];
        }
        #pragma unroll
        for (int nt = 0; nt < 4; nt++) {
            short8 bh = *(short8*)&Bh[nt * 16 + mn][quad * 8];
            short8 bl = *(short8*)&Bl[nt * 16 + mn][quad * 8];
            #pragma unroll
            for (int tm = 0; tm < 2; tm++) {
                acc[tm][nt] = __builtin_amdgcn_mfma_f32_16x16x32_bf16(ah[tm], bh, acc[tm][nt], 0, 0, 0);
                acc[tm][nt] = __builtin_amdgcn_mfma_f32_16x16x32_bf16(ah[tm], bl, acc[tm][nt], 0, 0, 0);
                acc[tm][nt] = __builtin_amdgcn_mfma_f32_16x16x32_bf16(al[tm], bh, acc[tm][nt], 0, 0, 0);
            }
        }
        __syncthreads();
    }
    // epilogue: leaky, then l2norm over cols 0-31 (cap A) and 32-63 (cap B) per row.
    #pragma unroll
    for (int tm = 0; tm < 2; tm++)
        #pragma unroll
        for (int nt = 0; nt < 4; nt++)
            #pragma unroll
            for (int r = 0; r < 4; r++) {
                float v = acc[tm][nt][r];
                acc[tm][nt][r] = (v >= 0.f) ? v : 0.1f * v;
            }
    float invA[2][4], invB[2][4];
    #pragma unroll
    for (int tm = 0; tm < 2; tm++)
        #pragma unroll
        for (int r = 0; r < 4; r++) {
            float ssA = acc[tm][0][r] * acc[tm][0][r] + acc[tm][1][r] * acc[tm][1][r];
            float ssB = acc[tm][2][r] * acc[tm][2][r] + acc[tm][3][r] * acc[tm][3][r];
            #pragma unroll
            for (int off = 1; off < 16; off <<= 1) {
                ssA += __shfl_xor(ssA, off);
                ssB += __shfl_xor(ssB, off);
            }
            invA[tm][r] = 1.f / (sqrtf(ssA) + EPSF);
            invB[tm][r] = 1.f / (sqrtf(ssB) + EPSF);
        }
    #pragma unroll
    for (int tm = 0; tm < 2; tm++)
        #pragma unroll
        for (int nt = 0; nt < 4; nt++)
            #pragma unroll
            for (int r = 0; r < 4; r++) {
                int mrow = m0 + w * 32 + tm * 16 + quad * 4 + r;
                int ncol = n0 + nt * 16 + mn;
                float sc = (nt < 2) ? invA[tm][r] : invB[tm][r];
                C[(size_t)mrow * 2048 + ncol] = acc[tm][nt][r] * sc;
            }
}

// ---------------- k2a (fp32 fallback) ----------------
__global__ __launch_bounds__(256) void k2a(const float* __restrict__ A,
                                           const float* __restrict__ Bm,
                                           float* __restrict__ C,
                                           int n0, int NW) {
    __shared__ float As[16][132];
    __shared__ float Bs[16][68];
    int m0 = blockIdx.x * 128;
    int nb0 = n0 + blockIdx.y * 64;
    int t = threadIdx.x;
    int tm = t >> 4, tn = t & 15;
    float acc[8][4] = {};
    for (int kc = 0; kc < 64; kc++) {
        #pragma unroll
        for (int j = 0; j < 2; j++) {
            int idx = t + j * 256;
            int row = idx >> 2, kq = idx & 3;
            float4 v = *(const float4*)(A + (size_t)(m0 + row) * 1024 + kc * 16 + kq * 4);
            As[kq * 4 + 0][row] = v.x; As[kq * 4 + 1][row] = v.y;
            As[kq * 4 + 2][row] = v.z; As[kq * 4 + 3][row] = v.w;
        }
        {
            int row = t >> 2, kq = t & 3;
            float4 v = *(const float4*)(Bm + (size_t)(nb0 + row) * 1024 + kc * 16 + kq * 4);
            Bs[kq * 4 + 0][row] = v.x; Bs[kq * 4 + 1][row] = v.y;
            Bs[kq * 4 + 2][row] = v.z; Bs[kq * 4 + 3][row] = v.w;
        }
        __syncthreads();
        #pragma unroll
        for (int kk = 0; kk < 16; kk++) {
            float a0[4], a1[4], bb[4];
            *(float4*)a0 = *(float4*)&As[kk][tm * 8];
            *(float4*)a1 = *(float4*)&As[kk][tm * 8 + 4];
            *(float4*)bb = *(float4*)&Bs[kk][tn * 4];
            #pragma unroll
            for (int i = 0; i < 4; i++)
                #pragma unroll
                for (int j2 = 0; j2 < 4; j2++) {
                    acc[i][j2]     += a0[i] * bb[j2];
                    acc[i + 4][j2] += a1[i] * bb[j2];
                }
        }
        __syncthreads();
    }
    int cw0 = nb0 - n0 + tn * 4;
    #pragma unroll
    for (int i = 0; i < 8; i++) {
        float4 v = make_float4(acc[i][0], acc[i][1], acc[i][2], acc[i][3]);
        *(float4*)(C + (size_t)(m0 + tm * 8 + i) * NW + cw0) = v;
    }
}

// ---------------- k2bm v16: v13 structure minus leaky/l2norm (VERIFIED ~75.5us) -----------
__global__ __launch_bounds__(64) void k2bm(const ushort_t* __restrict__ imgT,
                                           const float* __restrict__ captions,
                                           const float* __restrict__ attn,
                                           const float* __restrict__ ws,
                                           float* __restrict__ ts_out) {
    int orig = blockIdx.x;
    int fh = orig >> 10;                        // 0..1
    int rest = orig & 1023;
    int cpair = rest >> 5;                      // 0..31
    int bp = rest & 31;                         // 0..31 ; XCD = bp%8
    int b0 = bp * 2;
    int c0 = cpair * 2;
    __shared__ union {
        float A[2][2][36][33];                  // [bi][ci][r][l] attn tiles (phase 1), pad 33
        float T[2][2][16][33];                  // [bi][ci][fl][l] tnode half-tiles (phase 2)
    } u;
    int t = threadIdx.x;
    int l = t & 31, hi = t >> 5;

    // phase 0: load 4 attn tiles (2 b x 2 ci) — already leaky+l2norm'd
    for (int i = t; i < 1152; i += 64) {
        int bi = i >= 576;
        int i2 = i - bi * 576;
        int ci = i2 >= 288;
        int i3 = i2 - ci * 288;
        int r = i3 >> 3, q = i3 & 7;
        *(float4*)&u.A[bi][ci][r][q * 4] =
            *(const float4*)(attn + (size_t)((b0 + bi) * 36 + r) * 2048 + (c0 + ci) * 32 + q * 4);
    }
    __syncthreads();
    for (int i = t; i < 128; i += 64) {         // softmax over regions per (bi, ci, word)
        int bi = i >= 64;
        int i2 = i & 63;
        int ci = i2 >> 5, ll = i2 & 31;
        float mx = -1e30f;
        for (int r = 0; r < 36; r++) mx = fmaxf(mx, u.A[bi][ci][r][ll]);
        mx *= LAM;
        float sum = 0.f;
        for (int r = 0; r < 36; r++) { float p = __expf(LAM * u.A[bi][ci][r][ll] - mx); u.A[bi][ci][r][ll] = p; sum += p; }
        float inv = 1.f / sum;
        for (int r = 0; r < 36; r++) u.A[bi][ci][r][ll] *= inv;
    }
    __syncthreads();

    // B-frags (k=r, n=l), 32x32x16 layout: n=lane&31, k=(lane>>5)*8+j
    short8 bh[2][2][3], bl[2][2][3];            // [bi][ci][kstep]
    #pragma unroll
    for (int bi = 0; bi < 2; bi++)
        #pragma unroll
        for (int ci = 0; ci < 2; ci++)
            #pragma unroll
            for (int k3 = 0; k3 < 3; k3++) {
                union { short8 v; ushort_t u8[8]; } H, L;
                #pragma unroll
                for (int j = 0; j < 8; j++) {
                    int r = k3 * 16 + hi * 8 + j;
                    float v = (r < 36) ? u.A[bi][ci][r][l] : 0.f;
                    ushort_t hv = bf16_rne(v);
                    H.u8[j] = hv;
                    L.u8[j] = bf16_rne(v - bf16_f(hv));
                }
                bh[bi][ci][k3] = H.v;
                bl[bi][ci][k3] = L.v;
            }
    __syncthreads();                            // A dead; union space becomes T

    const ushort_t* ibH0 = imgT + (size_t)b0 * 49152;   // ((f*3 + k3)*64 + lane)*8
    const ushort_t* ibL0 = ibH0 + IMGT2_EL;
    const ushort_t* ibH1 = ibH0 + 49152;
    const ushort_t* ibL1 = ibL0 + 49152;
    const float* qnp = ws + OFF_QN;
    float sv[2];
    sv[0] = ws[OFF_S + c0 * 32 + l];
    sv[1] = ws[OFF_S + (c0 + 1) * 32 + l];
    const float* capb[2];
    capb[0] = captions + (size_t)c0 * 32768 + (size_t)l * 1024 + hi * 4;
    capb[1] = capb[0] + 32768;

    for (int fl = 0; fl < 16; fl++) {
        int f = fh * 16 + fl;
        // A-frags for BOTH b's, all k-steps (imgT; shared across the 2 captions)
        short8 aA[2][3], aB[2][3];              // [plane hi/lo][k3]
        #pragma unroll
        for (int k3 = 0; k3 < 3; k3++) {
            size_t off = ((size_t)(f * 3 + k3) * 64 + t) * 8;
            aA[0][k3] = *(const short8*)(ibH0 + off);
            aA[1][k3] = *(const short8*)(ibL0 + off);
            aB[0][k3] = *(const short8*)(ibH1 + off);
            aB[1][k3] = *(const short8*)(ibL1 + off);
        }
        #pragma unroll
        for (int ci = 0; ci < 2; ci++) {
            // caption values loaded ONCE, used for both b's (the demand halving)
            float4 cv[4];
            #pragma unroll
            for (int g = 0; g < 4; g++) cv[g] = *(const float4*)(capb[ci] + f * 32 + g * 8);
            f32x16 accA = {0.f,0.f,0.f,0.f,0.f,0.f,0.f,0.f,0.f,0.f,0.f,0.f,0.f,0.f,0.f,0.f};
            f32x16 accB = {0.f,0.f,0.f,0.f,0.f,0.f,0.f,0.f,0.f,0.f,0.f,0.f,0.f,0.f,0.f,0.f};
            #pragma unroll
            for (int k3 = 0; k3 < 3; k3++) {
                accA = __builtin_amdgcn_mfma_f32_32x32x16_bf16(aA[0][k3], bh[0][ci][k3], accA, 0, 0, 0);
                accA = __builtin_amdgcn_mfma_f32_32x32x16_bf16(aA[0][k3], bl[0][ci][k3], accA, 0, 0, 0);
                accA = __builtin_amdgcn_mfma_f32_32x32x16_bf16(aA[1][k3], bh[0][ci][k3], accA, 0, 0, 0);
                accB = __builtin_amdgcn_mfma_f32_32x32x16_bf16(aB[0][k3], bh[1][ci][k3], accB, 0, 0, 0);
                accB = __builtin_amdgcn_mfma_f32_32x32x16_bf16(aB[0][k3], bl[1][ci][k3], accB, 0, 0, 0);
                accB = __builtin_amdgcn_mfma_f32_32x32x16_bf16(aB[1][k3], bh[1][ci][k3], accB, 0, 0, 0);
            }
            // lane holds wctxT[e_loc=(reg&3)+8*(reg>>2)+4*hi][l]; cv[g] covers e_loc=g*8+4*hi+0..3
            float numA = 0.f, w2A = 0.f, numB = 0.f, w2B = 0.f;
            #pragma unroll
            for (int g = 0; g < 4; g++) {
                numA += cv[g].x * accA[g*4+0] + cv[g].y * accA[g*4+1]
                      + cv[g].z * accA[g*4+2] + cv[g].w * accA[g*4+3];
                w2A  += accA[g*4+0]*accA[g*4+0] + accA[g*4+1]*accA[g*4+1]
                      + accA[g*4+2]*accA[g*4+2] + accA[g*4+3]*accA[g*4+3];
                numB += cv[g].x * accB[g*4+0] + cv[g].y * accB[g*4+1]
                      + cv[g].z * accB[g*4+2] + cv[g].w * accB[g*4+3];
                w2B  += accB[g*4+0]*accB[g*4+0] + accB[g*4+1]*accB[g*4+1]
                      + accB[g*4+2]*accB[g*4+2] + accB[g*4+3]*accB[g*4+3];
            }
            numA += __shfl_xor(numA, 32); w2A += __shfl_xor(w2A, 32);
            numB += __shfl_xor(numB, 32); w2B += __shfl_xor(w2B, 32);
            if (hi == 0) {
                float qv = qnp[(c0 + ci) * 1024 + l * 32 + f];   // b-independent
                float denA = fmaxf(qv * sqrtf(w2A), EPSF);
                u.T[0][ci][fl][l] = (numA / denA) * sv[ci];
                float denB = fmaxf(qv * sqrtf(w2B), EPSF);
                u.T[1][ci][fl][l] = (numB / denB) * sv[ci];
            }
        }
    }
    __syncthreads();
    // burst: 2b x 2ci x 32l x 16f floats -> ts_out (transpose-read from T)
    #pragma unroll
    for (int j = 0; j < 8; j++) {
        int id = t + j * 64;                    // 0..511 float4-items
        int bi = id >> 8;
        int ci = (id >> 7) & 1;
        int r2 = id & 127;
        int ll = r2 >> 2, q = r2 & 3;
        float4 v;
        v.x = u.T[bi][ci][q * 4 + 0][ll];
        v.y = u.T[bi][ci][q * 4 + 1][ll];
        v.z = u.T[bi][ci][q * 4 + 2][ll];
        v.w = u.T[bi][ci][q * 4 + 3][ll];
        *(float4*)(ts_out + ((size_t)(c0 + ci) * 64 + b0 + bi) * 1024 + ll * 32 + fh * 16 + q * 4) = v;
    }
}

// ---------------- k2b (fp32 fallback, validated R4 version) ----------------
__global__ __launch_bounds__(256) void k2b(const float* __restrict__ images,
                                           const float* __restrict__ captions,
                                           const float* __restrict__ attn,
                                           const float* __restrict__ ws,
                                           float* __restrict__ ts_out,
                                           int c0, int NW) {
    int b = blockIdx.x;
    int cw = blockIdx.y;
    int ca = c0 + cw * 2;
    __shared__ float A2[2][36][36];
    __shared__ float Ims[36][256];
    __shared__ float scs[2][32];
    const float* img = images + (size_t)b * 36 * 1024;
    int t = threadIdx.x;
    int el = t & 63;
    int lg = t >> 6;

    for (int i = t; i < 576; i += 256) {
        int r = i >> 4, q = i & 15;
        float4 v = *(const float4*)(attn + (size_t)(b * 36 + r) * NW + cw * 64 + q * 4);
        *(float4*)&A2[q >> 3][r][(q & 7) * 4] = v;
    }
    __syncthreads();
    if (t < 72) {
        int ci = t >= 36, r = t - 36 * ci;
        float ss = 0.f;
        #pragma unroll
        for (int l = 0; l < 32; l++) {
            float v = A2[ci][r][l];
            v = (v >= 0.f) ? v : 0.1f * v;
            A2[ci][r][l] = v; ss += v * v;
        }
        float inv = 1.f / (sqrtf(ss) + EPSF);
        #pragma unroll
        for (int l = 0; l < 32; l++) A2[ci][r][l] *= inv;
    }
    __syncthreads();
    if (t < 64) {
        int ci = t >> 5, l = t & 31;
        float mx = -1e30f;
        for (int r = 0; r < 36; r++) mx = fmaxf(mx, A2[ci][r][l]);
        mx *= LAM;
        float sum = 0.f;
        for (int r = 0; r < 36; r++) { float p = __expf(LAM * A2[ci][r][l] - mx); A2[ci][r][l] = p; sum += p; }
        float inv = 1.f / sum;
        for (int r = 0; r < 36; r++) A2[ci][r][l] *= inv;
    } else if (t >= 128 && t < 192) {
        int i = t - 128;
        scs[i >> 5][i & 31] = ws[OFF_S + (ca + (i >> 5)) * 32 + (i & 31)];
    }
    __syncthreads();

    const float* qn = ws + OFF_QN;
    for (int g = 0; g < 4; g++) {
        for (int i = t; i < 2304; i += 256) {
            int r = i >> 6, q = i & 63;
            *(float4*)&Ims[r][q * 4] = *(const float4*)(img + (size_t)r * 1024 + g * 256 + q * 4);
        }
        __syncthreads();

        float acc[2][8][4] = {};
        #pragma unroll 2
        for (int r = 0; r < 36; r++) {
            float4 iv = *(float4*)&Ims[r][el * 4];
            float ivv[4] = {iv.x, iv.y, iv.z, iv.w};
            #pragma unroll
            for (int ci = 0; ci < 2; ci++) {
                float av[8];
                *(float4*)&av[0] = *(float4*)&A2[ci][r][lg * 8];
                *(float4*)&av[4] = *(float4*)&A2[ci][r][lg * 8 + 4];
                #pragma unroll
                for (int i = 0; i < 8; i++)
                    #pragma unroll
                    for (int e = 0; e < 4; e++)
                        acc[ci][i][e] += av[i] * ivv[e];
            }
        }

        int fb = el >> 3;
        int f = g * 8 + fb;
        #pragma unroll
        for (int ci = 0; ci < 2; ci++) {
            int c = ca + ci;
            const float* cap = captions + (size_t)c * 32 * 1024 + g * 256;
            #pragma unroll
            for (int i = 0; i < 8; i++) {
                int l = lg * 8 + i;
                float4 cv = *(const float4*)(cap + (size_t)l * 1024 + el * 4);
                float num = cv.x * acc[ci][i][0] + cv.y * acc[ci][i][1]
                          + cv.z * acc[ci][i][2] + cv.w * acc[ci][i][3];
                float w2 = acc[ci][i][0] * acc[ci][i][0] + acc[ci][i][1] * acc[ci][i][1]
                         + acc[ci][i][2] * acc[ci][i][2] + acc[ci][i][3] * acc[ci][i][3];
                num += __shfl_down(num, 4); w2 += __shfl_down(w2, 4);
                num += __shfl_down(num, 2); w2 += __shfl_down(w2, 2);
                num += __shfl_down(num, 1); w2 += __shfl_down(w2, 1);
                if ((el & 7) == 0) {
                    float den = fmaxf(qn[c * 1024 + l * 32 + f] * sqrtf(w2), EPSF);
                    ts_out[(((size_t)c * 64 + b) * 32 + l) * 32 + f] = (num / den) * scs[ci][l];
                }
            }
        }
        __syncthreads();
    }
}

// ---------------- k3 (MFMA): similarities[b][c] = mean_l W2·tanh(ts@M1^T + b1) + b2 ----------------
__global__ __launch_bounds__(256) void k3(const float* __restrict__ ts_ws,
                                          const ushort_t* __restrict__ Mb,
                                          const float* __restrict__ b1,
                                          const float* __restrict__ W2,
                                          const float* __restrict__ b2,
                                          float* __restrict__ out_sim) {
    int c = blockIdx.x >> 6, b = blockIdx.x & 63;
    __shared__ ushort_t tsh[32][32], tsl[32][32];
    __shared__ float red[4];
    int t = threadIdx.x;
    const float* tsrc = ts_ws + (size_t)(c * 64 + b) * 1024;
    {
        int row = t >> 3, q = t & 7;
        float4 v = *(const float4*)(tsrc + row * 32 + q * 4);
        float x[4] = {v.x, v.y, v.z, v.w};
        ushort_t hh[4], ll[4];
        #pragma unroll
        for (int j = 0; j < 4; j++) {
            hh[j] = bf16_rne(x[j]);
            ll[j] = bf16_rne(x[j] - bf16_f(hh[j]));
        }
        *(uint2*)&tsh[row][q * 4] = make_uint2(pack2(hh[0], hh[1]), pack2(hh[2], hh[3]));
        *(uint2*)&tsl[row][q * 4] = make_uint2(pack2(ll[0], ll[1]), pack2(ll[2], ll[3]));
    }
    __syncthreads();
    int w = t >> 6, lane = t & 63, quad = lane >> 4, mn = lane & 15;
    const ushort_t* M1H = Mb + 65536;
    short8 ah[2], al[2];
    #pragma unroll
    for (int mt = 0; mt < 2; mt++) {
        ah[mt] = *(short8*)&tsh[mt * 16 + mn][quad * 8];
        al[mt] = *(short8*)&tsl[mt * 16 + mn][quad * 8];
    }
    float psum = 0.f;
    #pragma unroll
    for (int nt = 0; nt < 8; nt++) {
        int h = w * 128 + nt * 16 + mn;
        short8 bh = *(const short8*)(M1H + h * 32 + quad * 8);
        short8 bl = *(const short8*)(M1H + 16384 + h * 32 + quad * 8);
        float b1v = b1[h], w2v = W2[h];
        #pragma unroll
        for (int mt = 0; mt < 2; mt++) {
            float4v acc = (float4v){0.f, 0.f, 0.f, 0.f};
            acc = __builtin_amdgcn_mfma_f32_16x16x32_bf16(ah[mt], bh, acc, 0, 0, 0);
            acc = __builtin_amdgcn_mfma_f32_16x16x32_bf16(ah[mt], bl, acc, 0, 0, 0);
            acc = __builtin_amdgcn_mfma_f32_16x16x32_bf16(al[mt], bh, acc, 0, 0, 0);
            #pragma unroll
            for (int r = 0; r < 4; r++) {
                float x = fminf(fmaxf(acc[r] + b1v, -15.f), 15.f);
                float e2 = __expf(2.f * x);
                psum += (1.f - 2.f / (e2 + 1.f)) * w2v;
            }
        }
    }
    #pragma unroll
    for (int off = 32; off >= 1; off >>= 1) psum += __shfl_down(psum, off);
    if (lane == 0) red[w] = psum;
    __syncthreads();
    if (t == 0) out_sim[b * 64 + c] = b2[0] + (red[0] + red[1] + red[2] + red[3]) * (1.f / 32.f);
}

// ---------------- k5 v2 (MFMA): k4 softmax folded in; block per (b,l), 256 threads --------
__global__ __launch_bounds__(256) void k5(const float* __restrict__ ts_ws,
                                          const float* __restrict__ ws,
                                          const float* __restrict__ b_mu,
                                          const float* __restrict__ b_lv,
                                          float* __restrict__ out) {
    int b = blockIdx.x >> 5, l = blockIdx.x & 31;
    int t = threadIdx.x;
    __shared__ ushort_t tsh[64][32], tsl[64][32];
    __shared__ float wls[64];
    {
        int cc = t >> 2, q = t & 3;
        const float* src = ts_ws + (((size_t)cc * 64 + b) * 32 + l) * 32 + q * 8;
        #pragma unroll
        for (int half = 0; half < 2; half++) {
            float4 v = *(const float4*)(src + half * 4);
            float x[4] = {v.x, v.y, v.z, v.w};
            ushort_t hh[4], ll[4];
            #pragma unroll
            for (int j = 0; j < 4; j++) {
                hh[j] = bf16_rne(x[j]);
                ll[j] = bf16_rne(x[j] - bf16_f(hh[j]));
            }
            *(uint2*)&tsh[cc][q * 8 + half * 4] = make_uint2(pack2(hh[0], hh[1]), pack2(hh[2], hh[3]));
            *(uint2*)&tsl[cc][q * 8 + half * 4] = make_uint2(pack2(ll[0], ll[1]), pack2(ll[2], ll[3]));
        }
    }
    if (t < 64) {                                // folded k4: softmax over c for this b
        float v = out[b * 64 + t];
        float mx = v;
        #pragma unroll
        for (int off = 32; off >= 1; off >>= 1) mx = fmaxf(mx, __shfl_xor(mx, off));
        float p = __expf(v - mx);
        float sum = p;
        #pragma unroll
        for (int off = 32; off >= 1; off >>= 1) sum += __shfl_xor(sum, off);
        wls[t] = p / sum;
    }
    __syncthreads();

    int w = t >> 6, lane = t & 63, quad = lane >> 4, mn = lane & 15;
    const ushort_t* Mb = (const ushort_t*)ws;
    const ushort_t* MmuH = Mb;
    const ushort_t* MlvH = Mb + 32768;
    short8 ah[4], al[4];
    #pragma unroll
    for (int mt = 0; mt < 4; mt++) {
        ah[mt] = *(short8*)&tsh[mt * 16 + mn][quad * 8];
        al[mt] = *(short8*)&tsl[mt * 16 + mn][quad * 8];
    }
    float pm[8], pq[8], pe[8];
    #pragma unroll
    for (int nt = 0; nt < 8; nt++) {
        int h = w * 128 + nt * 16 + mn;
        {
            short8 bh = *(const short8*)(MmuH + h * 32 + quad * 8);
            short8 bl = *(const short8*)(MmuH + 16384 + h * 32 + quad * 8);
            float bmv = b_mu[h];
            float am = 0.f, aq = 0.f;
            #pragma unroll
            for (int mt = 0; mt < 4; mt++) {
                float4v acc = (float4v){0.f, 0.f, 0.f, 0.f};
                acc = __builtin_amdgcn_mfma_f32_16x16x32_bf16(ah[mt], bh, acc, 0, 0, 0);
                acc = __builtin_amdgcn_mfma_f32_16x16x32_bf16(ah[mt], bl, acc, 0, 0, 0);
                acc = __builtin_amdgcn_mfma_f32_16x16x32_bf16(al[mt], bh, acc, 0, 0, 0);
                #pragma unroll
                for (int r = 0; r < 4; r++) {
                    int cc = mt * 16 + quad * 4 + r;
                    float mu = acc[r] + bmv;
                    float wv = wls[cc];
                    am += wv * mu;
                    aq += wv * mu * mu;
                }
            }
            am += __shfl_xor(am, 16); am += __shfl_xor(am, 32);
            aq += __shfl_xor(aq, 16); aq += __shfl_xor(aq, 32);
            pm[nt] = am; pq[nt] = aq;
        }
        {
            short8 bh = *(const short8*)(MlvH + h * 32 + quad * 8);
            short8 bl = *(const short8*)(MlvH + 16384 + h * 32 + quad * 8);
            float blv = b_lv[h];
            float ae = 0.f;
            #pragma unroll
            for (int mt = 0; mt < 4; mt++) {
                float4v acc = (float4v){0.f, 0.f, 0.f, 0.f};
                acc = __builtin_amdgcn_mfma_f32_16x16x32_bf16(ah[mt], bh, acc, 0, 0, 0);
                acc = __builtin_amdgcn_mfma_f32_16x16x32_bf16(ah[mt], bl, acc, 0, 0, 0);
                acc = __builtin_amdgcn_mfma_f32_16x16x32_bf16(al[mt], bh, acc, 0, 0, 0);
                #pragma unroll
                for (int r = 0; r < 4; r++) {
                    int cc = mt * 16 + quad * 4 + r;
                    ae += wls[cc] * __expf(acc[r] + blv);
                }
            }
            ae += __shfl_xor(ae, 16); ae += __shfl_xor(ae, 32);
            pe[nt] = ae;
        }
    }
    if (quad == 0) {
        #pragma unroll
        for (int nt = 0; nt < 8; nt++) {
            int h = w * 128 + nt * 16 + mn;
            size_t idx = (size_t)(b * 32 + l) * 512 + h;
            float m = pm[nt];
            out[4096 + idx] = m;
            float var = pe[nt] + pq[nt] - m * m;
            out[4096 + 64 * 32 * 512 + idx] = sqrtf(fmaxf(var, 1e-8f));
        }
    }
}

extern "C" void kernel_launch(void* const* d_in, const int* in_sizes, int n_in,
                              void* d_out, int out_size, void* d_ws, size_t ws_size,
                              hipStream_t stream) {
    const float* images   = (const float*)d_in[0];
    const float* captions = (const float*)d_in[1];
    const int*   depends  = (const int*)d_in[2];
    const float* Wgc = (const float*)d_in[3];
    const float* Wmu = (const float*)d_in[4];
    const float* bmu = (const float*)d_in[5];
    const float* Wlv = (const float*)d_in[6];
    const float* blv = (const float*)d_in[7];
    const float* W1  = (const float*)d_in[8];
    const float* b1  = (const float*)d_in[9];
    const float* W2  = (const float*)d_in[10];
    const float* b2  = (const float*)d_in[11];
    float* out = (float*)d_out;
    float* ws  = (float*)d_ws;

    size_t need_floats  = (size_t)OFF_CVT + CVT_FLOATS;             // cvt in-place (reuse)
    size_t need2_floats = need_floats + (size_t)IMGT2_EL;           // + separate imgT2
    bool use_mfma = ws_size >= need_floats * 4;
    bool sep_imgt = ws_size >= need2_floats * 4;

    if (use_mfma) {
        ushort_t* cvt = (ushort_t*)(ws + OFF_CVT);
        if (sep_imgt) {
            // 5-launch path: kcvt+kcvt2+kpre1 fused (all input-only readers, disjoint writes)
            ushort_t* imgT2 = (ushort_t*)(ws + OFF_IMGT2);
            hipLaunchKernelGGL(kfuse, dim3(KCVT_BLOCKS + KCVT2_BLOCKS + KPRE1_BLOCKS),
                               dim3(256), 0, stream,
                               images, captions, cvt, imgT2, Wmu, Wlv, W1, Wgc, depends, ws);
            hipLaunchKernelGGL(k2a_mfma, dim3(32, 18), dim3(256), 0, stream, cvt, ws + OFF_ATTN);
            hipLaunchKernelGGL(k2bm, dim3(2048), dim3(64), 0, stream,
                               imgT2, captions, ws + OFF_ATTN, ws, ws + OFF_TS);
        } else {
            // 6-launch fallback: imgT2 reuses the CVT region (dead after k2a)
            hipLaunchKernelGGL(kpre1, dim3(256), dim3(256), 0, stream,
                               Wmu, Wlv, W1, Wgc, captions, depends, ws, 0);
            hipLaunchKernelGGL(kcvt, dim3(KCVT_BLOCKS), dim3(256), 0, stream,
                               images, captions, cvt, ws);
            hipLaunchKernelGGL(k2a_mfma, dim3(32, 18), dim3(256), 0, stream, cvt, ws + OFF_ATTN);
            hipLaunchKernelGGL(kcvt2, dim3(KCVT2_BLOCKS), dim3(256), 0, stream, images, cvt);
            hipLaunchKernelGGL(k2bm, dim3(2048), dim3(64), 0, stream,
                               cvt, captions, ws + OFF_ATTN, ws, ws + OFF_TS);
        }
    } else {
        hipLaunchKernelGGL(kpre1, dim3(256), dim3(256), 0, stream,
                           Wmu, Wlv, W1, Wgc, captions, depends, ws, 1);
        int NW = 2048;
        while (NW > 64 && ((size_t)OFF_ATTN + (size_t)2304 * NW) * 4 > ws_size) NW >>= 1;
        for (int n0 = 0; n0 < 2048; n0 += NW) {
            hipLaunchKernelGGL(k2a, dim3(18, NW / 64), dim3(256), 0, stream,
                               images, captions, ws + OFF_ATTN, n0, NW);
            hipLaunchKernelGGL(k2b, dim3(64, NW / 64), dim3(256), 0, stream,
                               images, captions, ws + OFF_ATTN, ws, ws + OFF_TS, n0 / 32, NW);
        }
    }

    hipLaunchKernelGGL(k3, dim3(4096), dim3(256), 0, stream,
                       ws + OFF_TS, (const ushort_t*)ws, b1, W2, b2, out);
    hipLaunchKernelGGL(k5, dim3(2048), dim3(256), 0, stream, ws + OFF_TS, ws, bmu, blv, out);
}